// Round 3
// baseline (3837.165 us; speedup 1.0000x reference)
//
#include <hip/hip_runtime.h>
#include <hip/hip_bf16.h>

#define NN 300000
#define EE 299999
#define AA 150000
#define DD 64
#define HH 128
#define TT 512

typedef unsigned short u16;
typedef unsigned int u32;

// ---------- helpers ----------
__device__ __forceinline__ float bfb(u16 u) { return __uint_as_float(((u32)u) << 16); }
__device__ __forceinline__ u16 f2b(float f) {
    u32 u = __float_as_uint(f);
    u32 r = (u + 0x7FFFu + ((u >> 16) & 1u)) >> 16;
    return (u16)r;
}
__device__ __forceinline__ float ldin(const float* p, size_t i) { return p[i]; }
__device__ __forceinline__ float ldin(const u16* p, size_t i) { return bfb(p[i]); }
__device__ __forceinline__ unsigned f2key(float f) {
    unsigned u = __float_as_uint(f);
    return (u & 0x80000000u) ? ~u : (u | 0x80000000u);
}
__device__ __forceinline__ float key2f(unsigned k) {
    unsigned u = (k & 0x80000000u) ? (k & 0x7fffffffu) : ~k;
    return __uint_as_float(u);
}

// ---------- tiny precomputes (all-f32 inputs) ----------
__global__ void k_context(const float* __restrict__ focal, const float* __restrict__ Wseq,
                          const float* __restrict__ bseq, float* __restrict__ ctx) {
    int t = threadIdx.x;
    float acc = bseq[t];
    for (int d = 0; d < DD; ++d) acc = fmaf(focal[d], Wseq[d * HH + t], acc);
    ctx[t] = acc;
}

__global__ void k_c1(const float* __restrict__ ctx, const float* __restrict__ Wa1c,
                     const float* __restrict__ ba1, float* __restrict__ c1) {
    int t = threadIdx.x;
    float acc = ba1[t];
    for (int k = 0; k < HH; ++k) acc = fmaf(ctx[k], Wa1c[k * HH + t], acc);
    c1[t] = acc;
}

__global__ void k_tproj(const float* __restrict__ tt, const float* __restrict__ Wa1m,
                        float* __restrict__ tproj) {
    int ti = blockIdx.x, t = threadIdx.x;
    float acc = 0.f;
    for (int k = 0; k < HH; ++k)
        acc = fmaf(tt[ti * HH + k], Wa1m[k * HH + t], acc);
    tproj[(size_t)ti * HH + t] = acc;
}

// ---------- row-wise projection: out_bf16[r,:] = in[r,:] @ W + b ----------
template <int K, typename InT>
__global__ __launch_bounds__(256) void k_proj(const InT* __restrict__ in,
                                              const float* __restrict__ W,
                                              const float* __restrict__ bias,
                                              u16* __restrict__ out, int nrows) {
    __shared__ u16 wlds[K * HH];
    __shared__ float rows[2][K];
    for (int i = threadIdx.x; i < K * HH; i += 256) wlds[i] = f2b(W[i]);
    int t = threadIdx.x;
    int half = t >> 7, col = t & 127;
    float bcol = bias[col];
    int npairs = (nrows + 1) >> 1;
    for (int p = blockIdx.x; p < npairs; p += gridDim.x) {
        __syncthreads();
        if (t < 2 * K) {
            int rr = (K == 128) ? (t >> 7) : (t >> 6);
            int kk = t & (K - 1);
            int row = 2 * p + rr;
            rows[rr][kk] = (row < nrows) ? ldin(in, (size_t)row * K + kk) : 0.f;
        }
        __syncthreads();
        float acc = bcol;
#pragma unroll 8
        for (int k = 0; k < K; ++k)
            acc = fmaf(rows[half][k], bfb(wlds[k * HH + col]), acc);
        int row = 2 * p + half;
        if (row < nrows) out[(size_t)row * HH + col] = f2b(acc);
    }
}

// ---------- gathered projection: branch_f32[i,:] (+)= h_bf16[idx[i],:] @ W (+ b) ----------
template <bool ACC>
__global__ __launch_bounds__(256) void k_gproj(const u16* __restrict__ hsrc,
                                               const int* __restrict__ idx,
                                               const float* __restrict__ W,
                                               const float* __restrict__ bias,
                                               float* __restrict__ out, int nrows) {
    __shared__ u16 wlds[HH * HH];
    __shared__ float rows[2][HH];
    for (int i = threadIdx.x; i < HH * HH; i += 256) wlds[i] = f2b(W[i]);
    int t = threadIdx.x, half = t >> 7, col = t & 127;
    float bcol = (bias != nullptr) ? bias[col] : 0.f;
    int npairs = (nrows + 1) >> 1;
    for (int p = blockIdx.x; p < npairs; p += gridDim.x) {
        __syncthreads();
        {
            int it = 2 * p + half;
            int g = (it < nrows) ? idx[it] : -1;
            rows[half][col] = (g >= 0) ? bfb(hsrc[(size_t)g * HH + col]) : 0.f;
        }
        __syncthreads();
        float acc = bcol;
#pragma unroll 8
        for (int k = 0; k < HH; ++k)
            acc = fmaf(rows[half][k], bfb(wlds[k * HH + col]), acc);
        int item = 2 * p + half;
        if (item < nrows) {
            if (ACC) out[(size_t)item * HH + col] += acc;
            else     out[(size_t)item * HH + col] = acc;
        }
    }
}

// ---------- edge pass A: a[e] = leaky(xl[src]+xr[dst]) . att ; segment max ----------
__global__ __launch_bounds__(256) void k_edge_score(const u16* __restrict__ xl,
                                                    const u16* __restrict__ xr,
                                                    const int* __restrict__ src,
                                                    const int* __restrict__ dst,
                                                    const float* __restrict__ att,
                                                    float* __restrict__ a_e,
                                                    unsigned* __restrict__ amax) {
    __shared__ float att_l[HH];
    if (threadIdx.x < HH) att_l[threadIdx.x] = att[threadIdx.x];
    __syncthreads();
    int wid = blockIdx.x * 4 + (threadIdx.x >> 6);
    int lane = threadIdx.x & 63;
    if (wid >= EE) return;
    int s = src[wid], d = dst[wid];
    u32 pl = ((const u32*)xl)[(size_t)s * 64 + lane];
    u32 pr = ((const u32*)xr)[(size_t)d * 64 + lane];
    float e0 = bfb((u16)pl) + bfb((u16)pr);
    float e1 = bfb((u16)(pl >> 16)) + bfb((u16)(pr >> 16));
    e0 = e0 >= 0.f ? e0 : 0.2f * e0;
    e1 = e1 >= 0.f ? e1 : 0.2f * e1;
    float acc = fmaf(e0, att_l[2 * lane], e1 * att_l[2 * lane + 1]);
    for (int off = 32; off; off >>= 1) acc += __shfl_down(acc, off);
    if (lane == 0) {
        a_e[wid] = acc;
        atomicMax(&amax[d], f2key(acc));
    }
}

// ---------- edge pass B: ex = exp(a - amax[dst]); denom[dst] += ex ----------
__global__ __launch_bounds__(256) void k_edge_norm(float* __restrict__ a_e,
                                                   const int* __restrict__ dst,
                                                   const unsigned* __restrict__ amax,
                                                   float* __restrict__ denom) {
    int e = blockIdx.x * blockDim.x + threadIdx.x;
    if (e >= EE) return;
    int d = dst[e];
    float ex = __expf(a_e[e] - key2f(amax[d]));
    a_e[e] = ex;
    atomicAdd(&denom[d], ex);
}

// ---------- edge pass C (half of feature dim): agg[dst, half] += alpha * xl[src, half] ----------
__global__ __launch_bounds__(256) void k_edge_agg_half(const u16* __restrict__ xl,
                                                       const float* __restrict__ ex_e,
                                                       const int* __restrict__ src,
                                                       const int* __restrict__ dst,
                                                       const float* __restrict__ denom,
                                                       float* __restrict__ agg, int half) {
    int wid = blockIdx.x * 4 + (threadIdx.x >> 6);
    int lane = threadIdx.x & 63;
    if (wid >= EE) return;
    int s = src[wid], d = dst[wid];
    float alpha = ex_e[wid] / (denom[d] + 1e-16f);
    float v = bfb(xl[(size_t)s * HH + half * 64 + lane]);
    atomicAdd(&agg[(size_t)d * 64 + lane], alpha * v);
}

// ---------- h[:, half] += relu(agg + bias[half]) ----------
__global__ __launch_bounds__(256) void k_update_half(u16* __restrict__ h,
                                                     const float* __restrict__ agg,
                                                     const float* __restrict__ bias, int half) {
    size_t i = (size_t)blockIdx.x * 256 + threadIdx.x;  // over N*64
    if (i >= (size_t)NN * 64) return;
    int n = (int)(i >> 6), c = (int)(i & 63);
    int col = half * 64 + c;
    size_t hi = (size_t)n * HH + col;
    float hv = bfb(h[hi]);
    float av = agg[i] + bias[col];
    hv += fmaxf(av, 0.f);
    h[hi] = f2b(hv);
}

// ---------- fused z + logit (f32 output) ----------
__global__ __launch_bounds__(256) void k_zlogit(const float* __restrict__ branch,
                                                const int* __restrict__ time_idx,
                                                const float* __restrict__ tproj,
                                                const float* __restrict__ c1,
                                                const float* __restrict__ Wa1t,
                                                const float* __restrict__ Wa2,
                                                const float* __restrict__ ba2,
                                                float* __restrict__ out) {
    __shared__ u16 wlds[HH * HH];
    __shared__ float rows[2][HH];
    __shared__ float red[2][2];
    for (int i = threadIdx.x; i < HH * HH; i += 256) wlds[i] = f2b(Wa1t[i]);
    int t = threadIdx.x, half = t >> 7, col = t & 127;
    int lane = t & 63, wv = (t >> 6) & 1;
    float wa2c = Wa2[col];
    float ba2v = ba2[0];
    int npairs = (AA + 1) >> 1;
    for (int p = blockIdx.x; p < npairs; p += gridDim.x) {
        __syncthreads();
        {
            int it = 2 * p + half;
            rows[half][col] = (it < AA) ? branch[(size_t)it * HH + col] : 0.f;
        }
        __syncthreads();
        float acc = 0.f;
#pragma unroll 8
        for (int k = 0; k < HH; ++k)
            acc = fmaf(rows[half][k], bfb(wlds[k * HH + col]), acc);
        int item = 2 * p + half;
        float zv = 0.f;
        if (item < AA) {
            int ti = time_idx[item];
            zv = fmaxf(acc + tproj[(size_t)ti * HH + col] + c1[col], 0.f);
        }
        float partial = zv * wa2c;
        for (int off = 32; off; off >>= 1) partial += __shfl_down(partial, off);
        if (lane == 0) red[half][wv] = partial;
        __syncthreads();
        if (col == 0 && item < AA)
            out[item] = red[half][0] + red[half][1] + ba2v;
    }
}

// ---------- host side ----------
typedef const float* fp;

static void run_gat(u16* h, u16* xl, u16* xr, float* agg /*aliases xr*/,
                    float* a_e, unsigned* amax, float* denom,
                    const int* src, const int* dst,
                    fp Wl, fp bl, fp Wr, fp br, fp att, fp bias, hipStream_t stream) {
    hipMemsetAsync(amax, 0, (size_t)NN * 4, stream);
    hipMemsetAsync(denom, 0, (size_t)NN * 4, stream);
    k_proj<128, u16><<<1024, 256, 0, stream>>>(h, Wl, bl, xl, NN);
    k_proj<128, u16><<<1024, 256, 0, stream>>>(h, Wr, br, xr, NN);
    k_edge_score<<<(EE + 3) / 4, 256, 0, stream>>>(xl, xr, src, dst, att, a_e, amax);
    k_edge_norm<<<(EE + 255) / 256, 256, 0, stream>>>(a_e, dst, amax, denom);
    for (int half = 0; half < 2; ++half) {
        hipMemsetAsync(agg, 0, (size_t)NN * 64 * 4, stream);  // xr dead after score
        k_edge_agg_half<<<(EE + 3) / 4, 256, 0, stream>>>(xl, a_e, src, dst, denom, agg, half);
        k_update_half<<<((NN * 64) + 255) / 256, 256, 0, stream>>>(h, agg, bias, half);
    }
}

extern "C" void kernel_launch(void* const* d_in, const int* in_sizes, int n_in,
                              void* d_out, int out_size, void* d_ws, size_t ws_size,
                              hipStream_t stream) {
    fp x                 = (fp)d_in[0];
    const int* ei        = (const int*)d_in[1];
    fp focal             = (fp)d_in[2];
    const int* child_idx = (const int*)d_in[3];
    const int* parent_idx= (const int*)d_in[4];
    const int* time_idx  = (const int*)d_in[5];
    fp W_embed = (fp)d_in[6],  b_embed = (fp)d_in[7];
    fp bu_Wl   = (fp)d_in[8],  bu_bl   = (fp)d_in[9];
    fp bu_Wr   = (fp)d_in[10], bu_br   = (fp)d_in[11];
    fp bu_att  = (fp)d_in[12], bu_bias = (fp)d_in[13];
    fp td_Wl   = (fp)d_in[14], td_bl   = (fp)d_in[15];
    fp td_Wr   = (fp)d_in[16], td_br   = (fp)d_in[17];
    fp td_att  = (fp)d_in[18], td_bias = (fp)d_in[19];
    fp time_table = (fp)d_in[20];
    fp W_comb  = (fp)d_in[21], b_comb  = (fp)d_in[22];
    fp W_a1    = (fp)d_in[23], b_a1    = (fp)d_in[24];
    fp W_a2    = (fp)d_in[25], b_a2    = (fp)d_in[26];
    fp W_seq   = (fp)d_in[27], b_seq   = (fp)d_in[28];

    const size_t NH = (size_t)NN * HH;
    u16* h  = (u16*)d_ws;                 // N*H bf16           (76.8 MB)
    u16* xl = h + NH;                     // N*H bf16           (76.8 MB)
    u16* xr = xl + NH;                    // N*H bf16           (76.8 MB)
    float* agg = (float*)xr;              // N*64 f32, aliases xr (dead after score)
    float* branch = (float*)xl;           // A*H f32, aliases xl (dead after GATs)
    float* a_e   = (float*)(xr + NH);     // E
    unsigned* amax = (unsigned*)(a_e + EE);  // N
    float* denom = (float*)(amax + NN);   // N
    float* ctx   = denom + NN;            // H
    float* c1v   = ctx + HH;              // H
    float* tproj = c1v + HH;              // T*H

    // small precomputes (independent of h)
    k_context<<<1, 128, 0, stream>>>(focal, W_seq, b_seq, ctx);
    k_c1<<<1, 128, 0, stream>>>(ctx, W_a1 + (size_t)256 * HH, b_a1, c1v);
    k_tproj<<<TT, 128, 0, stream>>>(time_table, W_a1 + (size_t)128 * HH, tproj);

    // embed: h = x @ W_embed + b_embed
    k_proj<64, float><<<1024, 256, 0, stream>>>(x, W_embed, b_embed, h, NN);

    // bottom-up GAT: src = edge_index[1], dst = edge_index[0]
    run_gat(h, xl, xr, agg, a_e, amax, denom, ei + EE, ei,
            bu_Wl, bu_bl, bu_Wr, bu_br, bu_att, bu_bias, stream);
    // top-down GAT: src = edge_index[0], dst = edge_index[1]
    run_gat(h, xl, xr, agg, a_e, amax, denom, ei, ei + EE,
            td_Wl, td_bl, td_Wr, td_br, td_att, td_bias, stream);

    // branch = [h_child, h_parent] @ W_comb + b_comb   (branch stored over xl)
    k_gproj<false><<<1024, 256, 0, stream>>>(h, child_idx, W_comb, b_comb, branch, AA);
    k_gproj<true><<<1024, 256, 0, stream>>>(h, parent_idx, W_comb + (size_t)HH * HH, nullptr, branch, AA);

    // logits = relu(branch@Wa1_top + tproj[tidx] + c1) @ W_a2 + b_a2
    k_zlogit<<<1024, 256, 0, stream>>>(branch, time_idx, tproj, c1v,
                                       W_a1, W_a2, b_a2, (float*)d_out);
}

// Round 4
// 1541.772 us; speedup vs baseline: 2.4888x; 2.4888x over previous
//
#include <hip/hip_runtime.h>
#include <hip/hip_bf16.h>

#define NN 300000
#define EE 299999
#define AA 150000
#define DD 64
#define HH 128
#define TT 512

typedef unsigned short u16;
typedef unsigned int u32;
typedef __attribute__((ext_vector_type(8))) short short8;
typedef __attribute__((ext_vector_type(4))) float f32x4;

// ---------- helpers ----------
__device__ __forceinline__ float bfb(u16 u) { return __uint_as_float(((u32)u) << 16); }
__device__ __forceinline__ u16 f2b(float f) {
    u32 u = __float_as_uint(f);
    u32 r = (u + 0x7FFFu + ((u >> 16) & 1u)) >> 16;
    return (u16)r;
}
__device__ __forceinline__ unsigned f2key(float f) {
    unsigned u = __float_as_uint(f);
    return (u & 0x80000000u) ? ~u : (u | 0x80000000u);
}
__device__ __forceinline__ float key2f(unsigned k) {
    unsigned u = (k & 0x80000000u) ? (k & 0x7fffffffu) : ~k;
    return __uint_as_float(u);
}

// load 8 consecutive elements as 8 bf16 (uint4)
__device__ __forceinline__ uint4 load8(const u16* p) { return *(const uint4*)p; }
__device__ __forceinline__ uint4 load8(const float* p) {
    float4 f1 = *(const float4*)p;
    float4 f2 = *(const float4*)(p + 4);
    union { ushort s[8]; uint4 v; } u;
    u.s[0] = f2b(f1.x); u.s[1] = f2b(f1.y); u.s[2] = f2b(f1.z); u.s[3] = f2b(f1.w);
    u.s[4] = f2b(f2.x); u.s[5] = f2b(f2.y); u.s[6] = f2b(f2.z); u.s[7] = f2b(f2.w);
    return u.v;
}

// ---------- tiny precomputes (all-f32 inputs) ----------
__global__ void k_context(const float* __restrict__ focal, const float* __restrict__ Wseq,
                          const float* __restrict__ bseq, float* __restrict__ ctx) {
    int t = threadIdx.x;
    float acc = bseq[t];
    for (int d = 0; d < DD; ++d) acc = fmaf(focal[d], Wseq[d * HH + t], acc);
    ctx[t] = acc;
}

__global__ void k_c1(const float* __restrict__ ctx, const float* __restrict__ Wa1c,
                     const float* __restrict__ ba1, float* __restrict__ c1) {
    int t = threadIdx.x;
    float acc = ba1[t];
    for (int k = 0; k < HH; ++k) acc = fmaf(ctx[k], Wa1c[k * HH + t], acc);
    c1[t] = acc;
}

__global__ void k_tproj(const float* __restrict__ tt, const float* __restrict__ Wa1m,
                        float* __restrict__ tproj) {
    int ti = blockIdx.x, t = threadIdx.x;
    float acc = 0.f;
    for (int k = 0; k < HH; ++k)
        acc = fmaf(tt[ti * HH + k], Wa1m[k * HH + t], acc);
    tproj[(size_t)ti * HH + t] = acc;
}

// ============ MFMA GEMM: out_bf16[r,:] = in[r, 0:K] @ W[K,128] + b ============
// 128-row tiles, K staged in 64-chunks. a_lds/b_lds stride 72 (pad+8 bf16).
template <int K, typename InT>
__global__ __launch_bounds__(256) void k_mfma_proj(const InT* __restrict__ in,
                                                   const float* __restrict__ W,
                                                   const float* __restrict__ bias,
                                                   u16* __restrict__ out, int nrows) {
    __shared__ u16 a_lds[128 * 72];
    __shared__ u16 b_lds[128 * 72];
    const int t = threadIdx.x;
    const int tile_m = blockIdx.x * 128;
    const int wave = t >> 6, l = t & 15, quad = (t >> 4) & 3;
    const int wr = wave >> 1, wc = wave & 1;
    f32x4 acc[4][4] = {};

    for (int chunk = 0; chunk < K / 64; ++chunk) {
        const int c0 = chunk * 64;
        __syncthreads();
        // stage A: [row][k] k-contiguous
        for (int ci = t; ci < 1024; ci += 256) {
            int row = ci >> 3, kc = ci & 7;
            int grow = tile_m + row;
            uint4 v = make_uint4(0, 0, 0, 0);
            if (grow < nrows) v = load8(&in[(size_t)grow * K + c0 + kc * 8]);
            *(uint4*)&a_lds[row * 72 + kc * 8] = v;
        }
        // stage B transposed: b_lds[n][k] = W[k][n]
        for (int ci = t; ci < 1024; ci += 256) {
            int n = ci & 127, kc = ci >> 7;
            union { ushort s[8]; uint4 v; } u;
#pragma unroll
            for (int e = 0; e < 8; ++e)
                u.s[e] = f2b(W[(size_t)(c0 + kc * 8 + e) * HH + n]);
            *(uint4*)&b_lds[n * 72 + kc * 8] = u.v;
        }
        __syncthreads();
#pragma unroll
        for (int ks = 0; ks < 2; ++ks) {
            short8 af[4], bf[4];
#pragma unroll
            for (int i = 0; i < 4; ++i)
                af[i] = *(const short8*)&a_lds[(wr * 64 + i * 16 + l) * 72 + ks * 32 + quad * 8];
#pragma unroll
            for (int j = 0; j < 4; ++j)
                bf[j] = *(const short8*)&b_lds[(wc * 64 + j * 16 + l) * 72 + ks * 32 + quad * 8];
#pragma unroll
            for (int i = 0; i < 4; ++i)
#pragma unroll
                for (int j = 0; j < 4; ++j)
                    acc[i][j] = __builtin_amdgcn_mfma_f32_16x16x32_bf16(af[i], bf[j], acc[i][j], 0, 0, 0);
        }
    }
    // epilogue: C/D layout col=lane&15, row=quad*4+reg
#pragma unroll
    for (int j = 0; j < 4; ++j) {
        int col = wc * 64 + j * 16 + l;
        float b = bias[col];
#pragma unroll
        for (int i = 0; i < 4; ++i) {
            int rbase = tile_m + wr * 64 + i * 16 + quad * 4;
#pragma unroll
            for (int r = 0; r < 4; ++r) {
                int grow = rbase + r;
                if (grow < nrows) out[(size_t)grow * HH + col] = f2b(acc[i][j][r] + b);
            }
        }
    }
}

// ============ fused gathered GEMM: out_f32 = h[idx1]@W1 + h[idx2]@W2 + b ============
__global__ __launch_bounds__(256) void k_mfma_gproj(const u16* __restrict__ h,
                                                    const int* __restrict__ idx1,
                                                    const int* __restrict__ idx2,
                                                    const float* __restrict__ W1,
                                                    const float* __restrict__ W2,
                                                    const float* __restrict__ bias,
                                                    float* __restrict__ out, int nrows) {
    __shared__ u16 a_lds[128 * 72];
    __shared__ u16 b_lds[128 * 72];
    const int t = threadIdx.x;
    const int tile_m = blockIdx.x * 128;
    const int wave = t >> 6, l = t & 15, quad = (t >> 4) & 3;
    const int wr = wave >> 1, wc = wave & 1;
    f32x4 acc[4][4] = {};

    for (int pass = 0; pass < 2; ++pass) {
        const int* idx = pass ? idx2 : idx1;
        const float* W = pass ? W2 : W1;
        for (int chunk = 0; chunk < 2; ++chunk) {
            const int c0 = chunk * 64;
            __syncthreads();
            for (int ci = t; ci < 1024; ci += 256) {
                int row = ci >> 3, kc = ci & 7;
                int item = tile_m + row;
                int g = (item < nrows) ? idx[item] : -1;
                uint4 v = make_uint4(0, 0, 0, 0);
                if (g >= 0) v = load8(&h[(size_t)g * HH + c0 + kc * 8]);
                *(uint4*)&a_lds[row * 72 + kc * 8] = v;
            }
            for (int ci = t; ci < 1024; ci += 256) {
                int n = ci & 127, kc = ci >> 7;
                union { ushort s[8]; uint4 v; } u;
#pragma unroll
                for (int e = 0; e < 8; ++e)
                    u.s[e] = f2b(W[(size_t)(c0 + kc * 8 + e) * HH + n]);
                *(uint4*)&b_lds[n * 72 + kc * 8] = u.v;
            }
            __syncthreads();
#pragma unroll
            for (int ks = 0; ks < 2; ++ks) {
                short8 af[4], bf[4];
#pragma unroll
                for (int i = 0; i < 4; ++i)
                    af[i] = *(const short8*)&a_lds[(wr * 64 + i * 16 + l) * 72 + ks * 32 + quad * 8];
#pragma unroll
                for (int j = 0; j < 4; ++j)
                    bf[j] = *(const short8*)&b_lds[(wc * 64 + j * 16 + l) * 72 + ks * 32 + quad * 8];
#pragma unroll
                for (int i = 0; i < 4; ++i)
#pragma unroll
                    for (int j = 0; j < 4; ++j)
                        acc[i][j] = __builtin_amdgcn_mfma_f32_16x16x32_bf16(af[i], bf[j], acc[i][j], 0, 0, 0);
            }
        }
    }
#pragma unroll
    for (int j = 0; j < 4; ++j) {
        int col = wc * 64 + j * 16 + l;
        float b = bias[col];
#pragma unroll
        for (int i = 0; i < 4; ++i) {
            int rbase = tile_m + wr * 64 + i * 16 + quad * 4;
#pragma unroll
            for (int r = 0; r < 4; ++r) {
                int item = rbase + r;
                if (item < nrows) out[(size_t)item * HH + col] = acc[i][j][r] + b;
            }
        }
    }
}

// ---------- edge pass A: a[e] = leaky(xl[src]+xr[dst]) . att ; segment max ----------
__global__ __launch_bounds__(256) void k_edge_score(const u16* __restrict__ xl,
                                                    const u16* __restrict__ xr,
                                                    const int* __restrict__ src,
                                                    const int* __restrict__ dst,
                                                    const float* __restrict__ att,
                                                    float* __restrict__ a_e,
                                                    unsigned* __restrict__ amax) {
    __shared__ float att_l[HH];
    if (threadIdx.x < HH) att_l[threadIdx.x] = att[threadIdx.x];
    __syncthreads();
    int wid = blockIdx.x * 4 + (threadIdx.x >> 6);
    int lane = threadIdx.x & 63;
    if (wid >= EE) return;
    int s = src[wid], d = dst[wid];
    u32 pl = ((const u32*)xl)[(size_t)s * 64 + lane];
    u32 pr = ((const u32*)xr)[(size_t)d * 64 + lane];
    float e0 = bfb((u16)pl) + bfb((u16)pr);
    float e1 = bfb((u16)(pl >> 16)) + bfb((u16)(pr >> 16));
    e0 = e0 >= 0.f ? e0 : 0.2f * e0;
    e1 = e1 >= 0.f ? e1 : 0.2f * e1;
    float acc = fmaf(e0, att_l[2 * lane], e1 * att_l[2 * lane + 1]);
    for (int off = 32; off; off >>= 1) acc += __shfl_down(acc, off);
    if (lane == 0) {
        a_e[wid] = acc;
        atomicMax(&amax[d], f2key(acc));
    }
}

// ---------- edge pass B: ex = exp(a - amax[dst]); denom[dst] += ex ----------
__global__ __launch_bounds__(256) void k_edge_norm(float* __restrict__ a_e,
                                                   const int* __restrict__ dst,
                                                   const unsigned* __restrict__ amax,
                                                   float* __restrict__ denom) {
    int e = blockIdx.x * blockDim.x + threadIdx.x;
    if (e >= EE) return;
    int d = dst[e];
    float ex = __expf(a_e[e] - key2f(amax[d]));
    a_e[e] = ex;
    atomicAdd(&denom[d], ex);
}

// ---------- edge pass C (half of feature dim): agg[dst, half] += alpha * xl[src, half] ----------
__global__ __launch_bounds__(256) void k_edge_agg_half(const u16* __restrict__ xl,
                                                       const float* __restrict__ ex_e,
                                                       const int* __restrict__ src,
                                                       const int* __restrict__ dst,
                                                       const float* __restrict__ denom,
                                                       float* __restrict__ agg, int half) {
    int wid = blockIdx.x * 4 + (threadIdx.x >> 6);
    int lane = threadIdx.x & 63;
    if (wid >= EE) return;
    int s = src[wid], d = dst[wid];
    float alpha = ex_e[wid] / (denom[d] + 1e-16f);
    float v = bfb(xl[(size_t)s * HH + half * 64 + lane]);
    atomicAdd(&agg[(size_t)d * 64 + lane], alpha * v);
}

// ---------- h[:, half] += relu(agg + bias[half]) ----------
__global__ __launch_bounds__(256) void k_update_half(u16* __restrict__ h,
                                                     const float* __restrict__ agg,
                                                     const float* __restrict__ bias, int half) {
    size_t i = (size_t)blockIdx.x * 256 + threadIdx.x;  // over N*64
    if (i >= (size_t)NN * 64) return;
    int n = (int)(i >> 6), c = (int)(i & 63);
    int col = half * 64 + c;
    size_t hi = (size_t)n * HH + col;
    float hv = bfb(h[hi]);
    float av = agg[i] + bias[col];
    hv += fmaxf(av, 0.f);
    h[hi] = f2b(hv);
}

// ---------- fused z + logit (f32 output) ----------
__global__ __launch_bounds__(256) void k_zlogit(const float* __restrict__ branch,
                                                const int* __restrict__ time_idx,
                                                const float* __restrict__ tproj,
                                                const float* __restrict__ c1,
                                                const float* __restrict__ Wa1t,
                                                const float* __restrict__ Wa2,
                                                const float* __restrict__ ba2,
                                                float* __restrict__ out) {
    __shared__ u16 wlds[HH * HH];
    __shared__ float rows[2][HH];
    __shared__ float red[2][2];
    for (int i = threadIdx.x; i < HH * HH; i += 256) wlds[i] = f2b(Wa1t[i]);
    int t = threadIdx.x, half = t >> 7, col = t & 127;
    int lane = t & 63, wv = (t >> 6) & 1;
    float wa2c = Wa2[col];
    float ba2v = ba2[0];
    int npairs = (AA + 1) >> 1;
    for (int p = blockIdx.x; p < npairs; p += gridDim.x) {
        __syncthreads();
        {
            int it = 2 * p + half;
            rows[half][col] = (it < AA) ? branch[(size_t)it * HH + col] : 0.f;
        }
        __syncthreads();
        float acc = 0.f;
#pragma unroll 8
        for (int k = 0; k < HH; ++k)
            acc = fmaf(rows[half][k], bfb(wlds[k * HH + col]), acc);
        int item = 2 * p + half;
        float zv = 0.f;
        if (item < AA) {
            int ti = time_idx[item];
            zv = fmaxf(acc + tproj[(size_t)ti * HH + col] + c1[col], 0.f);
        }
        float partial = zv * wa2c;
        for (int off = 32; off; off >>= 1) partial += __shfl_down(partial, off);
        if (lane == 0) red[half][wv] = partial;
        __syncthreads();
        if (col == 0 && item < AA)
            out[item] = red[half][0] + red[half][1] + ba2v;
    }
}

// ---------- host side ----------
typedef const float* fp;

static void run_gat(u16* h, u16* xl, u16* xr, float* agg /*aliases xr*/,
                    float* a_e, unsigned* amax, float* denom,
                    const int* src, const int* dst,
                    fp Wl, fp bl, fp Wr, fp br, fp att, fp bias, hipStream_t stream) {
    const int NB = (NN + 127) / 128;
    hipMemsetAsync(amax, 0, (size_t)NN * 4, stream);
    hipMemsetAsync(denom, 0, (size_t)NN * 4, stream);
    k_mfma_proj<128, u16><<<NB, 256, 0, stream>>>(h, Wl, bl, xl, NN);
    k_mfma_proj<128, u16><<<NB, 256, 0, stream>>>(h, Wr, br, xr, NN);
    k_edge_score<<<(EE + 3) / 4, 256, 0, stream>>>(xl, xr, src, dst, att, a_e, amax);
    k_edge_norm<<<(EE + 255) / 256, 256, 0, stream>>>(a_e, dst, amax, denom);
    for (int half = 0; half < 2; ++half) {
        hipMemsetAsync(agg, 0, (size_t)NN * 64 * 4, stream);  // xr dead after score
        k_edge_agg_half<<<(EE + 3) / 4, 256, 0, stream>>>(xl, a_e, src, dst, denom, agg, half);
        k_update_half<<<((NN * 64) + 255) / 256, 256, 0, stream>>>(h, agg, bias, half);
    }
}

extern "C" void kernel_launch(void* const* d_in, const int* in_sizes, int n_in,
                              void* d_out, int out_size, void* d_ws, size_t ws_size,
                              hipStream_t stream) {
    fp x                 = (fp)d_in[0];
    const int* ei        = (const int*)d_in[1];
    fp focal             = (fp)d_in[2];
    const int* child_idx = (const int*)d_in[3];
    const int* parent_idx= (const int*)d_in[4];
    const int* time_idx  = (const int*)d_in[5];
    fp W_embed = (fp)d_in[6],  b_embed = (fp)d_in[7];
    fp bu_Wl   = (fp)d_in[8],  bu_bl   = (fp)d_in[9];
    fp bu_Wr   = (fp)d_in[10], bu_br   = (fp)d_in[11];
    fp bu_att  = (fp)d_in[12], bu_bias = (fp)d_in[13];
    fp td_Wl   = (fp)d_in[14], td_bl   = (fp)d_in[15];
    fp td_Wr   = (fp)d_in[16], td_br   = (fp)d_in[17];
    fp td_att  = (fp)d_in[18], td_bias = (fp)d_in[19];
    fp time_table = (fp)d_in[20];
    fp W_comb  = (fp)d_in[21], b_comb  = (fp)d_in[22];
    fp W_a1    = (fp)d_in[23], b_a1    = (fp)d_in[24];
    fp W_a2    = (fp)d_in[25], b_a2    = (fp)d_in[26];
    fp W_seq   = (fp)d_in[27], b_seq   = (fp)d_in[28];

    const size_t NH = (size_t)NN * HH;
    u16* h  = (u16*)d_ws;                 // N*H bf16           (76.8 MB)
    u16* xl = h + NH;                     // N*H bf16           (76.8 MB)
    u16* xr = xl + NH;                    // N*H bf16           (76.8 MB)
    float* agg = (float*)xr;              // N*64 f32, aliases xr (dead after score)
    float* branch = (float*)xl;           // A*H f32, aliases xl (dead after GATs)
    float* a_e   = (float*)(xr + NH);     // E
    unsigned* amax = (unsigned*)(a_e + EE);  // N
    float* denom = (float*)(amax + NN);   // N
    float* ctx   = denom + NN;            // H
    float* c1v   = ctx + HH;              // H
    float* tproj = c1v + HH;              // T*H

    // small precomputes (independent of h)
    k_context<<<1, 128, 0, stream>>>(focal, W_seq, b_seq, ctx);
    k_c1<<<1, 128, 0, stream>>>(ctx, W_a1 + (size_t)256 * HH, b_a1, c1v);
    k_tproj<<<TT, 128, 0, stream>>>(time_table, W_a1 + (size_t)128 * HH, tproj);

    const int NB = (NN + 127) / 128;
    // embed: h = x @ W_embed + b_embed  (MFMA, K=64, f32 input)
    k_mfma_proj<64, float><<<NB, 256, 0, stream>>>(x, W_embed, b_embed, h, NN);

    // bottom-up GAT: src = edge_index[1], dst = edge_index[0]
    run_gat(h, xl, xr, agg, a_e, amax, denom, ei + EE, ei,
            bu_Wl, bu_bl, bu_Wr, bu_br, bu_att, bu_bias, stream);
    // top-down GAT: src = edge_index[0], dst = edge_index[1]
    run_gat(h, xl, xr, agg, a_e, amax, denom, ei, ei + EE,
            td_Wl, td_bl, td_Wr, td_br, td_att, td_bias, stream);

    // branch = h[child]@Wc + h[parent]@Wp + b_comb  (fused, f32 out over xl)
    k_mfma_gproj<<<(AA + 127) / 128, 256, 0, stream>>>(
        h, child_idx, parent_idx, W_comb, W_comb + (size_t)HH * HH, b_comb, branch, AA);

    // logits = relu(branch@Wa1_top + tproj[tidx] + c1) @ W_a2 + b_a2
    k_zlogit<<<1024, 256, 0, stream>>>(branch, time_idx, tproj, c1v,
                                       W_a1, W_a2, b_a2, (float*)d_out);
}

// Round 5
// 1285.142 us; speedup vs baseline: 2.9858x; 1.1997x over previous
//
#include <hip/hip_runtime.h>
#include <hip/hip_bf16.h>

#define NN 300000
#define EE 299999
#define AA 150000
#define DD 64
#define HH 128
#define TT 512

typedef unsigned short u16;
typedef unsigned int u32;
typedef __attribute__((ext_vector_type(8))) short short8;
typedef __attribute__((ext_vector_type(4))) float f32x4;

// ---------- helpers ----------
__device__ __forceinline__ float bfb(u16 u) { return __uint_as_float(((u32)u) << 16); }
__device__ __forceinline__ u16 f2b(float f) {
    u32 u = __float_as_uint(f);
    u32 r = (u + 0x7FFFu + ((u >> 16) & 1u)) >> 16;
    return (u16)r;
}
__device__ __forceinline__ unsigned f2key(float f) {
    unsigned u = __float_as_uint(f);
    return (u & 0x80000000u) ? ~u : (u | 0x80000000u);
}
__device__ __forceinline__ float key2f(unsigned k) {
    unsigned u = (k & 0x80000000u) ? (k & 0x7fffffffu) : ~k;
    return __uint_as_float(u);
}

// load 8 consecutive elements as 8 bf16 (uint4)
__device__ __forceinline__ uint4 load8(const u16* p) { return *(const uint4*)p; }
__device__ __forceinline__ uint4 load8(const float* p) {
    float4 f1 = *(const float4*)p;
    float4 f2 = *(const float4*)(p + 4);
    union { ushort s[8]; uint4 v; } u;
    u.s[0] = f2b(f1.x); u.s[1] = f2b(f1.y); u.s[2] = f2b(f1.z); u.s[3] = f2b(f1.w);
    u.s[4] = f2b(f2.x); u.s[5] = f2b(f2.y); u.s[6] = f2b(f2.z); u.s[7] = f2b(f2.w);
    return u.v;
}

// ---------- tiny precomputes (all-f32 inputs) ----------
__global__ void k_context(const float* __restrict__ focal, const float* __restrict__ Wseq,
                          const float* __restrict__ bseq, float* __restrict__ ctx) {
    int t = threadIdx.x;
    float acc = bseq[t];
    for (int d = 0; d < DD; ++d) acc = fmaf(focal[d], Wseq[d * HH + t], acc);
    ctx[t] = acc;
}

__global__ void k_c1(const float* __restrict__ ctx, const float* __restrict__ Wa1c,
                     const float* __restrict__ ba1, float* __restrict__ c1) {
    int t = threadIdx.x;
    float acc = ba1[t];
    for (int k = 0; k < HH; ++k) acc = fmaf(ctx[k], Wa1c[k * HH + t], acc);
    c1[t] = acc;
}

__global__ void k_tproj(const float* __restrict__ tt, const float* __restrict__ Wa1m,
                        float* __restrict__ tproj) {
    int ti = blockIdx.x, t = threadIdx.x;
    float acc = 0.f;
    for (int k = 0; k < HH; ++k)
        acc = fmaf(tt[ti * HH + k], Wa1m[k * HH + t], acc);
    tproj[(size_t)ti * HH + t] = acc;
}

// ============ MFMA GEMM: out_bf16[r,:] = in[r, 0:K] @ W[K,128] + b ============
template <int K, typename InT>
__global__ __launch_bounds__(256) void k_mfma_proj(const InT* __restrict__ in,
                                                   const float* __restrict__ W,
                                                   const float* __restrict__ bias,
                                                   u16* __restrict__ out, int nrows) {
    __shared__ u16 a_lds[128 * 72];
    __shared__ u16 b_lds[128 * 72];
    const int t = threadIdx.x;
    const int tile_m = blockIdx.x * 128;
    const int wave = t >> 6, l = t & 15, quad = (t >> 4) & 3;
    const int wr = wave >> 1, wc = wave & 1;
    f32x4 acc[4][4] = {};

    for (int chunk = 0; chunk < K / 64; ++chunk) {
        const int c0 = chunk * 64;
        __syncthreads();
        for (int ci = t; ci < 1024; ci += 256) {
            int row = ci >> 3, kc = ci & 7;
            int grow = tile_m + row;
            uint4 v = make_uint4(0, 0, 0, 0);
            if (grow < nrows) v = load8(&in[(size_t)grow * K + c0 + kc * 8]);
            *(uint4*)&a_lds[row * 72 + kc * 8] = v;
        }
        for (int ci = t; ci < 1024; ci += 256) {
            int n = ci & 127, kc = ci >> 7;
            union { ushort s[8]; uint4 v; } u;
#pragma unroll
            for (int e = 0; e < 8; ++e)
                u.s[e] = f2b(W[(size_t)(c0 + kc * 8 + e) * HH + n]);
            *(uint4*)&b_lds[n * 72 + kc * 8] = u.v;
        }
        __syncthreads();
#pragma unroll
        for (int ks = 0; ks < 2; ++ks) {
            short8 af[4], bf[4];
#pragma unroll
            for (int i = 0; i < 4; ++i)
                af[i] = *(const short8*)&a_lds[(wr * 64 + i * 16 + l) * 72 + ks * 32 + quad * 8];
#pragma unroll
            for (int j = 0; j < 4; ++j)
                bf[j] = *(const short8*)&b_lds[(wc * 64 + j * 16 + l) * 72 + ks * 32 + quad * 8];
#pragma unroll
            for (int i = 0; i < 4; ++i)
#pragma unroll
                for (int j = 0; j < 4; ++j)
                    acc[i][j] = __builtin_amdgcn_mfma_f32_16x16x32_bf16(af[i], bf[j], acc[i][j], 0, 0, 0);
        }
    }
#pragma unroll
    for (int j = 0; j < 4; ++j) {
        int col = wc * 64 + j * 16 + l;
        float b = bias[col];
#pragma unroll
        for (int i = 0; i < 4; ++i) {
            int rbase = tile_m + wr * 64 + i * 16 + quad * 4;
#pragma unroll
            for (int r = 0; r < 4; ++r) {
                int grow = rbase + r;
                if (grow < nrows) out[(size_t)grow * HH + col] = f2b(acc[i][j][r] + b);
            }
        }
    }
}

// ============ fused gathered GEMM: out_f32 = h[idx1]@W1 + h[idx2]@W2 + b ============
__global__ __launch_bounds__(256) void k_mfma_gproj(const u16* __restrict__ h,
                                                    const int* __restrict__ idx1,
                                                    const int* __restrict__ idx2,
                                                    const float* __restrict__ W1,
                                                    const float* __restrict__ W2,
                                                    const float* __restrict__ bias,
                                                    float* __restrict__ out, int nrows) {
    __shared__ u16 a_lds[128 * 72];
    __shared__ u16 b_lds[128 * 72];
    const int t = threadIdx.x;
    const int tile_m = blockIdx.x * 128;
    const int wave = t >> 6, l = t & 15, quad = (t >> 4) & 3;
    const int wr = wave >> 1, wc = wave & 1;
    f32x4 acc[4][4] = {};

    for (int pass = 0; pass < 2; ++pass) {
        const int* idx = pass ? idx2 : idx1;
        const float* W = pass ? W2 : W1;
        for (int chunk = 0; chunk < 2; ++chunk) {
            const int c0 = chunk * 64;
            __syncthreads();
            for (int ci = t; ci < 1024; ci += 256) {
                int row = ci >> 3, kc = ci & 7;
                int item = tile_m + row;
                int g = (item < nrows) ? idx[item] : -1;
                uint4 v = make_uint4(0, 0, 0, 0);
                if (g >= 0) v = load8(&h[(size_t)g * HH + c0 + kc * 8]);
                *(uint4*)&a_lds[row * 72 + kc * 8] = v;
            }
            for (int ci = t; ci < 1024; ci += 256) {
                int n = ci & 127, kc = ci >> 7;
                union { ushort s[8]; uint4 v; } u;
#pragma unroll
                for (int e = 0; e < 8; ++e)
                    u.s[e] = f2b(W[(size_t)(c0 + kc * 8 + e) * HH + n]);
                *(uint4*)&b_lds[n * 72 + kc * 8] = u.v;
            }
            __syncthreads();
#pragma unroll
            for (int ks = 0; ks < 2; ++ks) {
                short8 af[4], bf[4];
#pragma unroll
                for (int i = 0; i < 4; ++i)
                    af[i] = *(const short8*)&a_lds[(wr * 64 + i * 16 + l) * 72 + ks * 32 + quad * 8];
#pragma unroll
                for (int j = 0; j < 4; ++j)
                    bf[j] = *(const short8*)&b_lds[(wc * 64 + j * 16 + l) * 72 + ks * 32 + quad * 8];
#pragma unroll
                for (int i = 0; i < 4; ++i)
#pragma unroll
                    for (int j = 0; j < 4; ++j)
                        acc[i][j] = __builtin_amdgcn_mfma_f32_16x16x32_bf16(af[i], bf[j], acc[i][j], 0, 0, 0);
            }
        }
    }
#pragma unroll
    for (int j = 0; j < 4; ++j) {
        int col = wc * 64 + j * 16 + l;
        float b = bias[col];
#pragma unroll
        for (int i = 0; i < 4; ++i) {
            int rbase = tile_m + wr * 64 + i * 16 + quad * 4;
#pragma unroll
            for (int r = 0; r < 4; ++r) {
                int item = rbase + r;
                if (item < nrows) out[(size_t)item * HH + col] = acc[i][j][r] + b;
            }
        }
    }
}

// ============ MFMA z+logit: out[i] = relu(branch[i]@Wa1t + tproj[ti]+c1) . Wa2 + ba2 ============
__global__ __launch_bounds__(256) void k_mfma_zlogit(const float* __restrict__ branch,
                                                     const int* __restrict__ time_idx,
                                                     const float* __restrict__ tproj,
                                                     const float* __restrict__ c1,
                                                     const float* __restrict__ Wa1t,
                                                     const float* __restrict__ Wa2,
                                                     const float* __restrict__ ba2,
                                                     float* __restrict__ out) {
    __shared__ u16 a_lds[128 * 72];
    __shared__ u16 b_lds[128 * 72];
    __shared__ float red[2][128];
    const int t = threadIdx.x;
    const int tile_m = blockIdx.x * 128;
    const int wave = t >> 6, l = t & 15, quad = (t >> 4) & 3;
    const int wr = wave >> 1, wc = wave & 1;
    f32x4 acc[4][4] = {};

    for (int chunk = 0; chunk < 2; ++chunk) {
        const int c0 = chunk * 64;
        __syncthreads();
        for (int ci = t; ci < 1024; ci += 256) {
            int row = ci >> 3, kc = ci & 7;
            int item = tile_m + row;
            uint4 v = make_uint4(0, 0, 0, 0);
            if (item < AA) v = load8(&branch[(size_t)item * HH + c0 + kc * 8]);
            *(uint4*)&a_lds[row * 72 + kc * 8] = v;
        }
        for (int ci = t; ci < 1024; ci += 256) {
            int n = ci & 127, kc = ci >> 7;
            union { ushort s[8]; uint4 v; } u;
#pragma unroll
            for (int e = 0; e < 8; ++e)
                u.s[e] = f2b(Wa1t[(size_t)(c0 + kc * 8 + e) * HH + n]);
            *(uint4*)&b_lds[n * 72 + kc * 8] = u.v;
        }
        __syncthreads();
#pragma unroll
        for (int ks = 0; ks < 2; ++ks) {
            short8 af[4], bf[4];
#pragma unroll
            for (int i = 0; i < 4; ++i)
                af[i] = *(const short8*)&a_lds[(wr * 64 + i * 16 + l) * 72 + ks * 32 + quad * 8];
#pragma unroll
            for (int j = 0; j < 4; ++j)
                bf[j] = *(const short8*)&b_lds[(wc * 64 + j * 16 + l) * 72 + ks * 32 + quad * 8];
#pragma unroll
            for (int i = 0; i < 4; ++i)
#pragma unroll
                for (int j = 0; j < 4; ++j)
                    acc[i][j] = __builtin_amdgcn_mfma_f32_16x16x32_bf16(af[i], bf[j], acc[i][j], 0, 0, 0);
        }
    }
    // epilogue: z = relu(acc + tproj[ti][col] + c1[col]); partial = z . Wa2
    float c1v[4], wa2v[4];
#pragma unroll
    for (int j = 0; j < 4; ++j) {
        int col = wc * 64 + j * 16 + l;
        c1v[j] = c1[col];
        wa2v[j] = Wa2[col];
    }
#pragma unroll
    for (int i = 0; i < 4; ++i) {
        int rbase = tile_m + wr * 64 + i * 16 + quad * 4;
#pragma unroll
        for (int r = 0; r < 4; ++r) {
            int item = rbase + r;
            int ti = (item < AA) ? time_idx[item] : 0;
            const float* tp = tproj + (size_t)ti * HH;
            float partial = 0.f;
#pragma unroll
            for (int j = 0; j < 4; ++j) {
                int col = wc * 64 + j * 16 + l;
                float z = fmaxf(acc[i][j][r] + tp[col] + c1v[j], 0.f);
                partial = fmaf(z, wa2v[j], partial);
            }
            // reduce over l (16 lanes within the quad group)
            partial += __shfl_xor(partial, 1);
            partial += __shfl_xor(partial, 2);
            partial += __shfl_xor(partial, 4);
            partial += __shfl_xor(partial, 8);
            if (l == 0) red[wc][wr * 64 + i * 16 + quad * 4 + r] = partial;
        }
    }
    __syncthreads();
    if (t < 128) {
        int item = tile_m + t;
        if (item < AA) out[item] = red[0][t] + red[1][t] + ba2[0];
    }
}

// ---------- edge pass A: a[e] = leaky(xl[src]+xr[dst]) . att ; segment max ----------
__global__ __launch_bounds__(256) void k_edge_score(const u16* __restrict__ xl,
                                                    const u16* __restrict__ xr,
                                                    const int* __restrict__ src,
                                                    const int* __restrict__ dst,
                                                    const float* __restrict__ att,
                                                    float* __restrict__ a_e,
                                                    unsigned* __restrict__ amax) {
    __shared__ float att_l[HH];
    if (threadIdx.x < HH) att_l[threadIdx.x] = att[threadIdx.x];
    __syncthreads();
    int wid = blockIdx.x * 4 + (threadIdx.x >> 6);
    int lane = threadIdx.x & 63;
    if (wid >= EE) return;
    int s = src[wid], d = dst[wid];
    u32 pl = ((const u32*)xl)[(size_t)s * 64 + lane];
    u32 pr = ((const u32*)xr)[(size_t)d * 64 + lane];
    float e0 = bfb((u16)pl) + bfb((u16)pr);
    float e1 = bfb((u16)(pl >> 16)) + bfb((u16)(pr >> 16));
    e0 = e0 >= 0.f ? e0 : 0.2f * e0;
    e1 = e1 >= 0.f ? e1 : 0.2f * e1;
    float acc = fmaf(e0, att_l[2 * lane], e1 * att_l[2 * lane + 1]);
    for (int off = 32; off; off >>= 1) acc += __shfl_down(acc, off);
    if (lane == 0) {
        a_e[wid] = acc;
        atomicMax(&amax[d], f2key(acc));
    }
}

// ---------- edge pass B: ex = exp(a - amax[dst]); denom[dst] += ex ----------
__global__ __launch_bounds__(256) void k_edge_norm(float* __restrict__ a_e,
                                                   const int* __restrict__ dst,
                                                   const unsigned* __restrict__ amax,
                                                   float* __restrict__ denom) {
    int e = blockIdx.x * blockDim.x + threadIdx.x;
    if (e >= EE) return;
    int d = dst[e];
    float ex = __expf(a_e[e] - key2f(amax[d]));
    a_e[e] = ex;
    atomicAdd(&denom[d], ex);
}

// ---------- edge pass C (half of feature dim): agg[dst, half] += alpha * xl[src, half] ----------
__global__ __launch_bounds__(256) void k_edge_agg_half(const u16* __restrict__ xl,
                                                       const float* __restrict__ ex_e,
                                                       const int* __restrict__ src,
                                                       const int* __restrict__ dst,
                                                       const float* __restrict__ denom,
                                                       float* __restrict__ agg, int half) {
    int wid = blockIdx.x * 4 + (threadIdx.x >> 6);
    int lane = threadIdx.x & 63;
    if (wid >= EE) return;
    int s = src[wid], d = dst[wid];
    float alpha = ex_e[wid] / (denom[d] + 1e-16f);
    float v = bfb(xl[(size_t)s * HH + half * 64 + lane]);
    atomicAdd(&agg[(size_t)d * 64 + lane], alpha * v);
}

// ---------- h[:, half] += relu(agg + bias[half]) ----------
__global__ __launch_bounds__(256) void k_update_half(u16* __restrict__ h,
                                                     const float* __restrict__ agg,
                                                     const float* __restrict__ bias, int half) {
    size_t i = (size_t)blockIdx.x * 256 + threadIdx.x;  // over N*64
    if (i >= (size_t)NN * 64) return;
    int n = (int)(i >> 6), c = (int)(i & 63);
    int col = half * 64 + c;
    size_t hi = (size_t)n * HH + col;
    float hv = bfb(h[hi]);
    float av = agg[i] + bias[col];
    hv += fmaxf(av, 0.f);
    h[hi] = f2b(hv);
}

// ---------- host side ----------
typedef const float* fp;

static void run_gat(u16* h, u16* xl, u16* xr, float* agg /*aliases xr*/,
                    float* a_e, unsigned* amax, float* denom,
                    const int* src, const int* dst,
                    fp Wl, fp bl, fp Wr, fp br, fp att, fp bias, hipStream_t stream) {
    const int NB = (NN + 127) / 128;
    hipMemsetAsync(amax, 0, (size_t)NN * 4, stream);
    hipMemsetAsync(denom, 0, (size_t)NN * 4, stream);
    k_mfma_proj<128, u16><<<NB, 256, 0, stream>>>(h, Wl, bl, xl, NN);
    k_mfma_proj<128, u16><<<NB, 256, 0, stream>>>(h, Wr, br, xr, NN);
    k_edge_score<<<(EE + 3) / 4, 256, 0, stream>>>(xl, xr, src, dst, att, a_e, amax);
    k_edge_norm<<<(EE + 255) / 256, 256, 0, stream>>>(a_e, dst, amax, denom);
    for (int half = 0; half < 2; ++half) {
        hipMemsetAsync(agg, 0, (size_t)NN * 64 * 4, stream);  // xr dead after score
        k_edge_agg_half<<<(EE + 3) / 4, 256, 0, stream>>>(xl, a_e, src, dst, denom, agg, half);
        k_update_half<<<((NN * 64) + 255) / 256, 256, 0, stream>>>(h, agg, bias, half);
    }
}

extern "C" void kernel_launch(void* const* d_in, const int* in_sizes, int n_in,
                              void* d_out, int out_size, void* d_ws, size_t ws_size,
                              hipStream_t stream) {
    fp x                 = (fp)d_in[0];
    const int* ei        = (const int*)d_in[1];
    fp focal             = (fp)d_in[2];
    const int* child_idx = (const int*)d_in[3];
    const int* parent_idx= (const int*)d_in[4];
    const int* time_idx  = (const int*)d_in[5];
    fp W_embed = (fp)d_in[6],  b_embed = (fp)d_in[7];
    fp bu_Wl   = (fp)d_in[8],  bu_bl   = (fp)d_in[9];
    fp bu_Wr   = (fp)d_in[10], bu_br   = (fp)d_in[11];
    fp bu_att  = (fp)d_in[12], bu_bias = (fp)d_in[13];
    fp td_Wl   = (fp)d_in[14], td_bl   = (fp)d_in[15];
    fp td_Wr   = (fp)d_in[16], td_br   = (fp)d_in[17];
    fp td_att  = (fp)d_in[18], td_bias = (fp)d_in[19];
    fp time_table = (fp)d_in[20];
    fp W_comb  = (fp)d_in[21], b_comb  = (fp)d_in[22];
    fp W_a1    = (fp)d_in[23], b_a1    = (fp)d_in[24];
    fp W_a2    = (fp)d_in[25], b_a2    = (fp)d_in[26];
    fp W_seq   = (fp)d_in[27], b_seq   = (fp)d_in[28];

    const size_t NH = (size_t)NN * HH;
    u16* h  = (u16*)d_ws;                 // N*H bf16           (76.8 MB)
    u16* xl = h + NH;                     // N*H bf16           (76.8 MB)
    u16* xr = xl + NH;                    // N*H bf16           (76.8 MB)
    float* agg = (float*)xr;              // N*64 f32, aliases xr (dead after score)
    float* branch = (float*)xl;           // A*H f32, aliases xl (dead after GATs)
    float* a_e   = (float*)(xr + NH);     // E
    unsigned* amax = (unsigned*)(a_e + EE);  // N
    float* denom = (float*)(amax + NN);   // N
    float* ctx   = denom + NN;            // H
    float* c1v   = ctx + HH;              // H
    float* tproj = c1v + HH;              // T*H

    // small precomputes (independent of h)
    k_context<<<1, 128, 0, stream>>>(focal, W_seq, b_seq, ctx);
    k_c1<<<1, 128, 0, stream>>>(ctx, W_a1 + (size_t)256 * HH, b_a1, c1v);
    k_tproj<<<TT, 128, 0, stream>>>(time_table, W_a1 + (size_t)128 * HH, tproj);

    const int NB = (NN + 127) / 128;
    // embed: h = x @ W_embed + b_embed  (MFMA, K=64, f32 input)
    k_mfma_proj<64, float><<<NB, 256, 0, stream>>>(x, W_embed, b_embed, h, NN);

    // bottom-up GAT: src = edge_index[1], dst = edge_index[0]
    run_gat(h, xl, xr, agg, a_e, amax, denom, ei + EE, ei,
            bu_Wl, bu_bl, bu_Wr, bu_br, bu_att, bu_bias, stream);
    // top-down GAT: src = edge_index[0], dst = edge_index[1]
    run_gat(h, xl, xr, agg, a_e, amax, denom, ei, ei + EE,
            td_Wl, td_bl, td_Wr, td_br, td_att, td_bias, stream);

    // branch = h[child]@Wc + h[parent]@Wp + b_comb  (fused, f32 out over xl)
    k_mfma_gproj<<<(AA + 127) / 128, 256, 0, stream>>>(
        h, child_idx, parent_idx, W_comb, W_comb + (size_t)HH * HH, b_comb, branch, AA);

    // logits = relu(branch@Wa1_top + tproj[tidx] + c1) @ W_a2 + b_a2  (MFMA fused)
    k_mfma_zlogit<<<(AA + 127) / 128, 256, 0, stream>>>(
        branch, time_idx, tproj, c1v, W_a1, W_a2, b_a2, (float*)d_out);
}

// Round 6
// 1082.654 us; speedup vs baseline: 3.5442x; 1.1870x over previous
//
#include <hip/hip_runtime.h>
#include <hip/hip_bf16.h>

#define NN 300000
#define EE 299999
#define AA 150000
#define DD 64
#define HH 128
#define TT 512

typedef unsigned short u16;
typedef unsigned int u32;
typedef __attribute__((ext_vector_type(8))) short short8;
typedef __attribute__((ext_vector_type(4))) float f32x4;

// ---------- helpers ----------
__device__ __forceinline__ float bfb(u16 u) { return __uint_as_float(((u32)u) << 16); }
__device__ __forceinline__ u16 f2b(float f) {
    u32 u = __float_as_uint(f);
    u32 r = (u + 0x7FFFu + ((u >> 16) & 1u)) >> 16;
    return (u16)r;
}
__device__ __forceinline__ unsigned f2key(float f) {
    unsigned u = __float_as_uint(f);
    return (u & 0x80000000u) ? ~u : (u | 0x80000000u);
}
__device__ __forceinline__ float key2f(unsigned k) {
    unsigned u = (k & 0x80000000u) ? (k & 0x7fffffffu) : ~k;
    return __uint_as_float(u);
}

__device__ __forceinline__ uint4 load8(const u16* p) { return *(const uint4*)p; }
__device__ __forceinline__ uint4 load8(const float* p) {
    float4 f1 = *(const float4*)p;
    float4 f2 = *(const float4*)(p + 4);
    union { ushort s[8]; uint4 v; } u;
    u.s[0] = f2b(f1.x); u.s[1] = f2b(f1.y); u.s[2] = f2b(f1.z); u.s[3] = f2b(f1.w);
    u.s[4] = f2b(f2.x); u.s[5] = f2b(f2.y); u.s[6] = f2b(f2.z); u.s[7] = f2b(f2.w);
    return u.v;
}

// ---------- weight pre-transpose: WT[n][k] = bf16(W[k][n]) ----------
// slots 0..6: K=128 (bu_Wl,bu_Wr,td_Wl,td_Wr,Wcomb_c,Wcomb_p,Wa1_top), slot 7: K=64 (W_embed)
__global__ __launch_bounds__(256) void k_wtrans(const float* w0, const float* w1,
                                                const float* w2, const float* w3,
                                                const float* w4, const float* w5,
                                                const float* w6, const float* w7,
                                                u16* __restrict__ wt) {
    int widx = blockIdx.x >> 3, part = blockIdx.x & 7;
    const float* W; int K = 128;
    switch (widx) {
        case 0: W = w0; break; case 1: W = w1; break;
        case 2: W = w2; break; case 3: W = w3; break;
        case 4: W = w4; break; case 5: W = w5; break;
        case 6: W = w6; break; default: W = w7; K = 64; break;
    }
    u16* dst = wt + widx * 16384;
    int total = K * 128;
    int lo = part * 2048, hi = lo + 2048;
    if (hi > total) hi = total;
    for (int idx = lo + threadIdx.x; idx < hi; idx += 256) {
        int k = idx >> 7, n = idx & 127;
        dst[n * K + k] = f2b(W[k * 128 + n]);
    }
}

// ---------- tiny precomputes ----------
__global__ void k_context(const float* __restrict__ focal, const float* __restrict__ Wseq,
                          const float* __restrict__ bseq, float* __restrict__ ctx) {
    int t = threadIdx.x;
    float acc = bseq[t];
    for (int d = 0; d < DD; ++d) acc = fmaf(focal[d], Wseq[d * HH + t], acc);
    ctx[t] = acc;
}

__global__ void k_c1(const float* __restrict__ ctx, const float* __restrict__ Wa1c,
                     const float* __restrict__ ba1, float* __restrict__ c1) {
    int t = threadIdx.x;
    float acc = ba1[t];
    for (int k = 0; k < HH; ++k) acc = fmaf(ctx[k], Wa1c[k * HH + t], acc);
    c1[t] = acc;
}

__global__ void k_tproj(const float* __restrict__ tt, const float* __restrict__ Wa1m,
                        float* __restrict__ tproj) {
    int ti = blockIdx.x, t = threadIdx.x;
    float acc = 0.f;
    for (int k = 0; k < HH; ++k)
        acc = fmaf(tt[ti * HH + k], Wa1m[k * HH + t], acc);
    tproj[(size_t)ti * HH + t] = acc;
}

// ============ MFMA GEMM: out_bf16[r,:] = in[r,0:K] @ W[K,128] + b, WT pre-transposed bf16 ============
template <int K, typename InT>
__global__ __launch_bounds__(256) void k_mfma_proj(const InT* __restrict__ in,
                                                   const u16* __restrict__ WT,
                                                   const float* __restrict__ bias,
                                                   u16* __restrict__ out, int nrows) {
    __shared__ u16 lds[2][128 * 72];   // a=lds[0], b=lds[1]; C-repack reuses both (128*136)
    u16* a_lds = lds[0];
    u16* b_lds = lds[1];
    u16* clds = lds[0];
    const int t = threadIdx.x;
    const int tile_m = blockIdx.x * 128;
    const int wave = t >> 6, l = t & 15, quad = (t >> 4) & 3;
    const int wr = wave >> 1, wc = wave & 1;
    f32x4 acc[4][4] = {};

    for (int chunk = 0; chunk < K / 64; ++chunk) {
        const int c0 = chunk * 64;
        __syncthreads();
        for (int ci = t; ci < 1024; ci += 256) {
            int row = ci >> 3, kc = ci & 7;
            int grow = tile_m + row;
            uint4 v = make_uint4(0, 0, 0, 0);
            if (grow < nrows) v = load8(&in[(size_t)grow * K + c0 + kc * 8]);
            *(uint4*)&a_lds[row * 72 + kc * 8] = v;
        }
        for (int ci = t; ci < 1024; ci += 256) {
            int n = ci >> 3, kc = ci & 7;
            *(uint4*)&b_lds[n * 72 + kc * 8] = *(const uint4*)&WT[(size_t)n * K + c0 + kc * 8];
        }
        __syncthreads();
#pragma unroll
        for (int ks = 0; ks < 2; ++ks) {
            short8 af[4], bf[4];
#pragma unroll
            for (int i = 0; i < 4; ++i)
                af[i] = *(const short8*)&a_lds[(wr * 64 + i * 16 + l) * 72 + ks * 32 + quad * 8];
#pragma unroll
            for (int j = 0; j < 4; ++j)
                bf[j] = *(const short8*)&b_lds[(wc * 64 + j * 16 + l) * 72 + ks * 32 + quad * 8];
#pragma unroll
            for (int i = 0; i < 4; ++i)
#pragma unroll
                for (int j = 0; j < 4; ++j)
                    acc[i][j] = __builtin_amdgcn_mfma_f32_16x16x32_bf16(af[i], bf[j], acc[i][j], 0, 0, 0);
        }
    }
    // ---- coalesced epilogue: repack C through LDS, store uint4 ----
    __syncthreads();
#pragma unroll
    for (int j = 0; j < 4; ++j) {
        int col = wc * 64 + j * 16 + l;
        float b = bias[col];
#pragma unroll
        for (int i = 0; i < 4; ++i) {
            int rloc = wr * 64 + i * 16 + quad * 4;
#pragma unroll
            for (int r = 0; r < 4; ++r)
                clds[(rloc + r) * 136 + col] = f2b(acc[i][j][r] + b);
        }
    }
    __syncthreads();
#pragma unroll
    for (int it = 0; it < 8; ++it) {
        int idx = it * 256 + t;           // 2048 uint4 = 128 rows x 16 chunks
        int row = idx >> 4, c16 = idx & 15;
        int grow = tile_m + row;
        if (grow < nrows)
            *(uint4*)&out[(size_t)grow * HH + c16 * 8] = *(const uint4*)&clds[row * 136 + c16 * 8];
    }
}

// ============ fused gathered GEMM: out_bf16 = h[idx1]@W1 + h[idx2]@W2 + b ============
__global__ __launch_bounds__(256) void k_mfma_gproj(const u16* __restrict__ h,
                                                    const int* __restrict__ idx1,
                                                    const int* __restrict__ idx2,
                                                    const u16* __restrict__ WT1,
                                                    const u16* __restrict__ WT2,
                                                    const float* __restrict__ bias,
                                                    u16* __restrict__ out, int nrows) {
    __shared__ u16 lds[2][128 * 72];
    u16* a_lds = lds[0];
    u16* b_lds = lds[1];
    u16* clds = lds[0];
    const int t = threadIdx.x;
    const int tile_m = blockIdx.x * 128;
    const int wave = t >> 6, l = t & 15, quad = (t >> 4) & 3;
    const int wr = wave >> 1, wc = wave & 1;
    f32x4 acc[4][4] = {};

    for (int pass = 0; pass < 2; ++pass) {
        const int* idx = pass ? idx2 : idx1;
        const u16* WT = pass ? WT2 : WT1;
        for (int chunk = 0; chunk < 2; ++chunk) {
            const int c0 = chunk * 64;
            __syncthreads();
            for (int ci = t; ci < 1024; ci += 256) {
                int row = ci >> 3, kc = ci & 7;
                int item = tile_m + row;
                int g = (item < nrows) ? idx[item] : -1;
                uint4 v = make_uint4(0, 0, 0, 0);
                if (g >= 0) v = load8(&h[(size_t)g * HH + c0 + kc * 8]);
                *(uint4*)&a_lds[row * 72 + kc * 8] = v;
            }
            for (int ci = t; ci < 1024; ci += 256) {
                int n = ci >> 3, kc = ci & 7;
                *(uint4*)&b_lds[n * 72 + kc * 8] = *(const uint4*)&WT[(size_t)n * HH + c0 + kc * 8];
            }
            __syncthreads();
#pragma unroll
            for (int ks = 0; ks < 2; ++ks) {
                short8 af[4], bf[4];
#pragma unroll
                for (int i = 0; i < 4; ++i)
                    af[i] = *(const short8*)&a_lds[(wr * 64 + i * 16 + l) * 72 + ks * 32 + quad * 8];
#pragma unroll
                for (int j = 0; j < 4; ++j)
                    bf[j] = *(const short8*)&b_lds[(wc * 64 + j * 16 + l) * 72 + ks * 32 + quad * 8];
#pragma unroll
                for (int i = 0; i < 4; ++i)
#pragma unroll
                    for (int j = 0; j < 4; ++j)
                        acc[i][j] = __builtin_amdgcn_mfma_f32_16x16x32_bf16(af[i], bf[j], acc[i][j], 0, 0, 0);
            }
        }
    }
    __syncthreads();
#pragma unroll
    for (int j = 0; j < 4; ++j) {
        int col = wc * 64 + j * 16 + l;
        float b = bias[col];
#pragma unroll
        for (int i = 0; i < 4; ++i) {
            int rloc = wr * 64 + i * 16 + quad * 4;
#pragma unroll
            for (int r = 0; r < 4; ++r)
                clds[(rloc + r) * 136 + col] = f2b(acc[i][j][r] + b);
        }
    }
    __syncthreads();
#pragma unroll
    for (int it = 0; it < 8; ++it) {
        int idx = it * 256 + t;
        int row = idx >> 4, c16 = idx & 15;
        int item = tile_m + row;
        if (item < nrows)
            *(uint4*)&out[(size_t)item * HH + c16 * 8] = *(const uint4*)&clds[row * 136 + c16 * 8];
    }
}

// ============ MFMA z+logit ============
__global__ __launch_bounds__(256) void k_mfma_zlogit(const u16* __restrict__ branch,
                                                     const int* __restrict__ time_idx,
                                                     const float* __restrict__ tproj,
                                                     const float* __restrict__ c1,
                                                     const u16* __restrict__ WTa1,
                                                     const float* __restrict__ Wa2,
                                                     const float* __restrict__ ba2,
                                                     float* __restrict__ out) {
    __shared__ u16 a_lds[128 * 72];
    __shared__ u16 b_lds[128 * 72];
    __shared__ float red[2][128];
    const int t = threadIdx.x;
    const int tile_m = blockIdx.x * 128;
    const int wave = t >> 6, l = t & 15, quad = (t >> 4) & 3;
    const int wr = wave >> 1, wc = wave & 1;
    f32x4 acc[4][4] = {};

    for (int chunk = 0; chunk < 2; ++chunk) {
        const int c0 = chunk * 64;
        __syncthreads();
        for (int ci = t; ci < 1024; ci += 256) {
            int row = ci >> 3, kc = ci & 7;
            int item = tile_m + row;
            uint4 v = make_uint4(0, 0, 0, 0);
            if (item < AA) v = load8(&branch[(size_t)item * HH + c0 + kc * 8]);
            *(uint4*)&a_lds[row * 72 + kc * 8] = v;
        }
        for (int ci = t; ci < 1024; ci += 256) {
            int n = ci >> 3, kc = ci & 7;
            *(uint4*)&b_lds[n * 72 + kc * 8] = *(const uint4*)&WTa1[(size_t)n * HH + c0 + kc * 8];
        }
        __syncthreads();
#pragma unroll
        for (int ks = 0; ks < 2; ++ks) {
            short8 af[4], bf[4];
#pragma unroll
            for (int i = 0; i < 4; ++i)
                af[i] = *(const short8*)&a_lds[(wr * 64 + i * 16 + l) * 72 + ks * 32 + quad * 8];
#pragma unroll
            for (int j = 0; j < 4; ++j)
                bf[j] = *(const short8*)&b_lds[(wc * 64 + j * 16 + l) * 72 + ks * 32 + quad * 8];
#pragma unroll
            for (int i = 0; i < 4; ++i)
#pragma unroll
                for (int j = 0; j < 4; ++j)
                    acc[i][j] = __builtin_amdgcn_mfma_f32_16x16x32_bf16(af[i], bf[j], acc[i][j], 0, 0, 0);
        }
    }
    float c1v[4], wa2v[4];
#pragma unroll
    for (int j = 0; j < 4; ++j) {
        int col = wc * 64 + j * 16 + l;
        c1v[j] = c1[col];
        wa2v[j] = Wa2[col];
    }
#pragma unroll
    for (int i = 0; i < 4; ++i) {
        int rbase = tile_m + wr * 64 + i * 16 + quad * 4;
#pragma unroll
        for (int r = 0; r < 4; ++r) {
            int item = rbase + r;
            int ti = (item < AA) ? time_idx[item] : 0;
            const float* tp = tproj + (size_t)ti * HH;
            float partial = 0.f;
#pragma unroll
            for (int j = 0; j < 4; ++j) {
                int col = wc * 64 + j * 16 + l;
                float z = fmaxf(acc[i][j][r] + tp[col] + c1v[j], 0.f);
                partial = fmaf(z, wa2v[j], partial);
            }
            partial += __shfl_xor(partial, 1);
            partial += __shfl_xor(partial, 2);
            partial += __shfl_xor(partial, 4);
            partial += __shfl_xor(partial, 8);
            if (l == 0) red[wc][wr * 64 + i * 16 + quad * 4 + r] = partial;
        }
    }
    __syncthreads();
    if (t < 128) {
        int item = tile_m + t;
        if (item < AA) out[item] = red[0][t] + red[1][t] + ba2[0];
    }
}

// ---------- edge pass A ----------
__global__ __launch_bounds__(256) void k_edge_score(const u16* __restrict__ xl,
                                                    const u16* __restrict__ xr,
                                                    const int* __restrict__ src,
                                                    const int* __restrict__ dst,
                                                    const float* __restrict__ att,
                                                    float* __restrict__ a_e,
                                                    unsigned* __restrict__ amax) {
    __shared__ float att_l[HH];
    if (threadIdx.x < HH) att_l[threadIdx.x] = att[threadIdx.x];
    __syncthreads();
    int wid = blockIdx.x * 4 + (threadIdx.x >> 6);
    int lane = threadIdx.x & 63;
    if (wid >= EE) return;
    int s = src[wid], d = dst[wid];
    u32 pl = ((const u32*)xl)[(size_t)s * 64 + lane];
    u32 pr = ((const u32*)xr)[(size_t)d * 64 + lane];
    float e0 = bfb((u16)pl) + bfb((u16)pr);
    float e1 = bfb((u16)(pl >> 16)) + bfb((u16)(pr >> 16));
    e0 = e0 >= 0.f ? e0 : 0.2f * e0;
    e1 = e1 >= 0.f ? e1 : 0.2f * e1;
    float acc = fmaf(e0, att_l[2 * lane], e1 * att_l[2 * lane + 1]);
    for (int off = 32; off; off >>= 1) acc += __shfl_down(acc, off);
    if (lane == 0) {
        a_e[wid] = acc;
        atomicMax(&amax[d], f2key(acc));
    }
}

// ---------- edge pass B ----------
__global__ __launch_bounds__(256) void k_edge_norm(float* __restrict__ a_e,
                                                   const int* __restrict__ dst,
                                                   const unsigned* __restrict__ amax,
                                                   float* __restrict__ denom) {
    int e = blockIdx.x * blockDim.x + threadIdx.x;
    if (e >= EE) return;
    int d = dst[e];
    float ex = __expf(a_e[e] - key2f(amax[d]));
    a_e[e] = ex;
    atomicAdd(&denom[d], ex);
}

// ---------- edge pass C (half feature) ----------
__global__ __launch_bounds__(256) void k_edge_agg_half(const u16* __restrict__ xl,
                                                       const float* __restrict__ ex_e,
                                                       const int* __restrict__ src,
                                                       const int* __restrict__ dst,
                                                       const float* __restrict__ denom,
                                                       float* __restrict__ agg, int half) {
    int wid = blockIdx.x * 4 + (threadIdx.x >> 6);
    int lane = threadIdx.x & 63;
    if (wid >= EE) return;
    int s = src[wid], d = dst[wid];
    float alpha = ex_e[wid] / (denom[d] + 1e-16f);
    float v = bfb(xl[(size_t)s * HH + half * 64 + lane]);
    atomicAdd(&agg[(size_t)d * 64 + lane], alpha * v);
}

// ---------- h update (half feature) ----------
__global__ __launch_bounds__(256) void k_update_half(u16* __restrict__ h,
                                                     const float* __restrict__ agg,
                                                     const float* __restrict__ bias, int half) {
    size_t i = (size_t)blockIdx.x * 256 + threadIdx.x;
    if (i >= (size_t)NN * 64) return;
    int n = (int)(i >> 6), c = (int)(i & 63);
    int col = half * 64 + c;
    size_t hi = (size_t)n * HH + col;
    float hv = bfb(h[hi]);
    float av = agg[i] + bias[col];
    hv += fmaxf(av, 0.f);
    h[hi] = f2b(hv);
}

// ---------- host side ----------
typedef const float* fp;

static void run_gat(u16* h, u16* xl, u16* xr, float* agg,
                    float* a_e, unsigned* amax, float* denom,
                    const int* src, const int* dst,
                    const u16* WTl, fp bl, const u16* WTr, fp br,
                    fp att, fp bias, hipStream_t stream) {
    const int NB = (NN + 127) / 128;
    hipMemsetAsync(amax, 0, (size_t)NN * 4, stream);
    hipMemsetAsync(denom, 0, (size_t)NN * 4, stream);
    k_mfma_proj<128, u16><<<NB, 256, 0, stream>>>(h, WTl, bl, xl, NN);
    k_mfma_proj<128, u16><<<NB, 256, 0, stream>>>(h, WTr, br, xr, NN);
    k_edge_score<<<(EE + 3) / 4, 256, 0, stream>>>(xl, xr, src, dst, att, a_e, amax);
    k_edge_norm<<<(EE + 255) / 256, 256, 0, stream>>>(a_e, dst, amax, denom);
    for (int half = 0; half < 2; ++half) {
        hipMemsetAsync(agg, 0, (size_t)NN * 64 * 4, stream);
        k_edge_agg_half<<<(EE + 3) / 4, 256, 0, stream>>>(xl, a_e, src, dst, denom, agg, half);
        k_update_half<<<((NN * 64) + 255) / 256, 256, 0, stream>>>(h, agg, bias, half);
    }
}

extern "C" void kernel_launch(void* const* d_in, const int* in_sizes, int n_in,
                              void* d_out, int out_size, void* d_ws, size_t ws_size,
                              hipStream_t stream) {
    fp x                 = (fp)d_in[0];
    const int* ei        = (const int*)d_in[1];
    fp focal             = (fp)d_in[2];
    const int* child_idx = (const int*)d_in[3];
    const int* parent_idx= (const int*)d_in[4];
    const int* time_idx  = (const int*)d_in[5];
    fp W_embed = (fp)d_in[6],  b_embed = (fp)d_in[7];
    fp bu_Wl   = (fp)d_in[8],  bu_bl   = (fp)d_in[9];
    fp bu_Wr   = (fp)d_in[10], bu_br   = (fp)d_in[11];
    fp bu_att  = (fp)d_in[12], bu_bias = (fp)d_in[13];
    fp td_Wl   = (fp)d_in[14], td_bl   = (fp)d_in[15];
    fp td_Wr   = (fp)d_in[16], td_br   = (fp)d_in[17];
    fp td_att  = (fp)d_in[18], td_bias = (fp)d_in[19];
    fp time_table = (fp)d_in[20];
    fp W_comb  = (fp)d_in[21], b_comb  = (fp)d_in[22];
    fp W_a1    = (fp)d_in[23], b_a1    = (fp)d_in[24];
    fp W_a2    = (fp)d_in[25], b_a2    = (fp)d_in[26];
    fp W_seq   = (fp)d_in[27], b_seq   = (fp)d_in[28];

    const size_t NH = (size_t)NN * HH;
    u16* wt = (u16*)d_ws;                 // 8 x 16384 u16 (512 KB), 16B-aligned slots
    u16* h  = wt + 8 * 16384;             // N*H bf16
    u16* xl = h + NH;
    u16* xr = xl + NH;
    float* agg = (float*)xr;              // N*64 f32, aliases xr (dead after score)
    u16* branch = xl;                     // A*H bf16, aliases xl (dead after GATs)
    float* a_e   = (float*)(xr + NH);     // E
    unsigned* amax = (unsigned*)(a_e + EE);  // N
    float* denom = (float*)(amax + NN);   // N
    float* ctx   = denom + NN;            // H
    float* c1v   = ctx + HH;              // H
    float* tproj = c1v + HH;              // T*H

    // pre-transpose all GEMM weights to bf16 [n][k]
    k_wtrans<<<64, 256, 0, stream>>>(bu_Wl, bu_Wr, td_Wl, td_Wr,
                                     W_comb, W_comb + (size_t)HH * HH, W_a1, W_embed, wt);
    const u16* wt_buWl = wt + 0 * 16384;
    const u16* wt_buWr = wt + 1 * 16384;
    const u16* wt_tdWl = wt + 2 * 16384;
    const u16* wt_tdWr = wt + 3 * 16384;
    const u16* wt_combC = wt + 4 * 16384;
    const u16* wt_combP = wt + 5 * 16384;
    const u16* wt_a1   = wt + 6 * 16384;
    const u16* wt_embed = wt + 7 * 16384;

    // small precomputes
    k_context<<<1, 128, 0, stream>>>(focal, W_seq, b_seq, ctx);
    k_c1<<<1, 128, 0, stream>>>(ctx, W_a1 + (size_t)256 * HH, b_a1, c1v);
    k_tproj<<<TT, 128, 0, stream>>>(time_table, W_a1 + (size_t)128 * HH, tproj);

    const int NB = (NN + 127) / 128;
    // embed: h = x @ W_embed + b_embed
    k_mfma_proj<64, float><<<NB, 256, 0, stream>>>(x, wt_embed, b_embed, h, NN);

    // bottom-up GAT
    run_gat(h, xl, xr, agg, a_e, amax, denom, ei + EE, ei,
            wt_buWl, bu_bl, wt_buWr, bu_br, bu_att, bu_bias, stream);
    // top-down GAT
    run_gat(h, xl, xr, agg, a_e, amax, denom, ei, ei + EE,
            wt_tdWl, td_bl, wt_tdWr, td_br, td_att, td_bias, stream);

    // branch = h[child]@Wc + h[parent]@Wp + b_comb  (bf16 out over xl)
    k_mfma_gproj<<<(AA + 127) / 128, 256, 0, stream>>>(
        h, child_idx, parent_idx, wt_combC, wt_combP, b_comb, branch, AA);

    // logits
    k_mfma_zlogit<<<(AA + 127) / 128, 256, 0, stream>>>(
        branch, time_idx, tproj, c1v, wt_a1, W_a2, b_a2, (float*)d_out);
}

// Round 7
// 665.613 us; speedup vs baseline: 5.7649x; 1.6266x over previous
//
#include <hip/hip_runtime.h>
#include <hip/hip_bf16.h>

#define NN 300000
#define EE 299999
#define AA 150000
#define DD 64
#define HH 128
#define TT 512
#define SCAN_NB ((NN + 1023) / 1024)

typedef unsigned short u16;
typedef unsigned int u32;
typedef __attribute__((ext_vector_type(8))) short short8;
typedef __attribute__((ext_vector_type(4))) float f32x4;

// ---------- helpers ----------
__device__ __forceinline__ float bfb(u16 u) { return __uint_as_float(((u32)u) << 16); }
__device__ __forceinline__ u16 f2b(float f) {
    u32 u = __float_as_uint(f);
    u32 r = (u + 0x7FFFu + ((u >> 16) & 1u)) >> 16;
    return (u16)r;
}
__device__ __forceinline__ uint4 load8(const u16* p) { return *(const uint4*)p; }
__device__ __forceinline__ uint4 load8(const float* p) {
    float4 f1 = *(const float4*)p;
    float4 f2 = *(const float4*)(p + 4);
    union { ushort s[8]; uint4 v; } u;
    u.s[0] = f2b(f1.x); u.s[1] = f2b(f1.y); u.s[2] = f2b(f1.z); u.s[3] = f2b(f1.w);
    u.s[4] = f2b(f2.x); u.s[5] = f2b(f2.y); u.s[6] = f2b(f2.z); u.s[7] = f2b(f2.w);
    return u.v;
}
__device__ __forceinline__ void unpack8(uint4 v, float* f) {
    u32 w0 = v.x, w1 = v.y, w2 = v.z, w3 = v.w;
    f[0] = bfb((u16)w0); f[1] = bfb((u16)(w0 >> 16));
    f[2] = bfb((u16)w1); f[3] = bfb((u16)(w1 >> 16));
    f[4] = bfb((u16)w2); f[5] = bfb((u16)(w2 >> 16));
    f[6] = bfb((u16)w3); f[7] = bfb((u16)(w3 >> 16));
}

// ---------- weight pre-transpose ----------
__global__ __launch_bounds__(256) void k_wtrans(const float* w0, const float* w1,
                                                const float* w2, const float* w3,
                                                const float* w4, const float* w5,
                                                const float* w6, const float* w7,
                                                u16* __restrict__ wt) {
    int widx = blockIdx.x >> 3, part = blockIdx.x & 7;
    const float* W; int K = 128;
    switch (widx) {
        case 0: W = w0; break; case 1: W = w1; break;
        case 2: W = w2; break; case 3: W = w3; break;
        case 4: W = w4; break; case 5: W = w5; break;
        case 6: W = w6; break; default: W = w7; K = 64; break;
    }
    u16* dst = wt + widx * 16384;
    int total = K * 128;
    int lo = part * 2048, hi = lo + 2048;
    if (hi > total) hi = total;
    for (int idx = lo + threadIdx.x; idx < hi; idx += 256) {
        int k = idx >> 7, n = idx & 127;
        dst[n * K + k] = f2b(W[k * 128 + n]);
    }
}

// ---------- tiny precomputes ----------
__global__ void k_context(const float* __restrict__ focal, const float* __restrict__ Wseq,
                          const float* __restrict__ bseq, float* __restrict__ ctx) {
    int t = threadIdx.x;
    float acc = bseq[t];
    for (int d = 0; d < DD; ++d) acc = fmaf(focal[d], Wseq[d * HH + t], acc);
    ctx[t] = acc;
}

__global__ void k_c1(const float* __restrict__ ctx, const float* __restrict__ Wa1c,
                     const float* __restrict__ ba1, float* __restrict__ c1) {
    int t = threadIdx.x;
    float acc = ba1[t];
    for (int k = 0; k < HH; ++k) acc = fmaf(ctx[k], Wa1c[k * HH + t], acc);
    c1[t] = acc;
}

__global__ void k_tproj(const float* __restrict__ tt, const float* __restrict__ Wa1m,
                        float* __restrict__ tproj) {
    int ti = blockIdx.x, t = threadIdx.x;
    float acc = 0.f;
    for (int k = 0; k < HH; ++k)
        acc = fmaf(tt[ti * HH + k], Wa1m[k * HH + t], acc);
    tproj[(size_t)ti * HH + t] = acc;
}

// ---------- CSR build ----------
__global__ void k_hist(const int* __restrict__ dst, int* __restrict__ counts) {
    int e = blockIdx.x * 256 + threadIdx.x;
    if (e < EE) atomicAdd(&counts[dst[e]], 1);
}

__global__ __launch_bounds__(256) void k_scan_block(const int* __restrict__ in,
                                                    int* __restrict__ out,
                                                    int* __restrict__ bsum, int n) {
    __shared__ int sh[256];
    int b = blockIdx.x, t = threadIdx.x;
    int base = b * 1024 + t * 4;
    int v0 = (base + 0 < n) ? in[base + 0] : 0;
    int v1 = (base + 1 < n) ? in[base + 1] : 0;
    int v2 = (base + 2 < n) ? in[base + 2] : 0;
    int v3 = (base + 3 < n) ? in[base + 3] : 0;
    int tsum = v0 + v1 + v2 + v3;
    sh[t] = tsum;
    __syncthreads();
    for (int d = 1; d < 256; d <<= 1) {
        int x = (t >= d) ? sh[t - d] : 0;
        __syncthreads();
        sh[t] += x;
        __syncthreads();
    }
    int excl = sh[t] - tsum;
    if (t == 255) bsum[b] = sh[255];
    if (base + 0 < n) out[base + 0] = excl;
    if (base + 1 < n) out[base + 1] = excl + v0;
    if (base + 2 < n) out[base + 2] = excl + v0 + v1;
    if (base + 3 < n) out[base + 3] = excl + v0 + v1 + v2;
}

__global__ __launch_bounds__(256) void k_scan_top(int* __restrict__ data, int n) {
    __shared__ int sh[256];
    int t = threadIdx.x;
    int base = t * 4;
    int v0 = (base + 0 < n) ? data[base + 0] : 0;
    int v1 = (base + 1 < n) ? data[base + 1] : 0;
    int v2 = (base + 2 < n) ? data[base + 2] : 0;
    int v3 = (base + 3 < n) ? data[base + 3] : 0;
    int tsum = v0 + v1 + v2 + v3;
    sh[t] = tsum;
    __syncthreads();
    for (int d = 1; d < 256; d <<= 1) {
        int x = (t >= d) ? sh[t - d] : 0;
        __syncthreads();
        sh[t] += x;
        __syncthreads();
    }
    int excl = sh[t] - tsum;
    if (base + 0 < n) data[base + 0] = excl;
    if (base + 1 < n) data[base + 1] = excl + v0;
    if (base + 2 < n) data[base + 2] = excl + v0 + v1;
    if (base + 3 < n) data[base + 3] = excl + v0 + v1 + v2;
}

__global__ void k_scan_add(int* __restrict__ out, const int* __restrict__ bsum, int n) {
    int i = blockIdx.x * 256 + threadIdx.x;
    if (i < n) out[i] += bsum[i >> 10];
}

__global__ void k_settail(int* o1, int* o2) {
    if (threadIdx.x == 0) { o1[NN] = EE; o2[NN] = EE; }
}

__global__ void k_scatter(const int* __restrict__ src, const int* __restrict__ dst,
                          int* __restrict__ cursor, int* __restrict__ elist) {
    int e = blockIdx.x * 256 + threadIdx.x;
    if (e >= EE) return;
    int pos = atomicAdd(&cursor[dst[e]], 1);
    elist[pos] = src[e];
}

// ============ MFMA GEMM: out_bf16[r,:] = in[r,0:K] @ W + b (WT bf16 [n][k]) ============
template <int K, typename InT>
__global__ __launch_bounds__(256) void k_mfma_proj(const InT* __restrict__ in,
                                                   const u16* __restrict__ WT,
                                                   const float* __restrict__ bias,
                                                   u16* __restrict__ out, int nrows) {
    __shared__ u16 lds[2][128 * 72];
    u16* a_lds = lds[0];
    u16* b_lds = lds[1];
    u16* clds = lds[0];
    const int t = threadIdx.x;
    const int tile_m = blockIdx.x * 128;
    const int wave = t >> 6, l = t & 15, quad = (t >> 4) & 3;
    const int wr = wave >> 1, wc = wave & 1;
    f32x4 acc[4][4] = {};

    for (int chunk = 0; chunk < K / 64; ++chunk) {
        const int c0 = chunk * 64;
        __syncthreads();
        for (int ci = t; ci < 1024; ci += 256) {
            int row = ci >> 3, kc = ci & 7;
            int grow = tile_m + row;
            uint4 v = make_uint4(0, 0, 0, 0);
            if (grow < nrows) v = load8(&in[(size_t)grow * K + c0 + kc * 8]);
            *(uint4*)&a_lds[row * 72 + kc * 8] = v;
        }
        for (int ci = t; ci < 1024; ci += 256) {
            int n = ci >> 3, kc = ci & 7;
            *(uint4*)&b_lds[n * 72 + kc * 8] = *(const uint4*)&WT[(size_t)n * K + c0 + kc * 8];
        }
        __syncthreads();
#pragma unroll
        for (int ks = 0; ks < 2; ++ks) {
            short8 af[4], bf[4];
#pragma unroll
            for (int i = 0; i < 4; ++i)
                af[i] = *(const short8*)&a_lds[(wr * 64 + i * 16 + l) * 72 + ks * 32 + quad * 8];
#pragma unroll
            for (int j = 0; j < 4; ++j)
                bf[j] = *(const short8*)&b_lds[(wc * 64 + j * 16 + l) * 72 + ks * 32 + quad * 8];
#pragma unroll
            for (int i = 0; i < 4; ++i)
#pragma unroll
                for (int j = 0; j < 4; ++j)
                    acc[i][j] = __builtin_amdgcn_mfma_f32_16x16x32_bf16(af[i], bf[j], acc[i][j], 0, 0, 0);
        }
    }
    __syncthreads();
#pragma unroll
    for (int j = 0; j < 4; ++j) {
        int col = wc * 64 + j * 16 + l;
        float b = bias[col];
#pragma unroll
        for (int i = 0; i < 4; ++i) {
            int rloc = wr * 64 + i * 16 + quad * 4;
#pragma unroll
            for (int r = 0; r < 4; ++r)
                clds[(rloc + r) * 136 + col] = f2b(acc[i][j][r] + b);
        }
    }
    __syncthreads();
#pragma unroll
    for (int it = 0; it < 8; ++it) {
        int idx = it * 256 + t;
        int row = idx >> 4, c16 = idx & 15;
        int grow = tile_m + row;
        if (grow < nrows)
            *(uint4*)&out[(size_t)grow * HH + c16 * 8] = *(const uint4*)&clds[row * 136 + c16 * 8];
    }
}

// ============ fused gathered GEMM ============
__global__ __launch_bounds__(256) void k_mfma_gproj(const u16* __restrict__ h,
                                                    const int* __restrict__ idx1,
                                                    const int* __restrict__ idx2,
                                                    const u16* __restrict__ WT1,
                                                    const u16* __restrict__ WT2,
                                                    const float* __restrict__ bias,
                                                    u16* __restrict__ out, int nrows) {
    __shared__ u16 lds[2][128 * 72];
    u16* a_lds = lds[0];
    u16* b_lds = lds[1];
    u16* clds = lds[0];
    const int t = threadIdx.x;
    const int tile_m = blockIdx.x * 128;
    const int wave = t >> 6, l = t & 15, quad = (t >> 4) & 3;
    const int wr = wave >> 1, wc = wave & 1;
    f32x4 acc[4][4] = {};

    for (int pass = 0; pass < 2; ++pass) {
        const int* idx = pass ? idx2 : idx1;
        const u16* WT = pass ? WT2 : WT1;
        for (int chunk = 0; chunk < 2; ++chunk) {
            const int c0 = chunk * 64;
            __syncthreads();
            for (int ci = t; ci < 1024; ci += 256) {
                int row = ci >> 3, kc = ci & 7;
                int item = tile_m + row;
                int g = (item < nrows) ? idx[item] : -1;
                uint4 v = make_uint4(0, 0, 0, 0);
                if (g >= 0) v = load8(&h[(size_t)g * HH + c0 + kc * 8]);
                *(uint4*)&a_lds[row * 72 + kc * 8] = v;
            }
            for (int ci = t; ci < 1024; ci += 256) {
                int n = ci >> 3, kc = ci & 7;
                *(uint4*)&b_lds[n * 72 + kc * 8] = *(const uint4*)&WT[(size_t)n * HH + c0 + kc * 8];
            }
            __syncthreads();
#pragma unroll
            for (int ks = 0; ks < 2; ++ks) {
                short8 af[4], bf[4];
#pragma unroll
                for (int i = 0; i < 4; ++i)
                    af[i] = *(const short8*)&a_lds[(wr * 64 + i * 16 + l) * 72 + ks * 32 + quad * 8];
#pragma unroll
                for (int j = 0; j < 4; ++j)
                    bf[j] = *(const short8*)&b_lds[(wc * 64 + j * 16 + l) * 72 + ks * 32 + quad * 8];
#pragma unroll
                for (int i = 0; i < 4; ++i)
#pragma unroll
                    for (int j = 0; j < 4; ++j)
                        acc[i][j] = __builtin_amdgcn_mfma_f32_16x16x32_bf16(af[i], bf[j], acc[i][j], 0, 0, 0);
            }
        }
    }
    __syncthreads();
#pragma unroll
    for (int j = 0; j < 4; ++j) {
        int col = wc * 64 + j * 16 + l;
        float b = bias[col];
#pragma unroll
        for (int i = 0; i < 4; ++i) {
            int rloc = wr * 64 + i * 16 + quad * 4;
#pragma unroll
            for (int r = 0; r < 4; ++r)
                clds[(rloc + r) * 136 + col] = f2b(acc[i][j][r] + b);
        }
    }
    __syncthreads();
#pragma unroll
    for (int it = 0; it < 8; ++it) {
        int idx = it * 256 + t;
        int row = idx >> 4, c16 = idx & 15;
        int item = tile_m + row;
        if (item < nrows)
            *(uint4*)&out[(size_t)item * HH + c16 * 8] = *(const uint4*)&clds[row * 136 + c16 * 8];
    }
}

// ============ MFMA z+logit ============
__global__ __launch_bounds__(256) void k_mfma_zlogit(const u16* __restrict__ branch,
                                                     const int* __restrict__ time_idx,
                                                     const float* __restrict__ tproj,
                                                     const float* __restrict__ c1,
                                                     const u16* __restrict__ WTa1,
                                                     const float* __restrict__ Wa2,
                                                     const float* __restrict__ ba2,
                                                     float* __restrict__ out) {
    __shared__ u16 a_lds[128 * 72];
    __shared__ u16 b_lds[128 * 72];
    __shared__ float red[2][128];
    const int t = threadIdx.x;
    const int tile_m = blockIdx.x * 128;
    const int wave = t >> 6, l = t & 15, quad = (t >> 4) & 3;
    const int wr = wave >> 1, wc = wave & 1;
    f32x4 acc[4][4] = {};

    for (int chunk = 0; chunk < 2; ++chunk) {
        const int c0 = chunk * 64;
        __syncthreads();
        for (int ci = t; ci < 1024; ci += 256) {
            int row = ci >> 3, kc = ci & 7;
            int item = tile_m + row;
            uint4 v = make_uint4(0, 0, 0, 0);
            if (item < AA) v = load8(&branch[(size_t)item * HH + c0 + kc * 8]);
            *(uint4*)&a_lds[row * 72 + kc * 8] = v;
        }
        for (int ci = t; ci < 1024; ci += 256) {
            int n = ci >> 3, kc = ci & 7;
            *(uint4*)&b_lds[n * 72 + kc * 8] = *(const uint4*)&WTa1[(size_t)n * HH + c0 + kc * 8];
        }
        __syncthreads();
#pragma unroll
        for (int ks = 0; ks < 2; ++ks) {
            short8 af[4], bf[4];
#pragma unroll
            for (int i = 0; i < 4; ++i)
                af[i] = *(const short8*)&a_lds[(wr * 64 + i * 16 + l) * 72 + ks * 32 + quad * 8];
#pragma unroll
            for (int j = 0; j < 4; ++j)
                bf[j] = *(const short8*)&b_lds[(wc * 64 + j * 16 + l) * 72 + ks * 32 + quad * 8];
#pragma unroll
            for (int i = 0; i < 4; ++i)
#pragma unroll
                for (int j = 0; j < 4; ++j)
                    acc[i][j] = __builtin_amdgcn_mfma_f32_16x16x32_bf16(af[i], bf[j], acc[i][j], 0, 0, 0);
        }
    }
    float c1v[4], wa2v[4];
#pragma unroll
    for (int j = 0; j < 4; ++j) {
        int col = wc * 64 + j * 16 + l;
        c1v[j] = c1[col];
        wa2v[j] = Wa2[col];
    }
#pragma unroll
    for (int i = 0; i < 4; ++i) {
        int rbase = tile_m + wr * 64 + i * 16 + quad * 4;
#pragma unroll
        for (int r = 0; r < 4; ++r) {
            int item = rbase + r;
            int ti = (item < AA) ? time_idx[item] : 0;
            const float* tp = tproj + (size_t)ti * HH;
            float partial = 0.f;
#pragma unroll
            for (int j = 0; j < 4; ++j) {
                int col = wc * 64 + j * 16 + l;
                float z = fmaxf(acc[i][j][r] + tp[col] + c1v[j], 0.f);
                partial = fmaf(z, wa2v[j], partial);
            }
            partial += __shfl_xor(partial, 1);
            partial += __shfl_xor(partial, 2);
            partial += __shfl_xor(partial, 4);
            partial += __shfl_xor(partial, 8);
            if (l == 0) red[wc][wr * 64 + i * 16 + quad * 4 + r] = partial;
        }
    }
    __syncthreads();
    if (t < 128) {
        int item = tile_m + t;
        if (item < AA) out[item] = red[0][t] + red[1][t] + ba2[0];
    }
}

// ============ fused GAT: per-dst softmax + aggregation + h update (CSR) ============
// 16 lanes per dst node; two passes over the dst's edge list (online softmax, then weighted sum).
__global__ __launch_bounds__(256) void k_gat_fused(u16* __restrict__ h,
                                                   const u16* __restrict__ xl,
                                                   const u16* __restrict__ xr,
                                                   const int* __restrict__ offs,
                                                   const int* __restrict__ elist,
                                                   const float* __restrict__ att,
                                                   const float* __restrict__ bias) {
    int g = blockIdx.x * 16 + (threadIdx.x >> 4);   // dst node (NN divisible by 16)
    int l = threadIdx.x & 15;
    float attv[8], biasv[8];
    *(float4*)&attv[0] = *(const float4*)&att[l * 8];
    *(float4*)&attv[4] = *(const float4*)&att[l * 8 + 4];
    *(float4*)&biasv[0] = *(const float4*)&bias[l * 8];
    *(float4*)&biasv[4] = *(const float4*)&bias[l * 8 + 4];
    float xrf[8];
    unpack8(*(const uint4*)&xr[(size_t)g * HH + l * 8], xrf);
    int e0 = offs[g], e1 = offs[g + 1];

    // pass 1: online max + exp-sum
    float m = -__builtin_inff(), s = 0.f;
    for (int e = e0; e < e1; ++e) {
        int sidx = elist[e];
        float xf[8];
        unpack8(*(const uint4*)&xl[(size_t)sidx * HH + l * 8], xf);
        float p = 0.f;
#pragma unroll
        for (int j = 0; j < 8; ++j) {
            float v = xf[j] + xrf[j];
            v = v >= 0.f ? v : 0.2f * v;
            p = fmaf(v, attv[j], p);
        }
        p += __shfl_xor(p, 1); p += __shfl_xor(p, 2);
        p += __shfl_xor(p, 4); p += __shfl_xor(p, 8);
        float mn = fmaxf(m, p);
        s = s * __expf(m - mn) + __expf(p - mn);
        m = mn;
    }
    float inv = 1.f / (s + 1e-16f);

    // pass 2: weighted accumulate
    float acc[8] = {};
    for (int e = e0; e < e1; ++e) {
        int sidx = elist[e];
        float xf[8];
        unpack8(*(const uint4*)&xl[(size_t)sidx * HH + l * 8], xf);
        float p = 0.f;
#pragma unroll
        for (int j = 0; j < 8; ++j) {
            float v = xf[j] + xrf[j];
            v = v >= 0.f ? v : 0.2f * v;
            p = fmaf(v, attv[j], p);
        }
        p += __shfl_xor(p, 1); p += __shfl_xor(p, 2);
        p += __shfl_xor(p, 4); p += __shfl_xor(p, 8);
        float w = __expf(p - m) * inv;
#pragma unroll
        for (int j = 0; j < 8; ++j) acc[j] = fmaf(w, xf[j], acc[j]);
    }

    // h[g] += relu(acc + bias)
    float hf[8];
    unpack8(*(const uint4*)&h[(size_t)g * HH + l * 8], hf);
    union { ushort sh[8]; uint4 v; } o;
#pragma unroll
    for (int j = 0; j < 8; ++j) {
        hf[j] += fmaxf(acc[j] + biasv[j], 0.f);
        o.sh[j] = f2b(hf[j]);
    }
    *(uint4*)&h[(size_t)g * HH + l * 8] = o.v;
}

// ---------- host side ----------
typedef const float* fp;

static void build_csr(const int* src, const int* dst, int* offs, int* elist,
                      int* work /*N ints: counts->cursor*/, int* bsum, hipStream_t stream) {
    hipMemsetAsync(work, 0, (size_t)NN * 4, stream);
    k_hist<<<(EE + 255) / 256, 256, 0, stream>>>(dst, work);
    k_scan_block<<<SCAN_NB, 256, 0, stream>>>(work, offs, bsum, NN);
    k_scan_top<<<1, 256, 0, stream>>>(bsum, SCAN_NB);
    k_scan_add<<<(NN + 255) / 256, 256, 0, stream>>>(offs, bsum, NN);
    hipMemcpyAsync(work, offs, (size_t)NN * 4, hipMemcpyDeviceToDevice, stream);
    k_scatter<<<(EE + 255) / 256, 256, 0, stream>>>(src, dst, work, elist);
}

extern "C" void kernel_launch(void* const* d_in, const int* in_sizes, int n_in,
                              void* d_out, int out_size, void* d_ws, size_t ws_size,
                              hipStream_t stream) {
    fp x                 = (fp)d_in[0];
    const int* ei        = (const int*)d_in[1];
    fp focal             = (fp)d_in[2];
    const int* child_idx = (const int*)d_in[3];
    const int* parent_idx= (const int*)d_in[4];
    const int* time_idx  = (const int*)d_in[5];
    fp W_embed = (fp)d_in[6],  b_embed = (fp)d_in[7];
    fp bu_Wl   = (fp)d_in[8],  bu_bl   = (fp)d_in[9];
    fp bu_Wr   = (fp)d_in[10], bu_br   = (fp)d_in[11];
    fp bu_att  = (fp)d_in[12], bu_bias = (fp)d_in[13];
    fp td_Wl   = (fp)d_in[14], td_bl   = (fp)d_in[15];
    fp td_Wr   = (fp)d_in[16], td_br   = (fp)d_in[17];
    fp td_att  = (fp)d_in[18], td_bias = (fp)d_in[19];
    fp time_table = (fp)d_in[20];
    fp W_comb  = (fp)d_in[21], b_comb  = (fp)d_in[22];
    fp W_a1    = (fp)d_in[23], b_a1    = (fp)d_in[24];
    fp W_a2    = (fp)d_in[25], b_a2    = (fp)d_in[26];
    fp W_seq   = (fp)d_in[27], b_seq   = (fp)d_in[28];

    const size_t NH = (size_t)NN * HH;
    u16* wt = (u16*)d_ws;                 // 8 x 16384 u16 (256 KB)
    u16* h  = wt + 8 * 16384;             // N*H bf16
    u16* xl = h + NH;
    u16* xr = xl + NH;
    u16* branch = xl;                     // A*H bf16, aliases xl (dead after GATs)
    float* ctx   = (float*)(xr + NH);     // H
    float* c1v   = ctx + HH;              // H
    float* tproj = c1v + HH;              // T*H
    int* offsBU  = (int*)(tproj + (size_t)TT * HH);  // N+1
    int* offsTD  = offsBU + NN + 1;                  // N+1
    int* elistBU = offsTD + NN + 1;                  // E
    int* elistTD = elistBU + EE;                     // E
    int* csr_work= elistTD + EE;                     // N
    int* bsum    = csr_work + NN;                    // SCAN_NB

    // CSR build (independent of h): BU dst=ei[0] src=ei[1]; TD dst=ei[1] src=ei[0]
    build_csr(ei + EE, ei, offsBU, elistBU, csr_work, bsum, stream);
    build_csr(ei, ei + EE, offsTD, elistTD, csr_work, bsum, stream);
    k_settail<<<1, 64, 0, stream>>>(offsBU, offsTD);

    // pre-transpose all GEMM weights to bf16 [n][k]
    k_wtrans<<<64, 256, 0, stream>>>(bu_Wl, bu_Wr, td_Wl, td_Wr,
                                     W_comb, W_comb + (size_t)HH * HH, W_a1, W_embed, wt);
    const u16* wt_buWl = wt + 0 * 16384;
    const u16* wt_buWr = wt + 1 * 16384;
    const u16* wt_tdWl = wt + 2 * 16384;
    const u16* wt_tdWr = wt + 3 * 16384;
    const u16* wt_combC = wt + 4 * 16384;
    const u16* wt_combP = wt + 5 * 16384;
    const u16* wt_a1   = wt + 6 * 16384;
    const u16* wt_embed = wt + 7 * 16384;

    // small precomputes
    k_context<<<1, 128, 0, stream>>>(focal, W_seq, b_seq, ctx);
    k_c1<<<1, 128, 0, stream>>>(ctx, W_a1 + (size_t)256 * HH, b_a1, c1v);
    k_tproj<<<TT, 128, 0, stream>>>(time_table, W_a1 + (size_t)128 * HH, tproj);

    const int NB = (NN + 127) / 128;
    // embed
    k_mfma_proj<64, float><<<NB, 256, 0, stream>>>(x, wt_embed, b_embed, h, NN);

    // bottom-up GAT
    k_mfma_proj<128, u16><<<NB, 256, 0, stream>>>(h, wt_buWl, bu_bl, xl, NN);
    k_mfma_proj<128, u16><<<NB, 256, 0, stream>>>(h, wt_buWr, bu_br, xr, NN);
    k_gat_fused<<<NN / 16, 256, 0, stream>>>(h, xl, xr, offsBU, elistBU, bu_att, bu_bias);

    // top-down GAT
    k_mfma_proj<128, u16><<<NB, 256, 0, stream>>>(h, wt_tdWl, td_bl, xl, NN);
    k_mfma_proj<128, u16><<<NB, 256, 0, stream>>>(h, wt_tdWr, td_br, xr, NN);
    k_gat_fused<<<NN / 16, 256, 0, stream>>>(h, xl, xr, offsTD, elistTD, td_att, td_bias);

    // branch = h[child]@Wc + h[parent]@Wp + b_comb
    k_mfma_gproj<<<(AA + 127) / 128, 256, 0, stream>>>(
        h, child_idx, parent_idx, wt_combC, wt_combP, b_comb, branch, AA);

    // logits
    k_mfma_zlogit<<<(AA + 127) / 128, 256, 0, stream>>>(
        branch, time_idx, tproj, c1v, wt_a1, W_a2, b_a2, (float*)d_out);
}

// Round 8
// 633.210 us; speedup vs baseline: 6.0599x; 1.0512x over previous
//
#include <hip/hip_runtime.h>
#include <hip/hip_bf16.h>

#define NN 300000
#define EE 299999
#define AA 150000
#define DD 64
#define HH 128
#define TT 512
#define SCAN_NB ((NN + 1023) / 1024)

typedef unsigned short u16;
typedef unsigned int u32;
typedef __attribute__((ext_vector_type(8))) short short8;
typedef __attribute__((ext_vector_type(4))) float f32x4;

// ---------- helpers ----------
__device__ __forceinline__ float bfb(u16 u) { return __uint_as_float(((u32)u) << 16); }
__device__ __forceinline__ u16 f2b(float f) {
    u32 u = __float_as_uint(f);
    u32 r = (u + 0x7FFFu + ((u >> 16) & 1u)) >> 16;
    return (u16)r;
}
__device__ __forceinline__ uint4 load8(const u16* p) { return *(const uint4*)p; }
__device__ __forceinline__ uint4 load8(const float* p) {
    float4 f1 = *(const float4*)p;
    float4 f2 = *(const float4*)(p + 4);
    union { ushort s[8]; uint4 v; } u;
    u.s[0] = f2b(f1.x); u.s[1] = f2b(f1.y); u.s[2] = f2b(f1.z); u.s[3] = f2b(f1.w);
    u.s[4] = f2b(f2.x); u.s[5] = f2b(f2.y); u.s[6] = f2b(f2.z); u.s[7] = f2b(f2.w);
    return u.v;
}
__device__ __forceinline__ void unpack8(uint4 v, float* f) {
    u32 w0 = v.x, w1 = v.y, w2 = v.z, w3 = v.w;
    f[0] = bfb((u16)w0); f[1] = bfb((u16)(w0 >> 16));
    f[2] = bfb((u16)w1); f[3] = bfb((u16)(w1 >> 16));
    f[4] = bfb((u16)w2); f[5] = bfb((u16)(w2 >> 16));
    f[6] = bfb((u16)w3); f[7] = bfb((u16)(w3 >> 16));
}

// ---------- weight pre-transpose ----------
__global__ __launch_bounds__(256) void k_wtrans(const float* w0, const float* w1,
                                                const float* w2, const float* w3,
                                                const float* w4, const float* w5,
                                                const float* w6, const float* w7,
                                                u16* __restrict__ wt) {
    int widx = blockIdx.x >> 3, part = blockIdx.x & 7;
    const float* W; int K = 128;
    switch (widx) {
        case 0: W = w0; break; case 1: W = w1; break;
        case 2: W = w2; break; case 3: W = w3; break;
        case 4: W = w4; break; case 5: W = w5; break;
        case 6: W = w6; break; default: W = w7; K = 64; break;
    }
    u16* dst = wt + widx * 16384;
    int total = K * 128;
    int lo = part * 2048, hi = lo + 2048;
    if (hi > total) hi = total;
    for (int idx = lo + threadIdx.x; idx < hi; idx += 256) {
        int k = idx >> 7, n = idx & 127;
        dst[n * K + k] = f2b(W[k * 128 + n]);
    }
}

// ---------- tiny precomputes ----------
__global__ void k_context(const float* __restrict__ focal, const float* __restrict__ Wseq,
                          const float* __restrict__ bseq, float* __restrict__ ctx) {
    int t = threadIdx.x;
    float acc = bseq[t];
    for (int d = 0; d < DD; ++d) acc = fmaf(focal[d], Wseq[d * HH + t], acc);
    ctx[t] = acc;
}

__global__ void k_c1(const float* __restrict__ ctx, const float* __restrict__ Wa1c,
                     const float* __restrict__ ba1, float* __restrict__ c1) {
    int t = threadIdx.x;
    float acc = ba1[t];
    for (int k = 0; k < HH; ++k) acc = fmaf(ctx[k], Wa1c[k * HH + t], acc);
    c1[t] = acc;
}

__global__ void k_tproj(const float* __restrict__ tt, const float* __restrict__ Wa1m,
                        float* __restrict__ tproj) {
    int ti = blockIdx.x, t = threadIdx.x;
    float acc = 0.f;
    for (int k = 0; k < HH; ++k)
        acc = fmaf(tt[ti * HH + k], Wa1m[k * HH + t], acc);
    tproj[(size_t)ti * HH + t] = acc;
}

// ---------- CSR build ----------
__global__ void k_hist(const int* __restrict__ dst, int* __restrict__ counts) {
    int e = blockIdx.x * 256 + threadIdx.x;
    if (e < EE) atomicAdd(&counts[dst[e]], 1);
}

__global__ __launch_bounds__(256) void k_scan_block(const int* __restrict__ in,
                                                    int* __restrict__ out,
                                                    int* __restrict__ bsum, int n) {
    __shared__ int sh[256];
    int b = blockIdx.x, t = threadIdx.x;
    int base = b * 1024 + t * 4;
    int v0 = (base + 0 < n) ? in[base + 0] : 0;
    int v1 = (base + 1 < n) ? in[base + 1] : 0;
    int v2 = (base + 2 < n) ? in[base + 2] : 0;
    int v3 = (base + 3 < n) ? in[base + 3] : 0;
    int tsum = v0 + v1 + v2 + v3;
    sh[t] = tsum;
    __syncthreads();
    for (int d = 1; d < 256; d <<= 1) {
        int x = (t >= d) ? sh[t - d] : 0;
        __syncthreads();
        sh[t] += x;
        __syncthreads();
    }
    int excl = sh[t] - tsum;
    if (t == 255) bsum[b] = sh[255];
    if (base + 0 < n) out[base + 0] = excl;
    if (base + 1 < n) out[base + 1] = excl + v0;
    if (base + 2 < n) out[base + 2] = excl + v0 + v1;
    if (base + 3 < n) out[base + 3] = excl + v0 + v1 + v2;
}

__global__ __launch_bounds__(256) void k_scan_top(int* __restrict__ data, int n) {
    __shared__ int sh[256];
    int t = threadIdx.x;
    int base = t * 4;
    int v0 = (base + 0 < n) ? data[base + 0] : 0;
    int v1 = (base + 1 < n) ? data[base + 1] : 0;
    int v2 = (base + 2 < n) ? data[base + 2] : 0;
    int v3 = (base + 3 < n) ? data[base + 3] : 0;
    int tsum = v0 + v1 + v2 + v3;
    sh[t] = tsum;
    __syncthreads();
    for (int d = 1; d < 256; d <<= 1) {
        int x = (t >= d) ? sh[t - d] : 0;
        __syncthreads();
        sh[t] += x;
        __syncthreads();
    }
    int excl = sh[t] - tsum;
    if (base + 0 < n) data[base + 0] = excl;
    if (base + 1 < n) data[base + 1] = excl + v0;
    if (base + 2 < n) data[base + 2] = excl + v0 + v1;
    if (base + 3 < n) data[base + 3] = excl + v0 + v1 + v2;
}

__global__ void k_scan_add(int* __restrict__ out, const int* __restrict__ bsum, int n) {
    int i = blockIdx.x * 256 + threadIdx.x;
    if (i < n) out[i] += bsum[i >> 10];
}

__global__ void k_settail(int* o1, int* o2) {
    if (threadIdx.x == 0) { o1[NN] = EE; o2[NN] = EE; }
}

__global__ void k_scatter(const int* __restrict__ src, const int* __restrict__ dst,
                          int* __restrict__ cursor, int* __restrict__ elist) {
    int e = blockIdx.x * 256 + threadIdx.x;
    if (e >= EE) return;
    int pos = atomicAdd(&cursor[dst[e]], 1);
    elist[pos] = src[e];
}

// ============ MFMA GEMM (single weight): out_bf16 = in @ W + b ============
template <int K, typename InT>
__global__ __launch_bounds__(256) void k_mfma_proj(const InT* __restrict__ in,
                                                   const u16* __restrict__ WT,
                                                   const float* __restrict__ bias,
                                                   u16* __restrict__ out, int nrows) {
    __shared__ u16 lds[2][128 * 72];
    u16* a_lds = lds[0];
    u16* b_lds = lds[1];
    u16* clds = lds[0];
    const int t = threadIdx.x;
    const int tile_m = blockIdx.x * 128;
    const int wave = t >> 6, l = t & 15, quad = (t >> 4) & 3;
    const int wr = wave >> 1, wc = wave & 1;
    f32x4 acc[4][4] = {};

    for (int chunk = 0; chunk < K / 64; ++chunk) {
        const int c0 = chunk * 64;
        __syncthreads();
        for (int ci = t; ci < 1024; ci += 256) {
            int row = ci >> 3, kc = ci & 7;
            int grow = tile_m + row;
            uint4 v = make_uint4(0, 0, 0, 0);
            if (grow < nrows) v = load8(&in[(size_t)grow * K + c0 + kc * 8]);
            *(uint4*)&a_lds[row * 72 + kc * 8] = v;
        }
        for (int ci = t; ci < 1024; ci += 256) {
            int n = ci >> 3, kc = ci & 7;
            *(uint4*)&b_lds[n * 72 + kc * 8] = *(const uint4*)&WT[(size_t)n * K + c0 + kc * 8];
        }
        __syncthreads();
#pragma unroll
        for (int ks = 0; ks < 2; ++ks) {
            short8 af[4], bf[4];
#pragma unroll
            for (int i = 0; i < 4; ++i)
                af[i] = *(const short8*)&a_lds[(wr * 64 + i * 16 + l) * 72 + ks * 32 + quad * 8];
#pragma unroll
            for (int j = 0; j < 4; ++j)
                bf[j] = *(const short8*)&b_lds[(wc * 64 + j * 16 + l) * 72 + ks * 32 + quad * 8];
#pragma unroll
            for (int i = 0; i < 4; ++i)
#pragma unroll
                for (int j = 0; j < 4; ++j)
                    acc[i][j] = __builtin_amdgcn_mfma_f32_16x16x32_bf16(af[i], bf[j], acc[i][j], 0, 0, 0);
        }
    }
    __syncthreads();
#pragma unroll
    for (int j = 0; j < 4; ++j) {
        int col = wc * 64 + j * 16 + l;
        float b = bias[col];
#pragma unroll
        for (int i = 0; i < 4; ++i) {
            int rloc = wr * 64 + i * 16 + quad * 4;
#pragma unroll
            for (int r = 0; r < 4; ++r)
                clds[(rloc + r) * 136 + col] = f2b(acc[i][j][r] + b);
        }
    }
    __syncthreads();
#pragma unroll
    for (int it = 0; it < 8; ++it) {
        int idx = it * 256 + t;
        int row = idx >> 4, c16 = idx & 15;
        int grow = tile_m + row;
        if (grow < nrows)
            *(uint4*)&out[(size_t)grow * HH + c16 * 8] = *(const uint4*)&clds[row * 136 + c16 * 8];
    }
}

// ============ fused dual GEMM: xl = h@Wl+bl, xr = h@Wr+br (A staged once) ============
__global__ __launch_bounds__(256) void k_mfma_proj2(const u16* __restrict__ in,
                                                    const u16* __restrict__ WT1,
                                                    const u16* __restrict__ WT2,
                                                    const float* __restrict__ b1,
                                                    const float* __restrict__ b2,
                                                    u16* __restrict__ out1,
                                                    u16* __restrict__ out2, int nrows) {
    __shared__ u16 lds[3 * 128 * 72];
    u16* a_lds = lds;
    u16* b1_lds = lds + 128 * 72;
    u16* b2_lds = lds + 2 * 128 * 72;
    u16* clds = lds;   // 128*136 <= 2*128*72
    const int t = threadIdx.x;
    const int tile_m = blockIdx.x * 128;
    const int wave = t >> 6, l = t & 15, quad = (t >> 4) & 3;
    const int wr = wave >> 1, wc = wave & 1;
    f32x4 acc1[4][4] = {}, acc2[4][4] = {};

    for (int chunk = 0; chunk < 2; ++chunk) {
        const int c0 = chunk * 64;
        __syncthreads();
        for (int ci = t; ci < 1024; ci += 256) {
            int row = ci >> 3, kc = ci & 7;
            int grow = tile_m + row;
            uint4 v = make_uint4(0, 0, 0, 0);
            if (grow < nrows) v = load8(&in[(size_t)grow * HH + c0 + kc * 8]);
            *(uint4*)&a_lds[row * 72 + kc * 8] = v;
        }
        for (int ci = t; ci < 1024; ci += 256) {
            int n = ci >> 3, kc = ci & 7;
            *(uint4*)&b1_lds[n * 72 + kc * 8] = *(const uint4*)&WT1[(size_t)n * HH + c0 + kc * 8];
            *(uint4*)&b2_lds[n * 72 + kc * 8] = *(const uint4*)&WT2[(size_t)n * HH + c0 + kc * 8];
        }
        __syncthreads();
#pragma unroll
        for (int ks = 0; ks < 2; ++ks) {
            short8 af[4], bf1[4], bf2[4];
#pragma unroll
            for (int i = 0; i < 4; ++i)
                af[i] = *(const short8*)&a_lds[(wr * 64 + i * 16 + l) * 72 + ks * 32 + quad * 8];
#pragma unroll
            for (int j = 0; j < 4; ++j) {
                bf1[j] = *(const short8*)&b1_lds[(wc * 64 + j * 16 + l) * 72 + ks * 32 + quad * 8];
                bf2[j] = *(const short8*)&b2_lds[(wc * 64 + j * 16 + l) * 72 + ks * 32 + quad * 8];
            }
#pragma unroll
            for (int i = 0; i < 4; ++i)
#pragma unroll
                for (int j = 0; j < 4; ++j) {
                    acc1[i][j] = __builtin_amdgcn_mfma_f32_16x16x32_bf16(af[i], bf1[j], acc1[i][j], 0, 0, 0);
                    acc2[i][j] = __builtin_amdgcn_mfma_f32_16x16x32_bf16(af[i], bf2[j], acc2[i][j], 0, 0, 0);
                }
        }
    }
    // epilogue out1
    __syncthreads();
#pragma unroll
    for (int j = 0; j < 4; ++j) {
        int col = wc * 64 + j * 16 + l;
        float b = b1[col];
#pragma unroll
        for (int i = 0; i < 4; ++i) {
            int rloc = wr * 64 + i * 16 + quad * 4;
#pragma unroll
            for (int r = 0; r < 4; ++r)
                clds[(rloc + r) * 136 + col] = f2b(acc1[i][j][r] + b);
        }
    }
    __syncthreads();
#pragma unroll
    for (int it = 0; it < 8; ++it) {
        int idx = it * 256 + t;
        int row = idx >> 4, c16 = idx & 15;
        int grow = tile_m + row;
        if (grow < nrows)
            *(uint4*)&out1[(size_t)grow * HH + c16 * 8] = *(const uint4*)&clds[row * 136 + c16 * 8];
    }
    // epilogue out2
    __syncthreads();
#pragma unroll
    for (int j = 0; j < 4; ++j) {
        int col = wc * 64 + j * 16 + l;
        float b = b2[col];
#pragma unroll
        for (int i = 0; i < 4; ++i) {
            int rloc = wr * 64 + i * 16 + quad * 4;
#pragma unroll
            for (int r = 0; r < 4; ++r)
                clds[(rloc + r) * 136 + col] = f2b(acc2[i][j][r] + b);
        }
    }
    __syncthreads();
#pragma unroll
    for (int it = 0; it < 8; ++it) {
        int idx = it * 256 + t;
        int row = idx >> 4, c16 = idx & 15;
        int grow = tile_m + row;
        if (grow < nrows)
            *(uint4*)&out2[(size_t)grow * HH + c16 * 8] = *(const uint4*)&clds[row * 136 + c16 * 8];
    }
}

// ============ fused gathered GEMM ============
__global__ __launch_bounds__(256) void k_mfma_gproj(const u16* __restrict__ h,
                                                    const int* __restrict__ idx1,
                                                    const int* __restrict__ idx2,
                                                    const u16* __restrict__ WT1,
                                                    const u16* __restrict__ WT2,
                                                    const float* __restrict__ bias,
                                                    u16* __restrict__ out, int nrows) {
    __shared__ u16 lds[2][128 * 72];
    u16* a_lds = lds[0];
    u16* b_lds = lds[1];
    u16* clds = lds[0];
    const int t = threadIdx.x;
    const int tile_m = blockIdx.x * 128;
    const int wave = t >> 6, l = t & 15, quad = (t >> 4) & 3;
    const int wr = wave >> 1, wc = wave & 1;
    f32x4 acc[4][4] = {};

    for (int pass = 0; pass < 2; ++pass) {
        const int* idx = pass ? idx2 : idx1;
        const u16* WT = pass ? WT2 : WT1;
        for (int chunk = 0; chunk < 2; ++chunk) {
            const int c0 = chunk * 64;
            __syncthreads();
            for (int ci = t; ci < 1024; ci += 256) {
                int row = ci >> 3, kc = ci & 7;
                int item = tile_m + row;
                int g = (item < nrows) ? idx[item] : -1;
                uint4 v = make_uint4(0, 0, 0, 0);
                if (g >= 0) v = load8(&h[(size_t)g * HH + c0 + kc * 8]);
                *(uint4*)&a_lds[row * 72 + kc * 8] = v;
            }
            for (int ci = t; ci < 1024; ci += 256) {
                int n = ci >> 3, kc = ci & 7;
                *(uint4*)&b_lds[n * 72 + kc * 8] = *(const uint4*)&WT[(size_t)n * HH + c0 + kc * 8];
            }
            __syncthreads();
#pragma unroll
            for (int ks = 0; ks < 2; ++ks) {
                short8 af[4], bf[4];
#pragma unroll
                for (int i = 0; i < 4; ++i)
                    af[i] = *(const short8*)&a_lds[(wr * 64 + i * 16 + l) * 72 + ks * 32 + quad * 8];
#pragma unroll
                for (int j = 0; j < 4; ++j)
                    bf[j] = *(const short8*)&b_lds[(wc * 64 + j * 16 + l) * 72 + ks * 32 + quad * 8];
#pragma unroll
                for (int i = 0; i < 4; ++i)
#pragma unroll
                    for (int j = 0; j < 4; ++j)
                        acc[i][j] = __builtin_amdgcn_mfma_f32_16x16x32_bf16(af[i], bf[j], acc[i][j], 0, 0, 0);
            }
        }
    }
    __syncthreads();
#pragma unroll
    for (int j = 0; j < 4; ++j) {
        int col = wc * 64 + j * 16 + l;
        float b = bias[col];
#pragma unroll
        for (int i = 0; i < 4; ++i) {
            int rloc = wr * 64 + i * 16 + quad * 4;
#pragma unroll
            for (int r = 0; r < 4; ++r)
                clds[(rloc + r) * 136 + col] = f2b(acc[i][j][r] + b);
        }
    }
    __syncthreads();
#pragma unroll
    for (int it = 0; it < 8; ++it) {
        int idx = it * 256 + t;
        int row = idx >> 4, c16 = idx & 15;
        int item = tile_m + row;
        if (item < nrows)
            *(uint4*)&out[(size_t)item * HH + c16 * 8] = *(const uint4*)&clds[row * 136 + c16 * 8];
    }
}

// ============ MFMA z+logit ============
__global__ __launch_bounds__(256) void k_mfma_zlogit(const u16* __restrict__ branch,
                                                     const int* __restrict__ time_idx,
                                                     const float* __restrict__ tproj,
                                                     const float* __restrict__ c1,
                                                     const u16* __restrict__ WTa1,
                                                     const float* __restrict__ Wa2,
                                                     const float* __restrict__ ba2,
                                                     float* __restrict__ out) {
    __shared__ u16 a_lds[128 * 72];
    __shared__ u16 b_lds[128 * 72];
    __shared__ float red[2][128];
    const int t = threadIdx.x;
    const int tile_m = blockIdx.x * 128;
    const int wave = t >> 6, l = t & 15, quad = (t >> 4) & 3;
    const int wr = wave >> 1, wc = wave & 1;
    f32x4 acc[4][4] = {};

    for (int chunk = 0; chunk < 2; ++chunk) {
        const int c0 = chunk * 64;
        __syncthreads();
        for (int ci = t; ci < 1024; ci += 256) {
            int row = ci >> 3, kc = ci & 7;
            int item = tile_m + row;
            uint4 v = make_uint4(0, 0, 0, 0);
            if (item < AA) v = load8(&branch[(size_t)item * HH + c0 + kc * 8]);
            *(uint4*)&a_lds[row * 72 + kc * 8] = v;
        }
        for (int ci = t; ci < 1024; ci += 256) {
            int n = ci >> 3, kc = ci & 7;
            *(uint4*)&b_lds[n * 72 + kc * 8] = *(const uint4*)&WTa1[(size_t)n * HH + c0 + kc * 8];
        }
        __syncthreads();
#pragma unroll
        for (int ks = 0; ks < 2; ++ks) {
            short8 af[4], bf[4];
#pragma unroll
            for (int i = 0; i < 4; ++i)
                af[i] = *(const short8*)&a_lds[(wr * 64 + i * 16 + l) * 72 + ks * 32 + quad * 8];
#pragma unroll
            for (int j = 0; j < 4; ++j)
                bf[j] = *(const short8*)&b_lds[(wc * 64 + j * 16 + l) * 72 + ks * 32 + quad * 8];
#pragma unroll
            for (int i = 0; i < 4; ++i)
#pragma unroll
                for (int j = 0; j < 4; ++j)
                    acc[i][j] = __builtin_amdgcn_mfma_f32_16x16x32_bf16(af[i], bf[j], acc[i][j], 0, 0, 0);
        }
    }
    float c1v[4], wa2v[4];
#pragma unroll
    for (int j = 0; j < 4; ++j) {
        int col = wc * 64 + j * 16 + l;
        c1v[j] = c1[col];
        wa2v[j] = Wa2[col];
    }
#pragma unroll
    for (int i = 0; i < 4; ++i) {
        int rbase = tile_m + wr * 64 + i * 16 + quad * 4;
#pragma unroll
        for (int r = 0; r < 4; ++r) {
            int item = rbase + r;
            int ti = (item < AA) ? time_idx[item] : 0;
            const float* tp = tproj + (size_t)ti * HH;
            float partial = 0.f;
#pragma unroll
            for (int j = 0; j < 4; ++j) {
                int col = wc * 64 + j * 16 + l;
                float z = fmaxf(acc[i][j][r] + tp[col] + c1v[j], 0.f);
                partial = fmaf(z, wa2v[j], partial);
            }
            partial += __shfl_xor(partial, 1);
            partial += __shfl_xor(partial, 2);
            partial += __shfl_xor(partial, 4);
            partial += __shfl_xor(partial, 8);
            if (l == 0) red[wc][wr * 64 + i * 16 + quad * 4 + r] = partial;
        }
    }
    __syncthreads();
    if (t < 128) {
        int item = tile_m + t;
        if (item < AA) out[item] = red[0][t] + red[1][t] + ba2[0];
    }
}

// ============ fused GAT: single-pass online softmax + aggregation + h update ============
__global__ __launch_bounds__(256) void k_gat_fused(u16* __restrict__ h,
                                                   const u16* __restrict__ xl,
                                                   const u16* __restrict__ xr,
                                                   const int* __restrict__ offs,
                                                   const int* __restrict__ elist,
                                                   const float* __restrict__ att,
                                                   const float* __restrict__ bias) {
    int g = blockIdx.x * 16 + (threadIdx.x >> 4);   // dst node (NN divisible by 16)
    int l = threadIdx.x & 15;
    float attv[8], biasv[8];
    *(float4*)&attv[0] = *(const float4*)&att[l * 8];
    *(float4*)&attv[4] = *(const float4*)&att[l * 8 + 4];
    *(float4*)&biasv[0] = *(const float4*)&bias[l * 8];
    *(float4*)&biasv[4] = *(const float4*)&bias[l * 8 + 4];
    float xrf[8];
    unpack8(*(const uint4*)&xr[(size_t)g * HH + l * 8], xrf);
    int e0 = offs[g], e1 = offs[g + 1];

    // single pass: online softmax with accumulator rescale
    float m = -__builtin_inff(), s = 0.f;
    float acc[8] = {};
    for (int e = e0; e < e1; ++e) {
        int sidx = elist[e];
        float xf[8];
        unpack8(*(const uint4*)&xl[(size_t)sidx * HH + l * 8], xf);
        float p = 0.f;
#pragma unroll
        for (int j = 0; j < 8; ++j) {
            float v = xf[j] + xrf[j];
            v = v >= 0.f ? v : 0.2f * v;
            p = fmaf(v, attv[j], p);
        }
        p += __shfl_xor(p, 1); p += __shfl_xor(p, 2);
        p += __shfl_xor(p, 4); p += __shfl_xor(p, 8);
        float mn = fmaxf(m, p);
        float so = __expf(m - mn);     // first edge: exp(-inf)=0
        float w = __expf(p - mn);
        s = s * so + w;
#pragma unroll
        for (int j = 0; j < 8; ++j) acc[j] = fmaf(acc[j], so, w * xf[j]);
        m = mn;
    }
    float inv = 1.f / (s + 1e-16f);

    // h[g] += relu(acc*inv + bias)
    float hf[8];
    unpack8(*(const uint4*)&h[(size_t)g * HH + l * 8], hf);
    union { ushort sh[8]; uint4 v; } o;
#pragma unroll
    for (int j = 0; j < 8; ++j) {
        hf[j] += fmaxf(fmaf(acc[j], inv, biasv[j]), 0.f);
        o.sh[j] = f2b(hf[j]);
    }
    *(uint4*)&h[(size_t)g * HH + l * 8] = o.v;
}

// ---------- host side ----------
typedef const float* fp;

static void build_csr(const int* src, const int* dst, int* offs, int* elist,
                      int* work, int* bsum, hipStream_t stream) {
    hipMemsetAsync(work, 0, (size_t)NN * 4, stream);
    k_hist<<<(EE + 255) / 256, 256, 0, stream>>>(dst, work);
    k_scan_block<<<SCAN_NB, 256, 0, stream>>>(work, offs, bsum, NN);
    k_scan_top<<<1, 256, 0, stream>>>(bsum, SCAN_NB);
    k_scan_add<<<(NN + 255) / 256, 256, 0, stream>>>(offs, bsum, NN);
    hipMemcpyAsync(work, offs, (size_t)NN * 4, hipMemcpyDeviceToDevice, stream);
    k_scatter<<<(EE + 255) / 256, 256, 0, stream>>>(src, dst, work, elist);
}

extern "C" void kernel_launch(void* const* d_in, const int* in_sizes, int n_in,
                              void* d_out, int out_size, void* d_ws, size_t ws_size,
                              hipStream_t stream) {
    fp x                 = (fp)d_in[0];
    const int* ei        = (const int*)d_in[1];
    fp focal             = (fp)d_in[2];
    const int* child_idx = (const int*)d_in[3];
    const int* parent_idx= (const int*)d_in[4];
    const int* time_idx  = (const int*)d_in[5];
    fp W_embed = (fp)d_in[6],  b_embed = (fp)d_in[7];
    fp bu_Wl   = (fp)d_in[8],  bu_bl   = (fp)d_in[9];
    fp bu_Wr   = (fp)d_in[10], bu_br   = (fp)d_in[11];
    fp bu_att  = (fp)d_in[12], bu_bias = (fp)d_in[13];
    fp td_Wl   = (fp)d_in[14], td_bl   = (fp)d_in[15];
    fp td_Wr   = (fp)d_in[16], td_br   = (fp)d_in[17];
    fp td_att  = (fp)d_in[18], td_bias = (fp)d_in[19];
    fp time_table = (fp)d_in[20];
    fp W_comb  = (fp)d_in[21], b_comb  = (fp)d_in[22];
    fp W_a1    = (fp)d_in[23], b_a1    = (fp)d_in[24];
    fp W_a2    = (fp)d_in[25], b_a2    = (fp)d_in[26];
    fp W_seq   = (fp)d_in[27], b_seq   = (fp)d_in[28];

    const size_t NH = (size_t)NN * HH;
    u16* wt = (u16*)d_ws;                 // 8 x 16384 u16 (256 KB)
    u16* h  = wt + 8 * 16384;             // N*H bf16
    u16* xl = h + NH;
    u16* xr = xl + NH;
    u16* branch = xl;                     // A*H bf16, aliases xl
    float* ctx   = (float*)(xr + NH);     // H
    float* c1v   = ctx + HH;              // H
    float* tproj = c1v + HH;              // T*H
    int* offsBU  = (int*)(tproj + (size_t)TT * HH);  // N+1
    int* offsTD  = offsBU + NN + 1;                  // N+1
    int* elistBU = offsTD + NN + 1;                  // E
    int* elistTD = elistBU + EE;                     // E
    int* csr_work= elistTD + EE;                     // N
    int* bsum    = csr_work + NN;                    // SCAN_NB

    // CSR build: BU dst=ei[0] src=ei[1]; TD dst=ei[1] src=ei[0]
    build_csr(ei + EE, ei, offsBU, elistBU, csr_work, bsum, stream);
    build_csr(ei, ei + EE, offsTD, elistTD, csr_work, bsum, stream);
    k_settail<<<1, 64, 0, stream>>>(offsBU, offsTD);

    // pre-transpose all GEMM weights to bf16 [n][k]
    k_wtrans<<<64, 256, 0, stream>>>(bu_Wl, bu_Wr, td_Wl, td_Wr,
                                     W_comb, W_comb + (size_t)HH * HH, W_a1, W_embed, wt);
    const u16* wt_buWl = wt + 0 * 16384;
    const u16* wt_buWr = wt + 1 * 16384;
    const u16* wt_tdWl = wt + 2 * 16384;
    const u16* wt_tdWr = wt + 3 * 16384;
    const u16* wt_combC = wt + 4 * 16384;
    const u16* wt_combP = wt + 5 * 16384;
    const u16* wt_a1   = wt + 6 * 16384;
    const u16* wt_embed = wt + 7 * 16384;

    // small precomputes
    k_context<<<1, 128, 0, stream>>>(focal, W_seq, b_seq, ctx);
    k_c1<<<1, 128, 0, stream>>>(ctx, W_a1 + (size_t)256 * HH, b_a1, c1v);
    k_tproj<<<TT, 128, 0, stream>>>(time_table, W_a1 + (size_t)128 * HH, tproj);

    const int NB = (NN + 127) / 128;
    // embed
    k_mfma_proj<64, float><<<NB, 256, 0, stream>>>(x, wt_embed, b_embed, h, NN);

    // bottom-up GAT
    k_mfma_proj2<<<NB, 256, 0, stream>>>(h, wt_buWl, wt_buWr, bu_bl, bu_br, xl, xr, NN);
    k_gat_fused<<<NN / 16, 256, 0, stream>>>(h, xl, xr, offsBU, elistBU, bu_att, bu_bias);

    // top-down GAT
    k_mfma_proj2<<<NB, 256, 0, stream>>>(h, wt_tdWl, wt_tdWr, td_bl, td_br, xl, xr, NN);
    k_gat_fused<<<NN / 16, 256, 0, stream>>>(h, xl, xr, offsTD, elistTD, td_att, td_bias);

    // branch = h[child]@Wc + h[parent]@Wp + b_comb
    k_mfma_gproj<<<(AA + 127) / 128, 256, 0, stream>>>(
        h, child_idx, parent_idx, wt_combC, wt_combP, b_comb, branch, AA);

    // logits
    k_mfma_zlogit<<<(AA + 127) / 128, 256, 0, stream>>>(
        branch, time_idx, tproj, c1v, wt_a1, W_a2, b_a2, (float*)d_out);
}

// Round 9
// 632.687 us; speedup vs baseline: 6.0649x; 1.0008x over previous
//
#include <hip/hip_runtime.h>
#include <hip/hip_bf16.h>

#define NN 300000
#define EE 299999
#define AA 150000
#define DD 64
#define HH 128
#define TT 512
#define SCAN_NB ((NN + 1023) / 1024)

typedef unsigned short u16;
typedef unsigned int u32;
typedef __attribute__((ext_vector_type(8))) short short8;
typedef __attribute__((ext_vector_type(4))) float f32x4;

// ---------- helpers ----------
__device__ __forceinline__ float bfb(u16 u) { return __uint_as_float(((u32)u) << 16); }
__device__ __forceinline__ u16 f2b(float f) {
    u32 u = __float_as_uint(f);
    u32 r = (u + 0x7FFFu + ((u >> 16) & 1u)) >> 16;
    return (u16)r;
}
__device__ __forceinline__ uint4 load8(const u16* p) { return *(const uint4*)p; }
__device__ __forceinline__ uint4 load8(const float* p) {
    float4 f1 = *(const float4*)p;
    float4 f2 = *(const float4*)(p + 4);
    union { ushort s[8]; uint4 v; } u;
    u.s[0] = f2b(f1.x); u.s[1] = f2b(f1.y); u.s[2] = f2b(f1.z); u.s[3] = f2b(f1.w);
    u.s[4] = f2b(f2.x); u.s[5] = f2b(f2.y); u.s[6] = f2b(f2.z); u.s[7] = f2b(f2.w);
    return u.v;
}
__device__ __forceinline__ void unpack8(uint4 v, float* f) {
    u32 w0 = v.x, w1 = v.y, w2 = v.z, w3 = v.w;
    f[0] = bfb((u16)w0); f[1] = bfb((u16)(w0 >> 16));
    f[2] = bfb((u16)w1); f[3] = bfb((u16)(w1 >> 16));
    f[4] = bfb((u16)w2); f[5] = bfb((u16)(w2 >> 16));
    f[6] = bfb((u16)w3); f[7] = bfb((u16)(w3 >> 16));
}
// XOR-swizzled LDS offset (u16 units): 128 rows x 64 k, 16B-aligned, conflict-free
__device__ __forceinline__ int swo(int row, int kblock) {
    return row * 64 + ((kblock ^ (row & 7)) * 8);
}

// ---------- weight pre-transpose ----------
__global__ __launch_bounds__(256) void k_wtrans(const float* w0, const float* w1,
                                                const float* w2, const float* w3,
                                                const float* w4, const float* w5,
                                                const float* w6, const float* w7,
                                                u16* __restrict__ wt) {
    int widx = blockIdx.x >> 3, part = blockIdx.x & 7;
    const float* W; int K = 128;
    switch (widx) {
        case 0: W = w0; break; case 1: W = w1; break;
        case 2: W = w2; break; case 3: W = w3; break;
        case 4: W = w4; break; case 5: W = w5; break;
        case 6: W = w6; break; default: W = w7; K = 64; break;
    }
    u16* dst = wt + widx * 16384;
    int total = K * 128;
    int lo = part * 2048, hi = lo + 2048;
    if (hi > total) hi = total;
    for (int idx = lo + threadIdx.x; idx < hi; idx += 256) {
        int k = idx >> 7, n = idx & 127;
        dst[n * K + k] = f2b(W[k * 128 + n]);
    }
}

// ---------- tiny precomputes ----------
__global__ void k_context(const float* __restrict__ focal, const float* __restrict__ Wseq,
                          const float* __restrict__ bseq, float* __restrict__ ctx) {
    int t = threadIdx.x;
    float acc = bseq[t];
    for (int d = 0; d < DD; ++d) acc = fmaf(focal[d], Wseq[d * HH + t], acc);
    ctx[t] = acc;
}

__global__ void k_c1(const float* __restrict__ ctx, const float* __restrict__ Wa1c,
                     const float* __restrict__ ba1, float* __restrict__ c1) {
    int t = threadIdx.x;
    float acc = ba1[t];
    for (int k = 0; k < HH; ++k) acc = fmaf(ctx[k], Wa1c[k * HH + t], acc);
    c1[t] = acc;
}

__global__ void k_tproj(const float* __restrict__ tt, const float* __restrict__ Wa1m,
                        float* __restrict__ tproj) {
    int ti = blockIdx.x, t = threadIdx.x;
    float acc = 0.f;
    for (int k = 0; k < HH; ++k)
        acc = fmaf(tt[ti * HH + k], Wa1m[k * HH + t], acc);
    tproj[(size_t)ti * HH + t] = acc;
}

// ---------- CSR build ----------
__global__ void k_hist(const int* __restrict__ dst, int* __restrict__ counts) {
    int e = blockIdx.x * 256 + threadIdx.x;
    if (e < EE) atomicAdd(&counts[dst[e]], 1);
}

__global__ __launch_bounds__(256) void k_scan_block(const int* __restrict__ in,
                                                    int* __restrict__ out,
                                                    int* __restrict__ bsum, int n) {
    __shared__ int sh[256];
    int b = blockIdx.x, t = threadIdx.x;
    int base = b * 1024 + t * 4;
    int v0 = (base + 0 < n) ? in[base + 0] : 0;
    int v1 = (base + 1 < n) ? in[base + 1] : 0;
    int v2 = (base + 2 < n) ? in[base + 2] : 0;
    int v3 = (base + 3 < n) ? in[base + 3] : 0;
    int tsum = v0 + v1 + v2 + v3;
    sh[t] = tsum;
    __syncthreads();
    for (int d = 1; d < 256; d <<= 1) {
        int x = (t >= d) ? sh[t - d] : 0;
        __syncthreads();
        sh[t] += x;
        __syncthreads();
    }
    int excl = sh[t] - tsum;
    if (t == 255) bsum[b] = sh[255];
    if (base + 0 < n) out[base + 0] = excl;
    if (base + 1 < n) out[base + 1] = excl + v0;
    if (base + 2 < n) out[base + 2] = excl + v0 + v1;
    if (base + 3 < n) out[base + 3] = excl + v0 + v1 + v2;
}

__global__ __launch_bounds__(256) void k_scan_top(int* __restrict__ data, int n) {
    __shared__ int sh[256];
    int t = threadIdx.x;
    int base = t * 4;
    int v0 = (base + 0 < n) ? data[base + 0] : 0;
    int v1 = (base + 1 < n) ? data[base + 1] : 0;
    int v2 = (base + 2 < n) ? data[base + 2] : 0;
    int v3 = (base + 3 < n) ? data[base + 3] : 0;
    int tsum = v0 + v1 + v2 + v3;
    sh[t] = tsum;
    __syncthreads();
    for (int d = 1; d < 256; d <<= 1) {
        int x = (t >= d) ? sh[t - d] : 0;
        __syncthreads();
        sh[t] += x;
        __syncthreads();
    }
    int excl = sh[t] - tsum;
    if (base + 0 < n) data[base + 0] = excl;
    if (base + 1 < n) data[base + 1] = excl + v0;
    if (base + 2 < n) data[base + 2] = excl + v0 + v1;
    if (base + 3 < n) data[base + 3] = excl + v0 + v1 + v2;
}

__global__ void k_scan_add(int* __restrict__ out, const int* __restrict__ bsum, int n) {
    int i = blockIdx.x * 256 + threadIdx.x;
    if (i < n) out[i] += bsum[i >> 10];
}

__global__ void k_settail(int* o1, int* o2) {
    if (threadIdx.x == 0) { o1[NN] = EE; o2[NN] = EE; }
}

__global__ void k_scatter(const int* __restrict__ src, const int* __restrict__ dst,
                          int* __restrict__ cursor, int* __restrict__ elist) {
    int e = blockIdx.x * 256 + threadIdx.x;
    if (e >= EE) return;
    int pos = atomicAdd(&cursor[dst[e]], 1);
    elist[pos] = src[e];
}

// ============ MFMA GEMM (single weight): out_bf16 = in @ W + b ============
template <int K, typename InT>
__global__ __launch_bounds__(256) void k_mfma_proj(const InT* __restrict__ in,
                                                   const u16* __restrict__ WT,
                                                   const float* __restrict__ bias,
                                                   u16* __restrict__ out, int nrows) {
    __shared__ u16 lds[17408];          // a[8192] + b[8192]; C-repack overlay needs 17408
    u16* a_lds = lds;
    u16* b_lds = lds + 8192;
    u16* clds = lds;
    const int t = threadIdx.x;
    const int tile_m = blockIdx.x * 128;
    const int wave = t >> 6, l = t & 15, quad = (t >> 4) & 3;
    const int wr = wave >> 1, wc = wave & 1;
    f32x4 acc[4][4] = {};

    for (int chunk = 0; chunk < K / 64; ++chunk) {
        const int c0 = chunk * 64;
        __syncthreads();
        for (int ci = t; ci < 1024; ci += 256) {
            int row = ci >> 3, kc = ci & 7;
            int grow = tile_m + row;
            uint4 v = make_uint4(0, 0, 0, 0);
            if (grow < nrows) v = load8(&in[(size_t)grow * K + c0 + kc * 8]);
            *(uint4*)&a_lds[swo(row, kc)] = v;
        }
        for (int ci = t; ci < 1024; ci += 256) {
            int n = ci >> 3, kc = ci & 7;
            *(uint4*)&b_lds[swo(n, kc)] = *(const uint4*)&WT[(size_t)n * K + c0 + kc * 8];
        }
        __syncthreads();
#pragma unroll
        for (int ks = 0; ks < 2; ++ks) {
            short8 af[4], bf[4];
#pragma unroll
            for (int i = 0; i < 4; ++i)
                af[i] = *(const short8*)&a_lds[swo(wr * 64 + i * 16 + l, ks * 4 + quad)];
#pragma unroll
            for (int j = 0; j < 4; ++j)
                bf[j] = *(const short8*)&b_lds[swo(wc * 64 + j * 16 + l, ks * 4 + quad)];
#pragma unroll
            for (int i = 0; i < 4; ++i)
#pragma unroll
                for (int j = 0; j < 4; ++j)
                    acc[i][j] = __builtin_amdgcn_mfma_f32_16x16x32_bf16(af[i], bf[j], acc[i][j], 0, 0, 0);
        }
    }
    __syncthreads();
#pragma unroll
    for (int j = 0; j < 4; ++j) {
        int col = wc * 64 + j * 16 + l;
        float b = bias[col];
#pragma unroll
        for (int i = 0; i < 4; ++i) {
            int rloc = wr * 64 + i * 16 + quad * 4;
#pragma unroll
            for (int r = 0; r < 4; ++r)
                clds[(rloc + r) * 136 + col] = f2b(acc[i][j][r] + b);
        }
    }
    __syncthreads();
#pragma unroll
    for (int it = 0; it < 8; ++it) {
        int idx = it * 256 + t;
        int row = idx >> 4, c16 = idx & 15;
        int grow = tile_m + row;
        if (grow < nrows)
            *(uint4*)&out[(size_t)grow * HH + c16 * 8] = *(const uint4*)&clds[row * 136 + c16 * 8];
    }
}

// ============ fused dual GEMM: xl = h@Wl+bl, xr = h@Wr+br (A staged once) ============
__global__ __launch_bounds__(256) void k_mfma_proj2(const u16* __restrict__ in,
                                                    const u16* __restrict__ WT1,
                                                    const u16* __restrict__ WT2,
                                                    const float* __restrict__ b1,
                                                    const float* __restrict__ b2,
                                                    u16* __restrict__ out1,
                                                    u16* __restrict__ out2, int nrows) {
    __shared__ u16 lds[24576];          // a + b1 + b2 (swizzled, 49152 B -> 3 blocks/CU)
    u16* a_lds = lds;
    u16* b1_lds = lds + 8192;
    u16* b2_lds = lds + 16384;
    u16* clds = lds;                    // C-repack overlay (17408 u16)
    const int t = threadIdx.x;
    const int tile_m = blockIdx.x * 128;
    const int wave = t >> 6, l = t & 15, quad = (t >> 4) & 3;
    const int wr = wave >> 1, wc = wave & 1;
    f32x4 acc1[4][4] = {}, acc2[4][4] = {};

    for (int chunk = 0; chunk < 2; ++chunk) {
        const int c0 = chunk * 64;
        __syncthreads();
        for (int ci = t; ci < 1024; ci += 256) {
            int row = ci >> 3, kc = ci & 7;
            int grow = tile_m + row;
            uint4 v = make_uint4(0, 0, 0, 0);
            if (grow < nrows) v = load8(&in[(size_t)grow * HH + c0 + kc * 8]);
            *(uint4*)&a_lds[swo(row, kc)] = v;
        }
        for (int ci = t; ci < 1024; ci += 256) {
            int n = ci >> 3, kc = ci & 7;
            *(uint4*)&b1_lds[swo(n, kc)] = *(const uint4*)&WT1[(size_t)n * HH + c0 + kc * 8];
            *(uint4*)&b2_lds[swo(n, kc)] = *(const uint4*)&WT2[(size_t)n * HH + c0 + kc * 8];
        }
        __syncthreads();
#pragma unroll
        for (int ks = 0; ks < 2; ++ks) {
            short8 af[4], bf1[4], bf2[4];
#pragma unroll
            for (int i = 0; i < 4; ++i)
                af[i] = *(const short8*)&a_lds[swo(wr * 64 + i * 16 + l, ks * 4 + quad)];
#pragma unroll
            for (int j = 0; j < 4; ++j) {
                bf1[j] = *(const short8*)&b1_lds[swo(wc * 64 + j * 16 + l, ks * 4 + quad)];
                bf2[j] = *(const short8*)&b2_lds[swo(wc * 64 + j * 16 + l, ks * 4 + quad)];
            }
#pragma unroll
            for (int i = 0; i < 4; ++i)
#pragma unroll
                for (int j = 0; j < 4; ++j) {
                    acc1[i][j] = __builtin_amdgcn_mfma_f32_16x16x32_bf16(af[i], bf1[j], acc1[i][j], 0, 0, 0);
                    acc2[i][j] = __builtin_amdgcn_mfma_f32_16x16x32_bf16(af[i], bf2[j], acc2[i][j], 0, 0, 0);
                }
        }
    }
    // epilogue out1
    __syncthreads();
#pragma unroll
    for (int j = 0; j < 4; ++j) {
        int col = wc * 64 + j * 16 + l;
        float b = b1[col];
#pragma unroll
        for (int i = 0; i < 4; ++i) {
            int rloc = wr * 64 + i * 16 + quad * 4;
#pragma unroll
            for (int r = 0; r < 4; ++r)
                clds[(rloc + r) * 136 + col] = f2b(acc1[i][j][r] + b);
        }
    }
    __syncthreads();
#pragma unroll
    for (int it = 0; it < 8; ++it) {
        int idx = it * 256 + t;
        int row = idx >> 4, c16 = idx & 15;
        int grow = tile_m + row;
        if (grow < nrows)
            *(uint4*)&out1[(size_t)grow * HH + c16 * 8] = *(const uint4*)&clds[row * 136 + c16 * 8];
    }
    // epilogue out2
    __syncthreads();
#pragma unroll
    for (int j = 0; j < 4; ++j) {
        int col = wc * 64 + j * 16 + l;
        float b = b2[col];
#pragma unroll
        for (int i = 0; i < 4; ++i) {
            int rloc = wr * 64 + i * 16 + quad * 4;
#pragma unroll
            for (int r = 0; r < 4; ++r)
                clds[(rloc + r) * 136 + col] = f2b(acc2[i][j][r] + b);
        }
    }
    __syncthreads();
#pragma unroll
    for (int it = 0; it < 8; ++it) {
        int idx = it * 256 + t;
        int row = idx >> 4, c16 = idx & 15;
        int grow = tile_m + row;
        if (grow < nrows)
            *(uint4*)&out2[(size_t)grow * HH + c16 * 8] = *(const uint4*)&clds[row * 136 + c16 * 8];
    }
}

// ============ fused gathered GEMM ============
__global__ __launch_bounds__(256) void k_mfma_gproj(const u16* __restrict__ h,
                                                    const int* __restrict__ idx1,
                                                    const int* __restrict__ idx2,
                                                    const u16* __restrict__ WT1,
                                                    const u16* __restrict__ WT2,
                                                    const float* __restrict__ bias,
                                                    u16* __restrict__ out, int nrows) {
    __shared__ u16 lds[17408];
    u16* a_lds = lds;
    u16* b_lds = lds + 8192;
    u16* clds = lds;
    const int t = threadIdx.x;
    const int tile_m = blockIdx.x * 128;
    const int wave = t >> 6, l = t & 15, quad = (t >> 4) & 3;
    const int wr = wave >> 1, wc = wave & 1;
    f32x4 acc[4][4] = {};

    for (int pass = 0; pass < 2; ++pass) {
        const int* idx = pass ? idx2 : idx1;
        const u16* WT = pass ? WT2 : WT1;
        for (int chunk = 0; chunk < 2; ++chunk) {
            const int c0 = chunk * 64;
            __syncthreads();
            for (int ci = t; ci < 1024; ci += 256) {
                int row = ci >> 3, kc = ci & 7;
                int item = tile_m + row;
                int g = (item < nrows) ? idx[item] : -1;
                uint4 v = make_uint4(0, 0, 0, 0);
                if (g >= 0) v = load8(&h[(size_t)g * HH + c0 + kc * 8]);
                *(uint4*)&a_lds[swo(row, kc)] = v;
            }
            for (int ci = t; ci < 1024; ci += 256) {
                int n = ci >> 3, kc = ci & 7;
                *(uint4*)&b_lds[swo(n, kc)] = *(const uint4*)&WT[(size_t)n * HH + c0 + kc * 8];
            }
            __syncthreads();
#pragma unroll
            for (int ks = 0; ks < 2; ++ks) {
                short8 af[4], bf[4];
#pragma unroll
                for (int i = 0; i < 4; ++i)
                    af[i] = *(const short8*)&a_lds[swo(wr * 64 + i * 16 + l, ks * 4 + quad)];
#pragma unroll
                for (int j = 0; j < 4; ++j)
                    bf[j] = *(const short8*)&b_lds[swo(wc * 64 + j * 16 + l, ks * 4 + quad)];
#pragma unroll
                for (int i = 0; i < 4; ++i)
#pragma unroll
                    for (int j = 0; j < 4; ++j)
                        acc[i][j] = __builtin_amdgcn_mfma_f32_16x16x32_bf16(af[i], bf[j], acc[i][j], 0, 0, 0);
            }
        }
    }
    __syncthreads();
#pragma unroll
    for (int j = 0; j < 4; ++j) {
        int col = wc * 64 + j * 16 + l;
        float b = bias[col];
#pragma unroll
        for (int i = 0; i < 4; ++i) {
            int rloc = wr * 64 + i * 16 + quad * 4;
#pragma unroll
            for (int r = 0; r < 4; ++r)
                clds[(rloc + r) * 136 + col] = f2b(acc[i][j][r] + b);
        }
    }
    __syncthreads();
#pragma unroll
    for (int it = 0; it < 8; ++it) {
        int idx = it * 256 + t;
        int row = idx >> 4, c16 = idx & 15;
        int item = tile_m + row;
        if (item < nrows)
            *(uint4*)&out[(size_t)item * HH + c16 * 8] = *(const uint4*)&clds[row * 136 + c16 * 8];
    }
}

// ============ MFMA z+logit ============
__global__ __launch_bounds__(256) void k_mfma_zlogit(const u16* __restrict__ branch,
                                                     const int* __restrict__ time_idx,
                                                     const float* __restrict__ tproj,
                                                     const float* __restrict__ c1,
                                                     const u16* __restrict__ WTa1,
                                                     const float* __restrict__ Wa2,
                                                     const float* __restrict__ ba2,
                                                     float* __restrict__ out) {
    __shared__ u16 lds[16384];
    u16* a_lds = lds;
    u16* b_lds = lds + 8192;
    __shared__ float red[2][128];
    const int t = threadIdx.x;
    const int tile_m = blockIdx.x * 128;
    const int wave = t >> 6, l = t & 15, quad = (t >> 4) & 3;
    const int wr = wave >> 1, wc = wave & 1;
    f32x4 acc[4][4] = {};

    for (int chunk = 0; chunk < 2; ++chunk) {
        const int c0 = chunk * 64;
        __syncthreads();
        for (int ci = t; ci < 1024; ci += 256) {
            int row = ci >> 3, kc = ci & 7;
            int item = tile_m + row;
            uint4 v = make_uint4(0, 0, 0, 0);
            if (item < AA) v = load8(&branch[(size_t)item * HH + c0 + kc * 8]);
            *(uint4*)&a_lds[swo(row, kc)] = v;
        }
        for (int ci = t; ci < 1024; ci += 256) {
            int n = ci >> 3, kc = ci & 7;
            *(uint4*)&b_lds[swo(n, kc)] = *(const uint4*)&WTa1[(size_t)n * HH + c0 + kc * 8];
        }
        __syncthreads();
#pragma unroll
        for (int ks = 0; ks < 2; ++ks) {
            short8 af[4], bf[4];
#pragma unroll
            for (int i = 0; i < 4; ++i)
                af[i] = *(const short8*)&a_lds[swo(wr * 64 + i * 16 + l, ks * 4 + quad)];
#pragma unroll
            for (int j = 0; j < 4; ++j)
                bf[j] = *(const short8*)&b_lds[swo(wc * 64 + j * 16 + l, ks * 4 + quad)];
#pragma unroll
            for (int i = 0; i < 4; ++i)
#pragma unroll
                for (int j = 0; j < 4; ++j)
                    acc[i][j] = __builtin_amdgcn_mfma_f32_16x16x32_bf16(af[i], bf[j], acc[i][j], 0, 0, 0);
        }
    }
    float c1v[4], wa2v[4];
#pragma unroll
    for (int j = 0; j < 4; ++j) {
        int col = wc * 64 + j * 16 + l;
        c1v[j] = c1[col];
        wa2v[j] = Wa2[col];
    }
#pragma unroll
    for (int i = 0; i < 4; ++i) {
        int rbase = tile_m + wr * 64 + i * 16 + quad * 4;
#pragma unroll
        for (int r = 0; r < 4; ++r) {
            int item = rbase + r;
            int ti = (item < AA) ? time_idx[item] : 0;
            const float* tp = tproj + (size_t)ti * HH;
            float partial = 0.f;
#pragma unroll
            for (int j = 0; j < 4; ++j) {
                int col = wc * 64 + j * 16 + l;
                float z = fmaxf(acc[i][j][r] + tp[col] + c1v[j], 0.f);
                partial = fmaf(z, wa2v[j], partial);
            }
            partial += __shfl_xor(partial, 1);
            partial += __shfl_xor(partial, 2);
            partial += __shfl_xor(partial, 4);
            partial += __shfl_xor(partial, 8);
            if (l == 0) red[wc][wr * 64 + i * 16 + quad * 4 + r] = partial;
        }
    }
    __syncthreads();
    if (t < 128) {
        int item = tile_m + t;
        if (item < AA) out[item] = red[0][t] + red[1][t] + ba2[0];
    }
}

// ============ fused GAT: single-pass online softmax + aggregation + h update ============
__global__ __launch_bounds__(256) void k_gat_fused(u16* __restrict__ h,
                                                   const u16* __restrict__ xl,
                                                   const u16* __restrict__ xr,
                                                   const int* __restrict__ offs,
                                                   const int* __restrict__ elist,
                                                   const float* __restrict__ att,
                                                   const float* __restrict__ bias) {
    int g = blockIdx.x * 16 + (threadIdx.x >> 4);   // dst node (NN divisible by 16)
    int l = threadIdx.x & 15;
    float attv[8], biasv[8];
    *(float4*)&attv[0] = *(const float4*)&att[l * 8];
    *(float4*)&attv[4] = *(const float4*)&att[l * 8 + 4];
    *(float4*)&biasv[0] = *(const float4*)&bias[l * 8];
    *(float4*)&biasv[4] = *(const float4*)&bias[l * 8 + 4];
    float xrf[8];
    unpack8(*(const uint4*)&xr[(size_t)g * HH + l * 8], xrf);
    int e0 = offs[g], e1 = offs[g + 1];

    float m = -__builtin_inff(), s = 0.f;
    float acc[8] = {};
    for (int e = e0; e < e1; ++e) {
        int sidx = elist[e];
        float xf[8];
        unpack8(*(const uint4*)&xl[(size_t)sidx * HH + l * 8], xf);
        float p = 0.f;
#pragma unroll
        for (int j = 0; j < 8; ++j) {
            float v = xf[j] + xrf[j];
            v = v >= 0.f ? v : 0.2f * v;
            p = fmaf(v, attv[j], p);
        }
        p += __shfl_xor(p, 1); p += __shfl_xor(p, 2);
        p += __shfl_xor(p, 4); p += __shfl_xor(p, 8);
        float mn = fmaxf(m, p);
        float so = __expf(m - mn);
        float w = __expf(p - mn);
        s = s * so + w;
#pragma unroll
        for (int j = 0; j < 8; ++j) acc[j] = fmaf(acc[j], so, w * xf[j]);
        m = mn;
    }
    float inv = 1.f / (s + 1e-16f);

    float hf[8];
    unpack8(*(const uint4*)&h[(size_t)g * HH + l * 8], hf);
    union { ushort sh[8]; uint4 v; } o;
#pragma unroll
    for (int j = 0; j < 8; ++j) {
        hf[j] += fmaxf(fmaf(acc[j], inv, biasv[j]), 0.f);
        o.sh[j] = f2b(hf[j]);
    }
    *(uint4*)&h[(size_t)g * HH + l * 8] = o.v;
}

// ---------- host side ----------
typedef const float* fp;

static void build_csr(const int* src, const int* dst, int* offs, int* elist,
                      int* work, int* bsum, hipStream_t stream) {
    hipMemsetAsync(work, 0, (size_t)NN * 4, stream);
    k_hist<<<(EE + 255) / 256, 256, 0, stream>>>(dst, work);
    k_scan_block<<<SCAN_NB, 256, 0, stream>>>(work, offs, bsum, NN);
    k_scan_top<<<1, 256, 0, stream>>>(bsum, SCAN_NB);
    k_scan_add<<<(NN + 255) / 256, 256, 0, stream>>>(offs, bsum, NN);
    hipMemcpyAsync(work, offs, (size_t)NN * 4, hipMemcpyDeviceToDevice, stream);
    k_scatter<<<(EE + 255) / 256, 256, 0, stream>>>(src, dst, work, elist);
}

extern "C" void kernel_launch(void* const* d_in, const int* in_sizes, int n_in,
                              void* d_out, int out_size, void* d_ws, size_t ws_size,
                              hipStream_t stream) {
    fp x                 = (fp)d_in[0];
    const int* ei        = (const int*)d_in[1];
    fp focal             = (fp)d_in[2];
    const int* child_idx = (const int*)d_in[3];
    const int* parent_idx= (const int*)d_in[4];
    const int* time_idx  = (const int*)d_in[5];
    fp W_embed = (fp)d_in[6],  b_embed = (fp)d_in[7];
    fp bu_Wl   = (fp)d_in[8],  bu_bl   = (fp)d_in[9];
    fp bu_Wr   = (fp)d_in[10], bu_br   = (fp)d_in[11];
    fp bu_att  = (fp)d_in[12], bu_bias = (fp)d_in[13];
    fp td_Wl   = (fp)d_in[14], td_bl   = (fp)d_in[15];
    fp td_Wr   = (fp)d_in[16], td_br   = (fp)d_in[17];
    fp td_att  = (fp)d_in[18], td_bias = (fp)d_in[19];
    fp time_table = (fp)d_in[20];
    fp W_comb  = (fp)d_in[21], b_comb  = (fp)d_in[22];
    fp W_a1    = (fp)d_in[23], b_a1    = (fp)d_in[24];
    fp W_a2    = (fp)d_in[25], b_a2    = (fp)d_in[26];
    fp W_seq   = (fp)d_in[27], b_seq   = (fp)d_in[28];

    const size_t NH = (size_t)NN * HH;
    u16* wt = (u16*)d_ws;                 // 8 x 16384 u16 (256 KB)
    u16* h  = wt + 8 * 16384;             // N*H bf16
    u16* xl = h + NH;
    u16* xr = xl + NH;
    u16* branch = xl;                     // A*H bf16, aliases xl
    float* ctx   = (float*)(xr + NH);     // H
    float* c1v   = ctx + HH;              // H
    float* tproj = c1v + HH;              // T*H
    int* offsBU  = (int*)(tproj + (size_t)TT * HH);  // N+1
    int* offsTD  = offsBU + NN + 1;                  // N+1
    int* elistBU = offsTD + NN + 1;                  // E
    int* elistTD = elistBU + EE;                     // E
    int* csr_work= elistTD + EE;                     // N
    int* bsum    = csr_work + NN;                    // SCAN_NB

    // CSR build: BU dst=ei[0] src=ei[1]; TD dst=ei[1] src=ei[0]
    build_csr(ei + EE, ei, offsBU, elistBU, csr_work, bsum, stream);
    build_csr(ei, ei + EE, offsTD, elistTD, csr_work, bsum, stream);
    k_settail<<<1, 64, 0, stream>>>(offsBU, offsTD);

    // pre-transpose all GEMM weights to bf16 [n][k]
    k_wtrans<<<64, 256, 0, stream>>>(bu_Wl, bu_Wr, td_Wl, td_Wr,
                                     W_comb, W_comb + (size_t)HH * HH, W_a1, W_embed, wt);
    const u16* wt_buWl = wt + 0 * 16384;
    const u16* wt_buWr = wt + 1 * 16384;
    const u16* wt_tdWl = wt + 2 * 16384;
    const u16* wt_tdWr = wt + 3 * 16384;
    const u16* wt_combC = wt + 4 * 16384;
    const u16* wt_combP = wt + 5 * 16384;
    const u16* wt_a1   = wt + 6 * 16384;
    const u16* wt_embed = wt + 7 * 16384;

    // small precomputes
    k_context<<<1, 128, 0, stream>>>(focal, W_seq, b_seq, ctx);
    k_c1<<<1, 128, 0, stream>>>(ctx, W_a1 + (size_t)256 * HH, b_a1, c1v);
    k_tproj<<<TT, 128, 0, stream>>>(time_table, W_a1 + (size_t)128 * HH, tproj);

    const int NB = (NN + 127) / 128;
    // embed
    k_mfma_proj<64, float><<<NB, 256, 0, stream>>>(x, wt_embed, b_embed, h, NN);

    // bottom-up GAT
    k_mfma_proj2<<<NB, 256, 0, stream>>>(h, wt_buWl, wt_buWr, bu_bl, bu_br, xl, xr, NN);
    k_gat_fused<<<NN / 16, 256, 0, stream>>>(h, xl, xr, offsBU, elistBU, bu_att, bu_bias);

    // top-down GAT
    k_mfma_proj2<<<NB, 256, 0, stream>>>(h, wt_tdWl, wt_tdWr, td_bl, td_br, xl, xr, NN);
    k_gat_fused<<<NN / 16, 256, 0, stream>>>(h, xl, xr, offsTD, elistTD, td_att, td_bias);

    // branch = h[child]@Wc + h[parent]@Wp + b_comb
    k_mfma_gproj<<<(AA + 127) / 128, 256, 0, stream>>>(
        h, child_idx, parent_idx, wt_combC, wt_combP, b_comb, branch, AA);

    // logits
    k_mfma_zlogit<<<(AA + 127) / 128, 256, 0, stream>>>(
        branch, time_idx, tproj, c1v, wt_a1, W_a2, b_a2, (float*)d_out);
}

// Round 10
// 570.417 us; speedup vs baseline: 6.7269x; 1.1092x over previous
//
#include <hip/hip_runtime.h>
#include <hip/hip_bf16.h>

#define NN 300000
#define EE 299999
#define AA 150000
#define DD 64
#define HH 128
#define TT 512
#define SCAN_NB ((NN + 1023) / 1024)

typedef unsigned short u16;
typedef unsigned int u32;
typedef __attribute__((ext_vector_type(8))) short short8;
typedef __attribute__((ext_vector_type(4))) float f32x4;

// ---------- helpers ----------
__device__ __forceinline__ float bfb(u16 u) { return __uint_as_float(((u32)u) << 16); }
__device__ __forceinline__ u16 f2b(float f) {
    u32 u = __float_as_uint(f);
    u32 r = (u + 0x7FFFu + ((u >> 16) & 1u)) >> 16;
    return (u16)r;
}
__device__ __forceinline__ uint4 load8(const u16* p) { return *(const uint4*)p; }
__device__ __forceinline__ uint4 load8(const float* p) {
    float4 f1 = *(const float4*)p;
    float4 f2 = *(const float4*)(p + 4);
    union { ushort s[8]; uint4 v; } u;
    u.s[0] = f2b(f1.x); u.s[1] = f2b(f1.y); u.s[2] = f2b(f1.z); u.s[3] = f2b(f1.w);
    u.s[4] = f2b(f2.x); u.s[5] = f2b(f2.y); u.s[6] = f2b(f2.z); u.s[7] = f2b(f2.w);
    return u.v;
}
__device__ __forceinline__ void unpack8(uint4 v, float* f) {
    u32 w0 = v.x, w1 = v.y, w2 = v.z, w3 = v.w;
    f[0] = bfb((u16)w0); f[1] = bfb((u16)(w0 >> 16));
    f[2] = bfb((u16)w1); f[3] = bfb((u16)(w1 >> 16));
    f[4] = bfb((u16)w2); f[5] = bfb((u16)(w2 >> 16));
    f[6] = bfb((u16)w3); f[7] = bfb((u16)(w3 >> 16));
}
// XOR-swizzled LDS offset (u16 units) for fragment READS: position c^(row&7) holds chunk c
__device__ __forceinline__ int swo(int row, int kblock) {
    return row * 64 + ((kblock ^ (row & 7)) * 8);
}
// async global->LDS, 16B per lane; dest = wave-uniform base + lane*16
__device__ __forceinline__ void gl_lds16(const u16* src, u16* ldsbase) {
    __builtin_amdgcn_global_load_lds((const __attribute__((address_space(1))) u32*)src,
                                     (__attribute__((address_space(3))) u32*)ldsbase, 16, 0, 0);
}

// ---------- weight pre-transpose ----------
__global__ __launch_bounds__(256) void k_wtrans(const float* w0, const float* w1,
                                                const float* w2, const float* w3,
                                                const float* w4, const float* w5,
                                                const float* w6, const float* w7,
                                                u16* __restrict__ wt) {
    int widx = blockIdx.x >> 3, part = blockIdx.x & 7;
    const float* W; int K = 128;
    switch (widx) {
        case 0: W = w0; break; case 1: W = w1; break;
        case 2: W = w2; break; case 3: W = w3; break;
        case 4: W = w4; break; case 5: W = w5; break;
        case 6: W = w6; break; default: W = w7; K = 64; break;
    }
    u16* dst = wt + widx * 16384;
    int total = K * 128;
    int lo = part * 2048, hi = lo + 2048;
    if (hi > total) hi = total;
    for (int idx = lo + threadIdx.x; idx < hi; idx += 256) {
        int k = idx >> 7, n = idx & 127;
        dst[n * K + k] = f2b(W[k * 128 + n]);
    }
}

// ---------- fused context + c1 precompute ----------
__global__ void k_ctx_c1(const float* __restrict__ focal, const float* __restrict__ Wseq,
                         const float* __restrict__ bseq, const float* __restrict__ Wa1c,
                         const float* __restrict__ ba1, float* __restrict__ c1) {
    __shared__ float cs[HH];
    int t = threadIdx.x;
    float acc = bseq[t];
    for (int d = 0; d < DD; ++d) acc = fmaf(focal[d], Wseq[d * HH + t], acc);
    cs[t] = acc;
    __syncthreads();
    float a2 = ba1[t];
    for (int k = 0; k < HH; ++k) a2 = fmaf(cs[k], Wa1c[k * HH + t], a2);
    c1[t] = a2;
}

__global__ void k_tproj(const float* __restrict__ tt, const float* __restrict__ Wa1m,
                        float* __restrict__ tproj) {
    int ti = blockIdx.x, t = threadIdx.x;
    float acc = 0.f;
    for (int k = 0; k < HH; ++k)
        acc = fmaf(tt[ti * HH + k], Wa1m[k * HH + t], acc);
    tproj[(size_t)ti * HH + t] = acc;
}

// ---------- CSR build ----------
__global__ void k_hist(const int* __restrict__ dst, int* __restrict__ counts) {
    int e = blockIdx.x * 256 + threadIdx.x;
    if (e < EE) atomicAdd(&counts[dst[e]], 1);
}

__global__ __launch_bounds__(256) void k_scan_block(const int* __restrict__ in,
                                                    int* __restrict__ out,
                                                    int* __restrict__ bsum, int n) {
    __shared__ int sh[256];
    int b = blockIdx.x, t = threadIdx.x;
    int base = b * 1024 + t * 4;
    int v0 = (base + 0 < n) ? in[base + 0] : 0;
    int v1 = (base + 1 < n) ? in[base + 1] : 0;
    int v2 = (base + 2 < n) ? in[base + 2] : 0;
    int v3 = (base + 3 < n) ? in[base + 3] : 0;
    int tsum = v0 + v1 + v2 + v3;
    sh[t] = tsum;
    __syncthreads();
    for (int d = 1; d < 256; d <<= 1) {
        int x = (t >= d) ? sh[t - d] : 0;
        __syncthreads();
        sh[t] += x;
        __syncthreads();
    }
    int excl = sh[t] - tsum;
    if (t == 255) bsum[b] = sh[255];
    if (base + 0 < n) out[base + 0] = excl;
    if (base + 1 < n) out[base + 1] = excl + v0;
    if (base + 2 < n) out[base + 2] = excl + v0 + v1;
    if (base + 3 < n) out[base + 3] = excl + v0 + v1 + v2;
}

__global__ __launch_bounds__(256) void k_scan_top(int* __restrict__ data, int n) {
    __shared__ int sh[256];
    int t = threadIdx.x;
    int base = t * 4;
    int v0 = (base + 0 < n) ? data[base + 0] : 0;
    int v1 = (base + 1 < n) ? data[base + 1] : 0;
    int v2 = (base + 2 < n) ? data[base + 2] : 0;
    int v3 = (base + 3 < n) ? data[base + 3] : 0;
    int tsum = v0 + v1 + v2 + v3;
    sh[t] = tsum;
    __syncthreads();
    for (int d = 1; d < 256; d <<= 1) {
        int x = (t >= d) ? sh[t - d] : 0;
        __syncthreads();
        sh[t] += x;
        __syncthreads();
    }
    int excl = sh[t] - tsum;
    if (base + 0 < n) data[base + 0] = excl;
    if (base + 1 < n) data[base + 1] = excl + v0;
    if (base + 2 < n) data[base + 2] = excl + v0 + v1;
    if (base + 3 < n) data[base + 3] = excl + v0 + v1 + v2;
}

__global__ void k_scan_add(int* __restrict__ out, const int* __restrict__ bsum, int n) {
    int i = blockIdx.x * 256 + threadIdx.x;
    if (i < n) out[i] += bsum[i >> 10];
}

__global__ void k_settail(int* o1, int* o2) {
    if (threadIdx.x == 0) { o1[NN] = EE; o2[NN] = EE; }
}

__global__ void k_scatter(const int* __restrict__ src, const int* __restrict__ dst,
                          int* __restrict__ cursor, int* __restrict__ elist) {
    int e = blockIdx.x * 256 + threadIdx.x;
    if (e >= EE) return;
    int pos = atomicAdd(&cursor[dst[e]], 1);
    elist[pos] = src[e];
}

// ============ MFMA GEMM (single weight, old staging — used for f32 embed only) ============
template <int K, typename InT>
__global__ __launch_bounds__(256) void k_mfma_proj(const InT* __restrict__ in,
                                                   const u16* __restrict__ WT,
                                                   const float* __restrict__ bias,
                                                   u16* __restrict__ out, int nrows) {
    __shared__ u16 lds[17408];
    u16* a_lds = lds;
    u16* b_lds = lds + 8192;
    u16* clds = lds;
    const int t = threadIdx.x;
    const int tile_m = blockIdx.x * 128;
    const int wave = t >> 6, l = t & 15, quad = (t >> 4) & 3;
    const int wr = wave >> 1, wc = wave & 1;
    f32x4 acc[4][4] = {};

    for (int chunk = 0; chunk < K / 64; ++chunk) {
        const int c0 = chunk * 64;
        __syncthreads();
        for (int ci = t; ci < 1024; ci += 256) {
            int row = ci >> 3, kc = ci & 7;
            int grow = tile_m + row;
            uint4 v = make_uint4(0, 0, 0, 0);
            if (grow < nrows) v = load8(&in[(size_t)grow * K + c0 + kc * 8]);
            *(uint4*)&a_lds[swo(row, kc)] = v;
        }
        for (int ci = t; ci < 1024; ci += 256) {
            int n = ci >> 3, kc = ci & 7;
            *(uint4*)&b_lds[swo(n, kc)] = *(const uint4*)&WT[(size_t)n * K + c0 + kc * 8];
        }
        __syncthreads();
#pragma unroll
        for (int ks = 0; ks < 2; ++ks) {
            short8 af[4], bf[4];
#pragma unroll
            for (int i = 0; i < 4; ++i)
                af[i] = *(const short8*)&a_lds[swo(wr * 64 + i * 16 + l, ks * 4 + quad)];
#pragma unroll
            for (int j = 0; j < 4; ++j)
                bf[j] = *(const short8*)&b_lds[swo(wc * 64 + j * 16 + l, ks * 4 + quad)];
#pragma unroll
            for (int i = 0; i < 4; ++i)
#pragma unroll
                for (int j = 0; j < 4; ++j)
                    acc[i][j] = __builtin_amdgcn_mfma_f32_16x16x32_bf16(af[i], bf[j], acc[i][j], 0, 0, 0);
        }
    }
    __syncthreads();
#pragma unroll
    for (int j = 0; j < 4; ++j) {
        int col = wc * 64 + j * 16 + l;
        float b = bias[col];
#pragma unroll
        for (int i = 0; i < 4; ++i) {
            int rloc = wr * 64 + i * 16 + quad * 4;
#pragma unroll
            for (int r = 0; r < 4; ++r)
                clds[(rloc + r) * 136 + col] = f2b(acc[i][j][r] + b);
        }
    }
    __syncthreads();
#pragma unroll
    for (int it = 0; it < 8; ++it) {
        int idx = it * 256 + t;
        int row = idx >> 4, c16 = idx & 15;
        int grow = tile_m + row;
        if (grow < nrows)
            *(uint4*)&out[(size_t)grow * HH + c16 * 8] = *(const uint4*)&clds[row * 136 + c16 * 8];
    }
}

// ============ fused dual GEMM: xl = h@Wl+bl, xr = h@Wr+br (global_load_lds staging) ============
__global__ __launch_bounds__(256) void k_mfma_proj2(const u16* __restrict__ in,
                                                    const u16* __restrict__ WT1,
                                                    const u16* __restrict__ WT2,
                                                    const float* __restrict__ b1,
                                                    const float* __restrict__ b2,
                                                    u16* __restrict__ out1,
                                                    u16* __restrict__ out2, int nrows) {
    __shared__ u16 lds[24576];          // a + b1 + b2 (8192 u16 each); clds overlay 17408
    u16* a_lds = lds;
    u16* b1_lds = lds + 8192;
    u16* b2_lds = lds + 16384;
    u16* clds = lds;
    const int t = threadIdx.x;
    const int tile_m = blockIdx.x * 128;
    const int wave = t >> 6, l = t & 15, quad = (t >> 4) & 3;
    const int wr = wave >> 1, wc = wave & 1;
    f32x4 acc1[4][4] = {}, acc2[4][4] = {};

    for (int chunk = 0; chunk < 2; ++chunk) {
        const int c0 = chunk * 64;
        __syncthreads();
#pragma unroll
        for (int it = 0; it < 4; ++it) {
            int ci = it * 256 + t;
            int row = ci >> 3;
            int colblk = ((ci & 7) ^ (row & 7)) * 8;     // source-side xor swizzle
            u16* wbase = lds + (ci & ~63) * 8;           // a region: offsets 0..8191
            int grow = tile_m + row; if (grow >= nrows) grow = nrows - 1;
            gl_lds16(&in[(size_t)grow * HH + c0 + colblk], wbase);
            gl_lds16(&WT1[(size_t)row * HH + c0 + colblk], wbase + 8192);
            gl_lds16(&WT2[(size_t)row * HH + c0 + colblk], wbase + 16384);
        }
        __syncthreads();
#pragma unroll
        for (int ks = 0; ks < 2; ++ks) {
            short8 af[4], bf1[4], bf2[4];
#pragma unroll
            for (int i = 0; i < 4; ++i)
                af[i] = *(const short8*)&a_lds[swo(wr * 64 + i * 16 + l, ks * 4 + quad)];
#pragma unroll
            for (int j = 0; j < 4; ++j) {
                bf1[j] = *(const short8*)&b1_lds[swo(wc * 64 + j * 16 + l, ks * 4 + quad)];
                bf2[j] = *(const short8*)&b2_lds[swo(wc * 64 + j * 16 + l, ks * 4 + quad)];
            }
#pragma unroll
            for (int i = 0; i < 4; ++i)
#pragma unroll
                for (int j = 0; j < 4; ++j) {
                    acc1[i][j] = __builtin_amdgcn_mfma_f32_16x16x32_bf16(af[i], bf1[j], acc1[i][j], 0, 0, 0);
                    acc2[i][j] = __builtin_amdgcn_mfma_f32_16x16x32_bf16(af[i], bf2[j], acc2[i][j], 0, 0, 0);
                }
        }
    }
    // epilogue out1
    __syncthreads();
#pragma unroll
    for (int j = 0; j < 4; ++j) {
        int col = wc * 64 + j * 16 + l;
        float b = b1[col];
#pragma unroll
        for (int i = 0; i < 4; ++i) {
            int rloc = wr * 64 + i * 16 + quad * 4;
#pragma unroll
            for (int r = 0; r < 4; ++r)
                clds[(rloc + r) * 136 + col] = f2b(acc1[i][j][r] + b);
        }
    }
    __syncthreads();
#pragma unroll
    for (int it = 0; it < 8; ++it) {
        int idx = it * 256 + t;
        int row = idx >> 4, c16 = idx & 15;
        int grow = tile_m + row;
        if (grow < nrows)
            *(uint4*)&out1[(size_t)grow * HH + c16 * 8] = *(const uint4*)&clds[row * 136 + c16 * 8];
    }
    // epilogue out2
    __syncthreads();
#pragma unroll
    for (int j = 0; j < 4; ++j) {
        int col = wc * 64 + j * 16 + l;
        float b = b2[col];
#pragma unroll
        for (int i = 0; i < 4; ++i) {
            int rloc = wr * 64 + i * 16 + quad * 4;
#pragma unroll
            for (int r = 0; r < 4; ++r)
                clds[(rloc + r) * 136 + col] = f2b(acc2[i][j][r] + b);
        }
    }
    __syncthreads();
#pragma unroll
    for (int it = 0; it < 8; ++it) {
        int idx = it * 256 + t;
        int row = idx >> 4, c16 = idx & 15;
        int grow = tile_m + row;
        if (grow < nrows)
            *(uint4*)&out2[(size_t)grow * HH + c16 * 8] = *(const uint4*)&clds[row * 136 + c16 * 8];
    }
}

// ============ fused gathered GEMM (global_load_lds staging + zero-fix for idx<0) ============
__global__ __launch_bounds__(256) void k_mfma_gproj(const u16* __restrict__ h,
                                                    const int* __restrict__ idx1,
                                                    const int* __restrict__ idx2,
                                                    const u16* __restrict__ WT1,
                                                    const u16* __restrict__ WT2,
                                                    const float* __restrict__ bias,
                                                    u16* __restrict__ out, int nrows) {
    __shared__ u16 lds[17408];
    u16* a_lds = lds;
    u16* b_lds = lds + 8192;
    u16* clds = lds;
    const int t = threadIdx.x;
    const int tile_m = blockIdx.x * 128;
    const int wave = t >> 6, l = t & 15, quad = (t >> 4) & 3;
    const int wr = wave >> 1, wc = wave & 1;
    f32x4 acc[4][4] = {};

    for (int pass = 0; pass < 2; ++pass) {
        const int* idx = pass ? idx2 : idx1;
        const u16* WT = pass ? WT2 : WT1;
        for (int chunk = 0; chunk < 2; ++chunk) {
            const int c0 = chunk * 64;
            __syncthreads();
            int gneg[4];
#pragma unroll
            for (int it = 0; it < 4; ++it) {
                int ci = it * 256 + t;
                int row = ci >> 3;
                int colblk = ((ci & 7) ^ (row & 7)) * 8;
                u16* wbase = lds + (ci & ~63) * 8;
                int item = tile_m + row; if (item >= nrows) item = nrows - 1;
                int g = idx[item];
                gneg[it] = (g < 0);
                if (g < 0) g = 0;
                gl_lds16(&h[(size_t)g * HH + c0 + colblk], wbase);
                gl_lds16(&WT[(size_t)row * HH + c0 + colblk], wbase + 8192);
            }
            __syncthreads();
            // zero-fix rows whose gather index was -1 (parent missing)
#pragma unroll
            for (int it = 0; it < 4; ++it) {
                if (gneg[it]) {
                    int ci = it * 256 + t;
                    *(uint4*)&a_lds[ci * 8] = make_uint4(0, 0, 0, 0);
                }
            }
            __syncthreads();
#pragma unroll
            for (int ks = 0; ks < 2; ++ks) {
                short8 af[4], bf[4];
#pragma unroll
                for (int i = 0; i < 4; ++i)
                    af[i] = *(const short8*)&a_lds[swo(wr * 64 + i * 16 + l, ks * 4 + quad)];
#pragma unroll
                for (int j = 0; j < 4; ++j)
                    bf[j] = *(const short8*)&b_lds[swo(wc * 64 + j * 16 + l, ks * 4 + quad)];
#pragma unroll
                for (int i = 0; i < 4; ++i)
#pragma unroll
                    for (int j = 0; j < 4; ++j)
                        acc[i][j] = __builtin_amdgcn_mfma_f32_16x16x32_bf16(af[i], bf[j], acc[i][j], 0, 0, 0);
            }
        }
    }
    __syncthreads();
#pragma unroll
    for (int j = 0; j < 4; ++j) {
        int col = wc * 64 + j * 16 + l;
        float b = bias[col];
#pragma unroll
        for (int i = 0; i < 4; ++i) {
            int rloc = wr * 64 + i * 16 + quad * 4;
#pragma unroll
            for (int r = 0; r < 4; ++r)
                clds[(rloc + r) * 136 + col] = f2b(acc[i][j][r] + b);
        }
    }
    __syncthreads();
#pragma unroll
    for (int it = 0; it < 8; ++it) {
        int idx = it * 256 + t;
        int row = idx >> 4, c16 = idx & 15;
        int item = tile_m + row;
        if (item < nrows)
            *(uint4*)&out[(size_t)item * HH + c16 * 8] = *(const uint4*)&clds[row * 136 + c16 * 8];
    }
}

// ============ MFMA z+logit (global_load_lds staging) ============
__global__ __launch_bounds__(256) void k_mfma_zlogit(const u16* __restrict__ branch,
                                                     const int* __restrict__ time_idx,
                                                     const float* __restrict__ tproj,
                                                     const float* __restrict__ c1,
                                                     const u16* __restrict__ WTa1,
                                                     const float* __restrict__ Wa2,
                                                     const float* __restrict__ ba2,
                                                     float* __restrict__ out) {
    __shared__ u16 lds[16384];
    u16* a_lds = lds;
    u16* b_lds = lds + 8192;
    __shared__ float red[2][128];
    const int t = threadIdx.x;
    const int tile_m = blockIdx.x * 128;
    const int wave = t >> 6, l = t & 15, quad = (t >> 4) & 3;
    const int wr = wave >> 1, wc = wave & 1;
    f32x4 acc[4][4] = {};

    for (int chunk = 0; chunk < 2; ++chunk) {
        const int c0 = chunk * 64;
        __syncthreads();
#pragma unroll
        for (int it = 0; it < 4; ++it) {
            int ci = it * 256 + t;
            int row = ci >> 3;
            int colblk = ((ci & 7) ^ (row & 7)) * 8;
            u16* wbase = lds + (ci & ~63) * 8;
            int item = tile_m + row; if (item >= AA) item = AA - 1;
            gl_lds16(&branch[(size_t)item * HH + c0 + colblk], wbase);
            gl_lds16(&WTa1[(size_t)row * HH + c0 + colblk], wbase + 8192);
        }
        __syncthreads();
#pragma unroll
        for (int ks = 0; ks < 2; ++ks) {
            short8 af[4], bf[4];
#pragma unroll
            for (int i = 0; i < 4; ++i)
                af[i] = *(const short8*)&a_lds[swo(wr * 64 + i * 16 + l, ks * 4 + quad)];
#pragma unroll
            for (int j = 0; j < 4; ++j)
                bf[j] = *(const short8*)&b_lds[swo(wc * 64 + j * 16 + l, ks * 4 + quad)];
#pragma unroll
            for (int i = 0; i < 4; ++i)
#pragma unroll
                for (int j = 0; j < 4; ++j)
                    acc[i][j] = __builtin_amdgcn_mfma_f32_16x16x32_bf16(af[i], bf[j], acc[i][j], 0, 0, 0);
        }
    }
    float c1v[4], wa2v[4];
#pragma unroll
    for (int j = 0; j < 4; ++j) {
        int col = wc * 64 + j * 16 + l;
        c1v[j] = c1[col];
        wa2v[j] = Wa2[col];
    }
#pragma unroll
    for (int i = 0; i < 4; ++i) {
        int rbase = tile_m + wr * 64 + i * 16 + quad * 4;
#pragma unroll
        for (int r = 0; r < 4; ++r) {
            int item = rbase + r;
            int ti = (item < AA) ? time_idx[item] : 0;
            const float* tp = tproj + (size_t)ti * HH;
            float partial = 0.f;
#pragma unroll
            for (int j = 0; j < 4; ++j) {
                int col = wc * 64 + j * 16 + l;
                float z = fmaxf(acc[i][j][r] + tp[col] + c1v[j], 0.f);
                partial = fmaf(z, wa2v[j], partial);
            }
            partial += __shfl_xor(partial, 1);
            partial += __shfl_xor(partial, 2);
            partial += __shfl_xor(partial, 4);
            partial += __shfl_xor(partial, 8);
            if (l == 0) red[wc][wr * 64 + i * 16 + quad * 4 + r] = partial;
        }
    }
    __syncthreads();
    if (t < 128) {
        int item = tile_m + t;
        if (item < AA) out[item] = red[0][t] + red[1][t] + ba2[0];
    }
}

// ============ fused GAT: single-pass online softmax + aggregation + h update ============
__global__ __launch_bounds__(256) void k_gat_fused(u16* __restrict__ h,
                                                   const u16* __restrict__ xl,
                                                   const u16* __restrict__ xr,
                                                   const int* __restrict__ offs,
                                                   const int* __restrict__ elist,
                                                   const float* __restrict__ att,
                                                   const float* __restrict__ bias) {
    int g = blockIdx.x * 16 + (threadIdx.x >> 4);   // dst node (NN divisible by 16)
    int l = threadIdx.x & 15;
    float attv[8], biasv[8];
    *(float4*)&attv[0] = *(const float4*)&att[l * 8];
    *(float4*)&attv[4] = *(const float4*)&att[l * 8 + 4];
    *(float4*)&biasv[0] = *(const float4*)&bias[l * 8];
    *(float4*)&biasv[4] = *(const float4*)&bias[l * 8 + 4];
    float xrf[8];
    unpack8(*(const uint4*)&xr[(size_t)g * HH + l * 8], xrf);
    int e0 = offs[g], e1 = offs[g + 1];

    float m = -__builtin_inff(), s = 0.f;
    float acc[8] = {};
    for (int e = e0; e < e1; ++e) {
        int sidx = elist[e];
        float xf[8];
        unpack8(*(const uint4*)&xl[(size_t)sidx * HH + l * 8], xf);
        float p = 0.f;
#pragma unroll
        for (int j = 0; j < 8; ++j) {
            float v = xf[j] + xrf[j];
            v = v >= 0.f ? v : 0.2f * v;
            p = fmaf(v, attv[j], p);
        }
        p += __shfl_xor(p, 1); p += __shfl_xor(p, 2);
        p += __shfl_xor(p, 4); p += __shfl_xor(p, 8);
        float mn = fmaxf(m, p);
        float so = __expf(m - mn);
        float w = __expf(p - mn);
        s = s * so + w;
#pragma unroll
        for (int j = 0; j < 8; ++j) acc[j] = fmaf(acc[j], so, w * xf[j]);
        m = mn;
    }
    float inv = 1.f / (s + 1e-16f);

    float hf[8];
    unpack8(*(const uint4*)&h[(size_t)g * HH + l * 8], hf);
    union { ushort sh[8]; uint4 v; } o;
#pragma unroll
    for (int j = 0; j < 8; ++j) {
        hf[j] += fmaxf(fmaf(acc[j], inv, biasv[j]), 0.f);
        o.sh[j] = f2b(hf[j]);
    }
    *(uint4*)&h[(size_t)g * HH + l * 8] = o.v;
}

// ---------- host side ----------
typedef const float* fp;

static void build_csr(const int* src, const int* dst, int* offs, int* elist,
                      int* work, int* bsum, hipStream_t stream) {
    hipMemsetAsync(work, 0, (size_t)NN * 4, stream);
    k_hist<<<(EE + 255) / 256, 256, 0, stream>>>(dst, work);
    k_scan_block<<<SCAN_NB, 256, 0, stream>>>(work, offs, bsum, NN);
    k_scan_top<<<1, 256, 0, stream>>>(bsum, SCAN_NB);
    k_scan_add<<<(NN + 255) / 256, 256, 0, stream>>>(offs, bsum, NN);
    hipMemcpyAsync(work, offs, (size_t)NN * 4, hipMemcpyDeviceToDevice, stream);
    k_scatter<<<(EE + 255) / 256, 256, 0, stream>>>(src, dst, work, elist);
}

extern "C" void kernel_launch(void* const* d_in, const int* in_sizes, int n_in,
                              void* d_out, int out_size, void* d_ws, size_t ws_size,
                              hipStream_t stream) {
    fp x                 = (fp)d_in[0];
    const int* ei        = (const int*)d_in[1];
    fp focal             = (fp)d_in[2];
    const int* child_idx = (const int*)d_in[3];
    const int* parent_idx= (const int*)d_in[4];
    const int* time_idx  = (const int*)d_in[5];
    fp W_embed = (fp)d_in[6],  b_embed = (fp)d_in[7];
    fp bu_Wl   = (fp)d_in[8],  bu_bl   = (fp)d_in[9];
    fp bu_Wr   = (fp)d_in[10], bu_br   = (fp)d_in[11];
    fp bu_att  = (fp)d_in[12], bu_bias = (fp)d_in[13];
    fp td_Wl   = (fp)d_in[14], td_bl   = (fp)d_in[15];
    fp td_Wr   = (fp)d_in[16], td_br   = (fp)d_in[17];
    fp td_att  = (fp)d_in[18], td_bias = (fp)d_in[19];
    fp time_table = (fp)d_in[20];
    fp W_comb  = (fp)d_in[21], b_comb  = (fp)d_in[22];
    fp W_a1    = (fp)d_in[23], b_a1    = (fp)d_in[24];
    fp W_a2    = (fp)d_in[25], b_a2    = (fp)d_in[26];
    fp W_seq   = (fp)d_in[27], b_seq   = (fp)d_in[28];

    const size_t NH = (size_t)NN * HH;
    u16* wt = (u16*)d_ws;                 // 8 x 16384 u16 (256 KB)
    u16* h  = wt + 8 * 16384;             // N*H bf16
    u16* xl = h + NH;
    u16* xr = xl + NH;
    u16* branch = xl;                     // A*H bf16, aliases xl
    float* c1v   = (float*)(xr + NH);     // H
    float* tproj = c1v + HH;              // T*H
    int* offsBU  = (int*)(tproj + (size_t)TT * HH);  // N+1
    int* offsTD  = offsBU + NN + 1;                  // N+1
    int* elistBU = offsTD + NN + 1;                  // E
    int* elistTD = elistBU + EE;                     // E
    int* csr_work= elistTD + EE;                     // N
    int* bsum    = csr_work + NN;                    // SCAN_NB

    // CSR build: BU dst=ei[0] src=ei[1]; TD dst=ei[1] src=ei[0]
    build_csr(ei + EE, ei, offsBU, elistBU, csr_work, bsum, stream);
    build_csr(ei, ei + EE, offsTD, elistTD, csr_work, bsum, stream);
    k_settail<<<1, 64, 0, stream>>>(offsBU, offsTD);

    // pre-transpose all GEMM weights to bf16 [n][k]
    k_wtrans<<<64, 256, 0, stream>>>(bu_Wl, bu_Wr, td_Wl, td_Wr,
                                     W_comb, W_comb + (size_t)HH * HH, W_a1, W_embed, wt);
    const u16* wt_buWl = wt + 0 * 16384;
    const u16* wt_buWr = wt + 1 * 16384;
    const u16* wt_tdWl = wt + 2 * 16384;
    const u16* wt_tdWr = wt + 3 * 16384;
    const u16* wt_combC = wt + 4 * 16384;
    const u16* wt_combP = wt + 5 * 16384;
    const u16* wt_a1   = wt + 6 * 16384;
    const u16* wt_embed = wt + 7 * 16384;

    // small precomputes
    k_ctx_c1<<<1, 128, 0, stream>>>(focal, W_seq, b_seq, W_a1 + (size_t)256 * HH, b_a1, c1v);
    k_tproj<<<TT, 128, 0, stream>>>(time_table, W_a1 + (size_t)128 * HH, tproj);

    const int NB = (NN + 127) / 128;
    // embed
    k_mfma_proj<64, float><<<NB, 256, 0, stream>>>(x, wt_embed, b_embed, h, NN);

    // bottom-up GAT
    k_mfma_proj2<<<NB, 256, 0, stream>>>(h, wt_buWl, wt_buWr, bu_bl, bu_br, xl, xr, NN);
    k_gat_fused<<<NN / 16, 256, 0, stream>>>(h, xl, xr, offsBU, elistBU, bu_att, bu_bias);

    // top-down GAT
    k_mfma_proj2<<<NB, 256, 0, stream>>>(h, wt_tdWl, wt_tdWr, td_bl, td_br, xl, xr, NN);
    k_gat_fused<<<NN / 16, 256, 0, stream>>>(h, xl, xr, offsTD, elistTD, td_att, td_bias);

    // branch = h[child]@Wc + h[parent]@Wp + b_comb
    k_mfma_gproj<<<(AA + 127) / 128, 256, 0, stream>>>(
        h, child_idx, parent_idx, wt_combC, wt_combP, b_comb, branch, AA);

    // logits
    k_mfma_zlogit<<<(AA + 127) / 128, 256, 0, stream>>>(
        branch, time_idx, tproj, c1v, wt_a1, W_a2, b_a2, (float*)d_out);
}

// Round 11
// 561.048 us; speedup vs baseline: 6.8393x; 1.0167x over previous
//
#include <hip/hip_runtime.h>
#include <hip/hip_bf16.h>

#define NN 300000
#define EE 299999
#define AA 150000
#define DD 64
#define HH 128
#define TT 512
#define SCAN_NB ((NN + 1023) / 1024)

typedef unsigned short u16;
typedef unsigned int u32;
typedef __attribute__((ext_vector_type(8))) short short8;
typedef __attribute__((ext_vector_type(4))) float f32x4;

// ---------- helpers ----------
__device__ __forceinline__ float bfb(u16 u) { return __uint_as_float(((u32)u) << 16); }
__device__ __forceinline__ u16 f2b(float f) {
    u32 u = __float_as_uint(f);
    u32 r = (u + 0x7FFFu + ((u >> 16) & 1u)) >> 16;
    return (u16)r;
}
__device__ __forceinline__ uint4 load8(const u16* p) { return *(const uint4*)p; }
__device__ __forceinline__ uint4 load8(const float* p) {
    float4 f1 = *(const float4*)p;
    float4 f2 = *(const float4*)(p + 4);
    union { ushort s[8]; uint4 v; } u;
    u.s[0] = f2b(f1.x); u.s[1] = f2b(f1.y); u.s[2] = f2b(f1.z); u.s[3] = f2b(f1.w);
    u.s[4] = f2b(f2.x); u.s[5] = f2b(f2.y); u.s[6] = f2b(f2.z); u.s[7] = f2b(f2.w);
    return u.v;
}
__device__ __forceinline__ void unpack8(uint4 v, float* f) {
    u32 w0 = v.x, w1 = v.y, w2 = v.z, w3 = v.w;
    f[0] = bfb((u16)w0); f[1] = bfb((u16)(w0 >> 16));
    f[2] = bfb((u16)w1); f[3] = bfb((u16)(w1 >> 16));
    f[4] = bfb((u16)w2); f[5] = bfb((u16)(w2 >> 16));
    f[6] = bfb((u16)w3); f[7] = bfb((u16)(w3 >> 16));
}
// XOR-swizzled LDS offset (u16 units): 64-k tiles, stride 64
__device__ __forceinline__ int swo(int row, int kblock) {
    return row * 64 + ((kblock ^ (row & 7)) * 8);
}
// 128-k tiles, stride 128 (kblock 0..15; xor only low 3 bits)
__device__ __forceinline__ int swo2(int row, int kblock) {
    return row * 128 + (((kblock & 8) | ((kblock & 7) ^ (row & 7))) * 8);
}
// async global->LDS, 16B per lane; dest = wave-uniform base + lane*16
__device__ __forceinline__ void gl_lds16(const u16* src, u16* ldsbase) {
    __builtin_amdgcn_global_load_lds((const __attribute__((address_space(1))) u32*)src,
                                     (__attribute__((address_space(3))) u32*)ldsbase, 16, 0, 0);
}

// ---------- weight pre-transpose ----------
__global__ __launch_bounds__(256) void k_wtrans(const float* w0, const float* w1,
                                                const float* w2, const float* w3,
                                                const float* w4, const float* w5,
                                                const float* w6, const float* w7,
                                                u16* __restrict__ wt) {
    int widx = blockIdx.x >> 3, part = blockIdx.x & 7;
    const float* W; int K = 128;
    switch (widx) {
        case 0: W = w0; break; case 1: W = w1; break;
        case 2: W = w2; break; case 3: W = w3; break;
        case 4: W = w4; break; case 5: W = w5; break;
        case 6: W = w6; break; default: W = w7; K = 64; break;
    }
    u16* dst = wt + widx * 16384;
    int total = K * 128;
    int lo = part * 2048, hi = lo + 2048;
    if (hi > total) hi = total;
    for (int idx = lo + threadIdx.x; idx < hi; idx += 256) {
        int k = idx >> 7, n = idx & 127;
        dst[n * K + k] = f2b(W[k * 128 + n]);
    }
}

// ---------- fused context + c1 precompute ----------
__global__ void k_ctx_c1(const float* __restrict__ focal, const float* __restrict__ Wseq,
                         const float* __restrict__ bseq, const float* __restrict__ Wa1c,
                         const float* __restrict__ ba1, float* __restrict__ c1) {
    __shared__ float cs[HH];
    int t = threadIdx.x;
    float acc = bseq[t];
    for (int d = 0; d < DD; ++d) acc = fmaf(focal[d], Wseq[d * HH + t], acc);
    cs[t] = acc;
    __syncthreads();
    float a2 = ba1[t];
    for (int k = 0; k < HH; ++k) a2 = fmaf(cs[k], Wa1c[k * HH + t], a2);
    c1[t] = a2;
}

__global__ void k_tproj(const float* __restrict__ tt, const float* __restrict__ Wa1m,
                        float* __restrict__ tproj) {
    int ti = blockIdx.x, t = threadIdx.x;
    float acc = 0.f;
    for (int k = 0; k < HH; ++k)
        acc = fmaf(tt[ti * HH + k], Wa1m[k * HH + t], acc);
    tproj[(size_t)ti * HH + t] = acc;
}

// ---------- CSR build ----------
__global__ void k_hist(const int* __restrict__ dst, int* __restrict__ counts) {
    int e = blockIdx.x * 256 + threadIdx.x;
    if (e < EE) atomicAdd(&counts[dst[e]], 1);
}

__global__ __launch_bounds__(256) void k_scan_block(const int* __restrict__ in,
                                                    int* __restrict__ out,
                                                    int* __restrict__ bsum, int n) {
    __shared__ int sh[256];
    int b = blockIdx.x, t = threadIdx.x;
    int base = b * 1024 + t * 4;
    int v0 = (base + 0 < n) ? in[base + 0] : 0;
    int v1 = (base + 1 < n) ? in[base + 1] : 0;
    int v2 = (base + 2 < n) ? in[base + 2] : 0;
    int v3 = (base + 3 < n) ? in[base + 3] : 0;
    int tsum = v0 + v1 + v2 + v3;
    sh[t] = tsum;
    __syncthreads();
    for (int d = 1; d < 256; d <<= 1) {
        int x = (t >= d) ? sh[t - d] : 0;
        __syncthreads();
        sh[t] += x;
        __syncthreads();
    }
    int excl = sh[t] - tsum;
    if (t == 255) bsum[b] = sh[255];
    if (base + 0 < n) out[base + 0] = excl;
    if (base + 1 < n) out[base + 1] = excl + v0;
    if (base + 2 < n) out[base + 2] = excl + v0 + v1;
    if (base + 3 < n) out[base + 3] = excl + v0 + v1 + v2;
}

__global__ __launch_bounds__(256) void k_scan_top(int* __restrict__ data, int n) {
    __shared__ int sh[256];
    int t = threadIdx.x;
    int base = t * 4;
    int v0 = (base + 0 < n) ? data[base + 0] : 0;
    int v1 = (base + 1 < n) ? data[base + 1] : 0;
    int v2 = (base + 2 < n) ? data[base + 2] : 0;
    int v3 = (base + 3 < n) ? data[base + 3] : 0;
    int tsum = v0 + v1 + v2 + v3;
    sh[t] = tsum;
    __syncthreads();
    for (int d = 1; d < 256; d <<= 1) {
        int x = (t >= d) ? sh[t - d] : 0;
        __syncthreads();
        sh[t] += x;
        __syncthreads();
    }
    int excl = sh[t] - tsum;
    if (base + 0 < n) data[base + 0] = excl;
    if (base + 1 < n) data[base + 1] = excl + v0;
    if (base + 2 < n) data[base + 2] = excl + v0 + v1;
    if (base + 3 < n) data[base + 3] = excl + v0 + v1 + v2;
}

__global__ void k_scan_add(int* __restrict__ out, const int* __restrict__ bsum, int n) {
    int i = blockIdx.x * 256 + threadIdx.x;
    if (i < n) out[i] += bsum[i >> 10];
}

__global__ void k_settail(int* o1, int* o2) {
    if (threadIdx.x == 0) { o1[NN] = EE; o2[NN] = EE; }
}

__global__ void k_scatter(const int* __restrict__ src, const int* __restrict__ dst,
                          int* __restrict__ cursor, int* __restrict__ elist) {
    int e = blockIdx.x * 256 + threadIdx.x;
    if (e >= EE) return;
    int pos = atomicAdd(&cursor[dst[e]], 1);
    elist[pos] = src[e];
}

// ============ MFMA GEMM (f32 input embed) ============
template <int K, typename InT>
__global__ __launch_bounds__(256) void k_mfma_proj(const InT* __restrict__ in,
                                                   const u16* __restrict__ WT,
                                                   const float* __restrict__ bias,
                                                   u16* __restrict__ out, int nrows) {
    __shared__ u16 lds[17408];
    u16* a_lds = lds;
    u16* b_lds = lds + 8192;
    u16* clds = lds;
    const int t = threadIdx.x;
    const int tile_m = blockIdx.x * 128;
    const int wave = t >> 6, l = t & 15, quad = (t >> 4) & 3;
    const int wr = wave >> 1, wc = wave & 1;
    f32x4 acc[4][4] = {};

    for (int chunk = 0; chunk < K / 64; ++chunk) {
        const int c0 = chunk * 64;
        __syncthreads();
        for (int ci = t; ci < 1024; ci += 256) {
            int row = ci >> 3, kc = ci & 7;
            int grow = tile_m + row;
            uint4 v = make_uint4(0, 0, 0, 0);
            if (grow < nrows) v = load8(&in[(size_t)grow * K + c0 + kc * 8]);
            *(uint4*)&a_lds[swo(row, kc)] = v;
        }
        for (int ci = t; ci < 1024; ci += 256) {
            int n = ci >> 3, kc = ci & 7;
            *(uint4*)&b_lds[swo(n, kc)] = *(const uint4*)&WT[(size_t)n * K + c0 + kc * 8];
        }
        __syncthreads();
#pragma unroll
        for (int ks = 0; ks < 2; ++ks) {
            short8 af[4], bf[4];
#pragma unroll
            for (int i = 0; i < 4; ++i)
                af[i] = *(const short8*)&a_lds[swo(wr * 64 + i * 16 + l, ks * 4 + quad)];
#pragma unroll
            for (int j = 0; j < 4; ++j)
                bf[j] = *(const short8*)&b_lds[swo(wc * 64 + j * 16 + l, ks * 4 + quad)];
#pragma unroll
            for (int i = 0; i < 4; ++i)
#pragma unroll
                for (int j = 0; j < 4; ++j)
                    acc[i][j] = __builtin_amdgcn_mfma_f32_16x16x32_bf16(af[i], bf[j], acc[i][j], 0, 0, 0);
        }
    }
    __syncthreads();
#pragma unroll
    for (int j = 0; j < 4; ++j) {
        int col = wc * 64 + j * 16 + l;
        float b = bias[col];
#pragma unroll
        for (int i = 0; i < 4; ++i) {
            int rloc = wr * 64 + i * 16 + quad * 4;
#pragma unroll
            for (int r = 0; r < 4; ++r)
                clds[(rloc + r) * 136 + col] = f2b(acc[i][j][r] + b);
        }
    }
    __syncthreads();
#pragma unroll
    for (int it = 0; it < 8; ++it) {
        int idx = it * 256 + t;
        int row = idx >> 4, c16 = idx & 15;
        int grow = tile_m + row;
        if (grow < nrows)
            *(uint4*)&out[(size_t)grow * HH + c16 * 8] = *(const uint4*)&clds[row * 136 + c16 * 8];
    }
}

// ============ fused dual GEMM, 512 threads / 8 waves ============
__global__ __launch_bounds__(512) void k_mfma_proj2(const u16* __restrict__ in,
                                                    const u16* __restrict__ WT1,
                                                    const u16* __restrict__ WT2,
                                                    const float* __restrict__ b1,
                                                    const float* __restrict__ b2,
                                                    u16* __restrict__ out1,
                                                    u16* __restrict__ out2, int nrows) {
    __shared__ u16 lds[24576];          // a + b1 + b2 (8192 u16 each); clds overlay 17408
    u16* a_lds = lds;
    u16* b1_lds = lds + 8192;
    u16* b2_lds = lds + 16384;
    u16* clds = lds;
    const int t = threadIdx.x;
    const int tile_m = blockIdx.x * 128;
    const int wave = t >> 6, l = t & 15, quad = (t >> 4) & 3;
    const int wr = wave >> 1, wc = wave & 1;   // wr 0..3 (32-row strip), wc 0..1
    f32x4 acc1[2][4] = {}, acc2[2][4] = {};

    for (int chunk = 0; chunk < 2; ++chunk) {
        const int c0 = chunk * 64;
        __syncthreads();
#pragma unroll
        for (int it = 0; it < 2; ++it) {
            int ci = it * 512 + t;
            int row = ci >> 3;
            int colblk = ((ci & 7) ^ (row & 7)) * 8;
            u16* wbase = lds + (ci & ~63) * 8;
            int grow = tile_m + row; if (grow >= nrows) grow = nrows - 1;
            gl_lds16(&in[(size_t)grow * HH + c0 + colblk], wbase);
            gl_lds16(&WT1[(size_t)row * HH + c0 + colblk], wbase + 8192);
            gl_lds16(&WT2[(size_t)row * HH + c0 + colblk], wbase + 16384);
        }
        __syncthreads();
#pragma unroll
        for (int ks = 0; ks < 2; ++ks) {
            short8 af[2], bf1[4], bf2[4];
#pragma unroll
            for (int i = 0; i < 2; ++i)
                af[i] = *(const short8*)&a_lds[swo(wr * 32 + i * 16 + l, ks * 4 + quad)];
#pragma unroll
            for (int j = 0; j < 4; ++j) {
                bf1[j] = *(const short8*)&b1_lds[swo(wc * 64 + j * 16 + l, ks * 4 + quad)];
                bf2[j] = *(const short8*)&b2_lds[swo(wc * 64 + j * 16 + l, ks * 4 + quad)];
            }
#pragma unroll
            for (int i = 0; i < 2; ++i)
#pragma unroll
                for (int j = 0; j < 4; ++j) {
                    acc1[i][j] = __builtin_amdgcn_mfma_f32_16x16x32_bf16(af[i], bf1[j], acc1[i][j], 0, 0, 0);
                    acc2[i][j] = __builtin_amdgcn_mfma_f32_16x16x32_bf16(af[i], bf2[j], acc2[i][j], 0, 0, 0);
                }
        }
    }
    // epilogue out1
    __syncthreads();
#pragma unroll
    for (int j = 0; j < 4; ++j) {
        int col = wc * 64 + j * 16 + l;
        float b = b1[col];
#pragma unroll
        for (int i = 0; i < 2; ++i) {
            int rloc = wr * 32 + i * 16 + quad * 4;
#pragma unroll
            for (int r = 0; r < 4; ++r)
                clds[(rloc + r) * 136 + col] = f2b(acc1[i][j][r] + b);
        }
    }
    __syncthreads();
#pragma unroll
    for (int it = 0; it < 4; ++it) {
        int idx = it * 512 + t;
        int row = idx >> 4, c16 = idx & 15;
        int grow = tile_m + row;
        if (grow < nrows)
            *(uint4*)&out1[(size_t)grow * HH + c16 * 8] = *(const uint4*)&clds[row * 136 + c16 * 8];
    }
    // epilogue out2
    __syncthreads();
#pragma unroll
    for (int j = 0; j < 4; ++j) {
        int col = wc * 64 + j * 16 + l;
        float b = b2[col];
#pragma unroll
        for (int i = 0; i < 2; ++i) {
            int rloc = wr * 32 + i * 16 + quad * 4;
#pragma unroll
            for (int r = 0; r < 4; ++r)
                clds[(rloc + r) * 136 + col] = f2b(acc2[i][j][r] + b);
        }
    }
    __syncthreads();
#pragma unroll
    for (int it = 0; it < 4; ++it) {
        int idx = it * 512 + t;
        int row = idx >> 4, c16 = idx & 15;
        int grow = tile_m + row;
        if (grow < nrows)
            *(uint4*)&out2[(size_t)grow * HH + c16 * 8] = *(const uint4*)&clds[row * 136 + c16 * 8];
    }
}

// ============ fused branch + z + logit: out[i] = relu((h[c]@W1+h[p]@W2+b)@Wa1 + tp + c1).Wa2 + ba2 ============
__global__ __launch_bounds__(256) void k_branch_logit(const u16* __restrict__ h,
                                                      const int* __restrict__ idx1,
                                                      const int* __restrict__ idx2,
                                                      const u16* __restrict__ WT1,
                                                      const u16* __restrict__ WT2,
                                                      const float* __restrict__ bias,
                                                      const int* __restrict__ time_idx,
                                                      const float* __restrict__ tproj,
                                                      const float* __restrict__ c1,
                                                      const u16* __restrict__ WTa1,
                                                      const float* __restrict__ Wa2,
                                                      const float* __restrict__ ba2,
                                                      float* __restrict__ out) {
    __shared__ u16 lds[24576];   // phase1: stA[0..8191], stB[8192..16383]; abuf = lds[0..16383]; z2 = lds[16384..]
    __shared__ float red[2][128];
    u16* a_lds = lds;
    u16* b_lds = lds + 8192;
    u16* abuf = lds;
    u16* z2 = lds + 16384;
    const int t = threadIdx.x;
    const int tile_m = blockIdx.x * 128;
    const int wave = t >> 6, l = t & 15, quad = (t >> 4) & 3;
    const int wr = wave >> 1, wc = wave & 1;
    f32x4 acc[4][4] = {};

    // ---- phase 1: branch = h[idx1]@W1 + h[idx2]@W2 ----
    for (int pass = 0; pass < 2; ++pass) {
        const int* idx = pass ? idx2 : idx1;
        const u16* WT = pass ? WT2 : WT1;
        for (int chunk = 0; chunk < 2; ++chunk) {
            const int c0 = chunk * 64;
            __syncthreads();
            int gneg[4];
#pragma unroll
            for (int it = 0; it < 4; ++it) {
                int ci = it * 256 + t;
                int row = ci >> 3;
                int colblk = ((ci & 7) ^ (row & 7)) * 8;
                u16* wbase = lds + (ci & ~63) * 8;
                int item = tile_m + row; if (item >= AA) item = AA - 1;
                int g = idx[item];
                gneg[it] = (g < 0);
                if (g < 0) g = 0;
                gl_lds16(&h[(size_t)g * HH + c0 + colblk], wbase);
                gl_lds16(&WT[(size_t)row * HH + c0 + colblk], wbase + 8192);
            }
            __syncthreads();
#pragma unroll
            for (int it = 0; it < 4; ++it) {
                if (gneg[it]) {
                    int ci = it * 256 + t;
                    *(uint4*)&a_lds[ci * 8] = make_uint4(0, 0, 0, 0);
                }
            }
            __syncthreads();
#pragma unroll
            for (int ks = 0; ks < 2; ++ks) {
                short8 af[4], bf[4];
#pragma unroll
                for (int i = 0; i < 4; ++i)
                    af[i] = *(const short8*)&a_lds[swo(wr * 64 + i * 16 + l, ks * 4 + quad)];
#pragma unroll
                for (int j = 0; j < 4; ++j)
                    bf[j] = *(const short8*)&b_lds[swo(wc * 64 + j * 16 + l, ks * 4 + quad)];
#pragma unroll
                for (int i = 0; i < 4; ++i)
#pragma unroll
                    for (int j = 0; j < 4; ++j)
                        acc[i][j] = __builtin_amdgcn_mfma_f32_16x16x32_bf16(af[i], bf[j], acc[i][j], 0, 0, 0);
            }
        }
    }
    // ---- write branch tile (bf16 + bias) into abuf, swizzled A layout (K=128) ----
    __syncthreads();
#pragma unroll
    for (int j = 0; j < 4; ++j) {
        int col = wc * 64 + j * 16 + l;
        float b = bias[col];
        int kb = col >> 3, ko = col & 7;
#pragma unroll
        for (int i = 0; i < 4; ++i) {
            int rloc = wr * 64 + i * 16 + quad * 4;
#pragma unroll
            for (int r = 0; r < 4; ++r)
                abuf[swo2(rloc + r, kb) + ko] = f2b(acc[i][j][r] + b);
        }
    }
    // ---- phase 2: z-GEMM: accz = branch @ Wa1_top ----
    f32x4 accz[4][4] = {};
    for (int chunk = 0; chunk < 2; ++chunk) {
        const int c0 = chunk * 64;
        __syncthreads();
#pragma unroll
        for (int it = 0; it < 4; ++it) {
            int ci = it * 256 + t;
            int row = ci >> 3;
            int colblk = ((ci & 7) ^ (row & 7)) * 8;
            u16* wbase = z2 + (ci & ~63) * 8;
            gl_lds16(&WTa1[(size_t)row * HH + c0 + colblk], wbase);
        }
        __syncthreads();
#pragma unroll
        for (int ks = 0; ks < 2; ++ks) {
            short8 af[4], bf[4];
            int kb = chunk * 8 + ks * 4 + quad;
#pragma unroll
            for (int i = 0; i < 4; ++i)
                af[i] = *(const short8*)&abuf[swo2(wr * 64 + i * 16 + l, kb)];
#pragma unroll
            for (int j = 0; j < 4; ++j)
                bf[j] = *(const short8*)&z2[swo(wc * 64 + j * 16 + l, ks * 4 + quad)];
#pragma unroll
            for (int i = 0; i < 4; ++i)
#pragma unroll
                for (int j = 0; j < 4; ++j)
                    accz[i][j] = __builtin_amdgcn_mfma_f32_16x16x32_bf16(af[i], bf[j], accz[i][j], 0, 0, 0);
        }
    }
    // ---- epilogue: relu(z + tproj + c1) . Wa2, reduce, store ----
    float c1v[4], wa2v[4];
#pragma unroll
    for (int j = 0; j < 4; ++j) {
        int col = wc * 64 + j * 16 + l;
        c1v[j] = c1[col];
        wa2v[j] = Wa2[col];
    }
#pragma unroll
    for (int i = 0; i < 4; ++i) {
        int rbase = tile_m + wr * 64 + i * 16 + quad * 4;
#pragma unroll
        for (int r = 0; r < 4; ++r) {
            int item = rbase + r;
            int ti = (item < AA) ? time_idx[item] : 0;
            const float* tp = tproj + (size_t)ti * HH;
            float partial = 0.f;
#pragma unroll
            for (int j = 0; j < 4; ++j) {
                int col = wc * 64 + j * 16 + l;
                float z = fmaxf(accz[i][j][r] + tp[col] + c1v[j], 0.f);
                partial = fmaf(z, wa2v[j], partial);
            }
            partial += __shfl_xor(partial, 1);
            partial += __shfl_xor(partial, 2);
            partial += __shfl_xor(partial, 4);
            partial += __shfl_xor(partial, 8);
            if (l == 0) red[wc][wr * 64 + i * 16 + quad * 4 + r] = partial;
        }
    }
    __syncthreads();
    if (t < 128) {
        int item = tile_m + t;
        if (item < AA) out[item] = red[0][t] + red[1][t] + ba2[0];
    }
}

// ============ fused GAT: single-pass online softmax + aggregation + h update ============
__global__ __launch_bounds__(256) void k_gat_fused(u16* __restrict__ h,
                                                   const u16* __restrict__ xl,
                                                   const u16* __restrict__ xr,
                                                   const int* __restrict__ offs,
                                                   const int* __restrict__ elist,
                                                   const float* __restrict__ att,
                                                   const float* __restrict__ bias) {
    int g = blockIdx.x * 16 + (threadIdx.x >> 4);   // dst node (NN divisible by 16)
    int l = threadIdx.x & 15;
    float attv[8], biasv[8];
    *(float4*)&attv[0] = *(const float4*)&att[l * 8];
    *(float4*)&attv[4] = *(const float4*)&att[l * 8 + 4];
    *(float4*)&biasv[0] = *(const float4*)&bias[l * 8];
    *(float4*)&biasv[4] = *(const float4*)&bias[l * 8 + 4];
    float xrf[8];
    unpack8(*(const uint4*)&xr[(size_t)g * HH + l * 8], xrf);
    int e0 = offs[g], e1 = offs[g + 1];

    float m = -__builtin_inff(), s = 0.f;
    float acc[8] = {};
    for (int e = e0; e < e1; ++e) {
        int sidx = elist[e];
        float xf[8];
        unpack8(*(const uint4*)&xl[(size_t)sidx * HH + l * 8], xf);
        float p = 0.f;
#pragma unroll
        for (int j = 0; j < 8; ++j) {
            float v = xf[j] + xrf[j];
            v = v >= 0.f ? v : 0.2f * v;
            p = fmaf(v, attv[j], p);
        }
        p += __shfl_xor(p, 1); p += __shfl_xor(p, 2);
        p += __shfl_xor(p, 4); p += __shfl_xor(p, 8);
        float mn = fmaxf(m, p);
        float so = __expf(m - mn);
        float w = __expf(p - mn);
        s = s * so + w;
#pragma unroll
        for (int j = 0; j < 8; ++j) acc[j] = fmaf(acc[j], so, w * xf[j]);
        m = mn;
    }
    float inv = 1.f / (s + 1e-16f);

    float hf[8];
    unpack8(*(const uint4*)&h[(size_t)g * HH + l * 8], hf);
    union { ushort sh[8]; uint4 v; } o;
#pragma unroll
    for (int j = 0; j < 8; ++j) {
        hf[j] += fmaxf(fmaf(acc[j], inv, biasv[j]), 0.f);
        o.sh[j] = f2b(hf[j]);
    }
    *(uint4*)&h[(size_t)g * HH + l * 8] = o.v;
}

// ---------- host side ----------
typedef const float* fp;

static void build_csr(const int* src, const int* dst, int* offs, int* elist,
                      int* work, int* bsum, hipStream_t stream) {
    hipMemsetAsync(work, 0, (size_t)NN * 4, stream);
    k_hist<<<(EE + 255) / 256, 256, 0, stream>>>(dst, work);
    k_scan_block<<<SCAN_NB, 256, 0, stream>>>(work, offs, bsum, NN);
    k_scan_top<<<1, 256, 0, stream>>>(bsum, SCAN_NB);
    k_scan_add<<<(NN + 255) / 256, 256, 0, stream>>>(offs, bsum, NN);
    hipMemcpyAsync(work, offs, (size_t)NN * 4, hipMemcpyDeviceToDevice, stream);
    k_scatter<<<(EE + 255) / 256, 256, 0, stream>>>(src, dst, work, elist);
}

extern "C" void kernel_launch(void* const* d_in, const int* in_sizes, int n_in,
                              void* d_out, int out_size, void* d_ws, size_t ws_size,
                              hipStream_t stream) {
    fp x                 = (fp)d_in[0];
    const int* ei        = (const int*)d_in[1];
    fp focal             = (fp)d_in[2];
    const int* child_idx = (const int*)d_in[3];
    const int* parent_idx= (const int*)d_in[4];
    const int* time_idx  = (const int*)d_in[5];
    fp W_embed = (fp)d_in[6],  b_embed = (fp)d_in[7];
    fp bu_Wl   = (fp)d_in[8],  bu_bl   = (fp)d_in[9];
    fp bu_Wr   = (fp)d_in[10], bu_br   = (fp)d_in[11];
    fp bu_att  = (fp)d_in[12], bu_bias = (fp)d_in[13];
    fp td_Wl   = (fp)d_in[14], td_bl   = (fp)d_in[15];
    fp td_Wr   = (fp)d_in[16], td_br   = (fp)d_in[17];
    fp td_att  = (fp)d_in[18], td_bias = (fp)d_in[19];
    fp time_table = (fp)d_in[20];
    fp W_comb  = (fp)d_in[21], b_comb  = (fp)d_in[22];
    fp W_a1    = (fp)d_in[23], b_a1    = (fp)d_in[24];
    fp W_a2    = (fp)d_in[25], b_a2    = (fp)d_in[26];
    fp W_seq   = (fp)d_in[27], b_seq   = (fp)d_in[28];

    const size_t NH = (size_t)NN * HH;
    u16* wt = (u16*)d_ws;                 // 8 x 16384 u16 (256 KB)
    u16* h  = wt + 8 * 16384;             // N*H bf16
    u16* xl = h + NH;
    u16* xr = xl + NH;
    float* c1v   = (float*)(xr + NH);     // H
    float* tproj = c1v + HH;              // T*H
    int* offsBU  = (int*)(tproj + (size_t)TT * HH);  // N+1
    int* offsTD  = offsBU + NN + 1;                  // N+1
    int* elistBU = offsTD + NN + 1;                  // E
    int* elistTD = elistBU + EE;                     // E
    int* csr_work= elistTD + EE;                     // N
    int* bsum    = csr_work + NN;                    // SCAN_NB

    // CSR build: BU dst=ei[0] src=ei[1]; TD dst=ei[1] src=ei[0]
    build_csr(ei + EE, ei, offsBU, elistBU, csr_work, bsum, stream);
    build_csr(ei, ei + EE, offsTD, elistTD, csr_work, bsum, stream);
    k_settail<<<1, 64, 0, stream>>>(offsBU, offsTD);

    // pre-transpose all GEMM weights to bf16 [n][k]
    k_wtrans<<<64, 256, 0, stream>>>(bu_Wl, bu_Wr, td_Wl, td_Wr,
                                     W_comb, W_comb + (size_t)HH * HH, W_a1, W_embed, wt);
    const u16* wt_buWl = wt + 0 * 16384;
    const u16* wt_buWr = wt + 1 * 16384;
    const u16* wt_tdWl = wt + 2 * 16384;
    const u16* wt_tdWr = wt + 3 * 16384;
    const u16* wt_combC = wt + 4 * 16384;
    const u16* wt_combP = wt + 5 * 16384;
    const u16* wt_a1   = wt + 6 * 16384;
    const u16* wt_embed = wt + 7 * 16384;

    // small precomputes
    k_ctx_c1<<<1, 128, 0, stream>>>(focal, W_seq, b_seq, W_a1 + (size_t)256 * HH, b_a1, c1v);
    k_tproj<<<TT, 128, 0, stream>>>(time_table, W_a1 + (size_t)128 * HH, tproj);

    const int NB = (NN + 127) / 128;
    // embed
    k_mfma_proj<64, float><<<NB, 256, 0, stream>>>(x, wt_embed, b_embed, h, NN);

    // bottom-up GAT
    k_mfma_proj2<<<NB, 512, 0, stream>>>(h, wt_buWl, wt_buWr, bu_bl, bu_br, xl, xr, NN);
    k_gat_fused<<<NN / 16, 256, 0, stream>>>(h, xl, xr, offsBU, elistBU, bu_att, bu_bias);

    // top-down GAT
    k_mfma_proj2<<<NB, 512, 0, stream>>>(h, wt_tdWl, wt_tdWr, td_bl, td_br, xl, xr, NN);
    k_gat_fused<<<NN / 16, 256, 0, stream>>>(h, xl, xr, offsTD, elistTD, td_att, td_bias);

    // branch + z + logit fused
    k_branch_logit<<<(AA + 127) / 128, 256, 0, stream>>>(
        h, child_idx, parent_idx, wt_combC, wt_combP, b_comb,
        time_idx, tproj, c1v, wt_a1, W_a2, b_a2, (float*)d_out);
}